// Round 4
// baseline (8565.627 us; speedup 1.0000x reference)
//
#include <hip/hip_runtime.h>

// ---------------------------------------------------------------------------
// Autoformer forward, MI355X. Round 4: f16x2-split MFMA GEMMs, alias fixes.
// B=32, L=512, D=512, C=21, MARK=4, FF=2048, MA_K=25, top_k=6
// GEMM trick: C = Ah*Bh + Ah*Bl + Al*Bh via K-concat (512 -> 1536), f32 acc.
//   A-side layout (M x 1536): [hi | hi | lo]   ("HHL")
//   B-side layout (N x 1536): [hi | lo | hi]   ("HLH", stored N-major = B^T)
// ---------------------------------------------------------------------------

typedef _Float16 h8 __attribute__((ext_vector_type(8)));
typedef float f32x4 __attribute__((ext_vector_type(4)));

__device__ __forceinline__ float gelu_f(float x){
    return 0.5f * x * (1.0f + erff(x * 0.70710678118654752f));
}

__global__ void zero_k(float* __restrict__ p, long n){
    long i = (long)blockIdx.x * 256 + threadIdx.x;
    if (i < n) p[i] = 0.f;
}

// ------------------------- f16 split kernels -------------------------------
// X (rows x 512) f32 -> Y (rows x 1536) f16. HLH=0: [hi,hi,lo]; HLH=1: [hi,lo,hi]
template<int HLH>
__global__ __launch_bounds__(256)
void split_k(const float* __restrict__ x, _Float16* __restrict__ y)
{
    long t = (long)blockIdx.x * 256 + threadIdx.x;   // one per 8 elems
    long row = t >> 6; int kc = (int)(t & 63) * 8;
    const float4 v0 = *(const float4*)(x + row * 512 + kc);
    const float4 v1 = *(const float4*)(x + row * 512 + kc + 4);
    float vv[8] = {v0.x,v0.y,v0.z,v0.w,v1.x,v1.y,v1.z,v1.w};
    h8 hi, lo;
#pragma unroll
    for (int j = 0; j < 8; j++) {
        _Float16 h = (_Float16)vv[j];
        hi[j] = h;
        lo[j] = (_Float16)(vv[j] - (float)h);
    }
    _Float16* base = y + row * 1536 + kc;
    *(h8*)(base)        = hi;
    *(h8*)(base + 512)  = HLH ? lo : hi;
    *(h8*)(base + 1024) = HLH ? hi : lo;
}

// W (512 x N) f32 -> dst (N x 1536) f16 HLH (transposed).  grid (16, N/32)
__global__ __launch_bounds__(256)
void convW_k(const float* __restrict__ src, _Float16* __restrict__ dst, int N)
{
    __shared__ float t[32][33];
    int k0 = blockIdx.x * 32, n0 = blockIdx.y * 32, tid = threadIdx.x;
#pragma unroll
    for (int i = 0; i < 4; i++) {
        int lin = tid + i * 256; int r = lin >> 5, c = lin & 31;
        t[r][c] = src[(long)(k0 + r) * N + n0 + c];
    }
    __syncthreads();
#pragma unroll
    for (int i = 0; i < 4; i++) {
        int lin = tid + i * 256; int n = lin >> 5, k = lin & 31;
        float v = t[k][n];
        _Float16 hi = (_Float16)v;
        _Float16 lo = (_Float16)(v - (float)hi);
        long base = (long)(n0 + n) * 1536 + k0 + k;
        dst[base] = hi; dst[base + 512] = lo; dst[base + 1024] = hi;
    }
}

// ------------------------------ MFMA GEMM ----------------------------------
// C(M x N f32) = Acat(M x Ka f16) * BcatT(N x Ka f16)^T, Ka % 64 == 0.
// 128x128 tile, BK=64, 256 thr (4 waves, 2x2), each wave 64x64 (4x4 frags).
// EPI: 0 none, 1 v+=R, 2 gelu, 3 v+=C.
template<int EPI>
__global__ __launch_bounds__(256)
void hgemm_k(const _Float16* __restrict__ A, const _Float16* __restrict__ Bm,
             const float* __restrict__ R, float* __restrict__ C,
             int Ka, int ldc, long sA, long sB, long sC)
{
    __shared__ _Float16 As[128 * 64];
    __shared__ _Float16 Bs[128 * 64];
    const int bz = blockIdx.z;
    const _Float16* Ap = A + (long)bz * sA + (long)blockIdx.y * 128 * Ka;
    const _Float16* Bp = Bm + (long)bz * sB + (long)blockIdx.x * 128 * Ka;
    float* Cp = C + (long)bz * sC;
    const float* Rp = (EPI == 1) ? (R + (long)bz * sC) : nullptr;
    const int tid = threadIdx.x;
    const int lane = tid & 63;
    const int w = tid >> 6, wr = w >> 1, wc = w & 1;

    f32x4 acc[4][4] = {};

    int row_[4], ps_[4], ls_[4];
#pragma unroll
    for (int i = 0; i < 4; i++) {
        int lin = tid + i * 256;
        row_[i] = lin >> 3; ps_[i] = lin & 7; ls_[i] = ps_[i] ^ (row_[i] & 7);
    }
    float4 ra[4], rb[4];
#pragma unroll
    for (int i = 0; i < 4; i++) {
        ra[i] = *(const float4*)(Ap + (long)row_[i] * Ka + ls_[i] * 8);
        rb[i] = *(const float4*)(Bp + (long)row_[i] * Ka + ls_[i] * 8);
    }
    const int NT = Ka >> 6;
    for (int kt = 0; kt < NT; ++kt) {
#pragma unroll
        for (int i = 0; i < 4; i++) {
            *(float4*)(As + row_[i] * 64 + ps_[i] * 8) = ra[i];
            *(float4*)(Bs + row_[i] * 64 + ps_[i] * 8) = rb[i];
        }
        __syncthreads();
        if (kt + 1 < NT) {
            int k0h = (kt + 1) << 6;
#pragma unroll
            for (int i = 0; i < 4; i++) {
                ra[i] = *(const float4*)(Ap + (long)row_[i] * Ka + k0h + ls_[i] * 8);
                rb[i] = *(const float4*)(Bp + (long)row_[i] * Ka + k0h + ls_[i] * 8);
            }
        }
#pragma unroll
        for (int kk = 0; kk < 2; ++kk) {
            h8 af[4], bf[4];
            const int ks = kk * 4 + (lane >> 4);
#pragma unroll
            for (int m = 0; m < 4; m++) {
                int rowa = wr * 64 + m * 16 + (lane & 15);
                af[m] = *(const h8*)(As + rowa * 64 + ((ks ^ (rowa & 7)) * 8));
                int rowb = wc * 64 + m * 16 + (lane & 15);
                bf[m] = *(const h8*)(Bs + rowb * 64 + ((ks ^ (rowb & 7)) * 8));
            }
#pragma unroll
            for (int m = 0; m < 4; m++)
#pragma unroll
                for (int n = 0; n < 4; n++)
                    acc[m][n] = __builtin_amdgcn_mfma_f32_16x16x32_f16(af[m], bf[n], acc[m][n], 0, 0, 0);
        }
        __syncthreads();
    }
    const int crow0 = blockIdx.y * 128 + wr * 64 + (lane >> 4) * 4;
    const int ccol0 = blockIdx.x * 128 + wc * 64 + (lane & 15);
#pragma unroll
    for (int m = 0; m < 4; m++)
#pragma unroll
        for (int n = 0; n < 4; n++) {
            int col = ccol0 + n * 16;
#pragma unroll
            for (int r2 = 0; r2 < 4; r2++) {
                long idx = (long)(crow0 + m * 16 + r2) * ldc + col;
                float v = acc[m][n][r2];
                if (EPI == 1) v += Rp[idx];
                if (EPI == 2) v = gelu_f(v);
                if (EPI == 3) v += Cp[idx];
                Cp[idx] = v;
            }
        }
}

// ------------------------- embedding (conv3 + mark + pe) -------------------
__global__ __launch_bounds__(256)
void embed_k(const float* __restrict__ x, const float* __restrict__ mark,
             const float* __restrict__ valW, const float* __restrict__ timeW,
             float* __restrict__ out)
{
    const int lg = blockIdx.x, dh = blockIdx.y, b = blockIdx.z;
    const int tid = threadIdx.x;
    const int dd = dh * 256 + tid;
    const int l0 = lg * 8;
    __shared__ float xs[10][21];
    __shared__ float mk[8][4];
    if (tid < 210) {
        int r = tid / 21, c = tid % 21;
        int ll = (l0 - 1 + r + 512) & 511;
        xs[r][c] = x[((long)b * 512 + ll) * 21 + c];
    }
    if (tid >= 224 && tid < 256) {
        int t2 = tid - 224, il = t2 >> 2, m = t2 & 3;
        mk[il][m] = mark[((long)b * 512 + l0 + il) * 4 + m];
    }
    __syncthreads();
    float acc[8];
#pragma unroll
    for (int il = 0; il < 8; il++) acc[il] = 0.f;
    for (int t = 0; t < 3; t++)
        for (int c = 0; c < 21; c++) {
            float w = valW[(t * 21 + c) * 512 + dd];
#pragma unroll
            for (int il = 0; il < 8; il++)
                acc[il] = fmaf(xs[il + t][c], w, acc[il]);
        }
    for (int m = 0; m < 4; m++) {
        float w = timeW[m * 512 + dd];
#pragma unroll
        for (int il = 0; il < 8; il++)
            acc[il] = fmaf(mk[il][m], w, acc[il]);
    }
    const float freq = expf((float)(dd & ~1) * (-9.210340371976184f / 512.0f));
#pragma unroll
    for (int il = 0; il < 8; il++) {
        float ang = (float)(l0 + il) * freq;
        float pe = (dd & 1) ? cosf(ang) : sinf(ang);
        out[((long)b * 512 + l0 + il) * 512 + dd] = acc[il] + pe;
    }
}

// ------------------------- series decomp -----------------------------------
__global__ void decomp21_k(const float* __restrict__ x, float* __restrict__ seas,
                           float* __restrict__ trend, int total)
{
    int i = blockIdx.x * 256 + threadIdx.x;
    if (i >= total) return;
    int c = i % 21, l = (i / 21) % 512, b = i / 10752;
    float s = 0.f;
    for (int j = -12; j <= 12; j++) {
        int ll = l + j; ll = ll < 0 ? 0 : (ll > 511 ? 511 : ll);
        s += x[((long)b * 512 + ll) * 21 + c];
    }
    float t = s * (1.f / 25.f);
    trend[i] = t;
    seas[i] = x[i] - t;
}

template<int TREND>
__global__ __launch_bounds__(256)
void decomp512_k(const float* __restrict__ x, float* __restrict__ out,
                 float* __restrict__ ts)
{
    long i = (long)blockIdx.x * 256 + threadIdx.x;
    int d = (int)(i & 511), l = (int)((i >> 9) & 511), b = (int)(i >> 18);
    const float* xb = x + ((long)b << 18);
    float s = 0.f;
#pragma unroll
    for (int j = -12; j <= 12; j++) {
        int ll = l + j; ll = ll < 0 ? 0 : (ll > 511 ? 511 : ll);
        s += xb[((long)ll << 9) + d];
    }
    float t = s * (1.f / 25.f);
    out[i] = x[i] - t;
    if (TREND) ts[i] += t;
}

// ------------------------- small prep kernels ------------------------------
__global__ void meanseq_k(const float* __restrict__ x, float* __restrict__ xm, int total)
{
    int i = blockIdx.x * 256 + threadIdx.x;
    if (i >= total) return;
    int c = i % 21, b = i / 21;
    float s = 0.f;
    for (int l = 0; l < 512; l++) s += x[((long)b * 512 + l) * 21 + c];
    xm[i] = s * (1.f / 512.f);
}

__global__ void buildinit_k(const float* __restrict__ seas, const float* __restrict__ trend,
                            const float* __restrict__ xm,
                            float* __restrict__ sinit, float* __restrict__ tinit, int total)
{
    int i = blockIdx.x * 256 + threadIdx.x;
    if (i >= total) return;
    int c = i % 21, l = (i / 21) % 512, b = i / 10752;
    if (l < 256) {
        sinit[i] = seas[((long)b * 512 + 256 + l) * 21 + c];
        tinit[i] = trend[((long)b * 512 + 256 + l) * 21 + c];
    } else {
        sinit[i] = 0.f;
        tinit[i] = xm[b * 21 + c];
    }
}

// ------------------------- autocorrelation pieces --------------------------
__global__ void diagred_k(const float* __restrict__ S, float* __restrict__ mc)
{
    int tau = blockIdx.x * 256 + threadIdx.x;   // grid (2, Bc)
    int b = blockIdx.y;
    const float* Sb = S + ((long)b << 18);
    float s = 0.f;
    for (int m = 0; m < 512; m++)
        s += Sb[((long)((m + tau) & 511) << 9) + m];
    mc[b * 512 + tau] = s * (1.f / 512.f);
}

__global__ __launch_bounds__(256)
void topk_k(const float* __restrict__ mc, int* __restrict__ delays,
            float* __restrict__ wts)
{
    int b = blockIdx.x, tid = threadIdx.x;
    __shared__ float v[512];
    __shared__ float rv[256];
    __shared__ int   ri[256];
    __shared__ float selv[6];
    v[tid] = mc[b * 512 + tid];
    v[tid + 256] = mc[b * 512 + tid + 256];
    __syncthreads();
    for (int p = 0; p < 6; p++) {
        float bv = v[tid]; int bi = tid;
        float v2 = v[tid + 256];
        if (v2 > bv) { bv = v2; bi = tid + 256; }
        rv[tid] = bv; ri[tid] = bi;
        __syncthreads();
        for (int s = 128; s > 0; s >>= 1) {
            if (tid < s) {
                float ov = rv[tid + s]; int oi = ri[tid + s];
                if (ov > rv[tid] || (ov == rv[tid] && oi < ri[tid])) {
                    rv[tid] = ov; ri[tid] = oi;
                }
            }
            __syncthreads();
        }
        if (tid == 0) { selv[p] = rv[0]; delays[b * 6 + p] = ri[0]; v[ri[0]] = -3.4e38f; }
        __syncthreads();
    }
    if (tid == 0) {
        float mx = selv[0];
        for (int p = 1; p < 6; p++) mx = fmaxf(mx, selv[p]);
        float e[6], sum = 0.f;
        for (int p = 0; p < 6; p++) { e[p] = expf(selv[p] - mx); sum += e[p]; }
        for (int p = 0; p < 6; p++) wts[b * 6 + p] = e[p] / sum;
    }
}

__global__ __launch_bounds__(256)
void agg_k(const float* __restrict__ V, const int* __restrict__ delays,
           const float* __restrict__ wts, float* __restrict__ out)
{
    long i = (long)blockIdx.x * 256 + threadIdx.x;
    int d = (int)(i & 511), l = (int)((i >> 9) & 511), b = (int)(i >> 18);
    const float* Vb = V + ((long)b << 18);
    float s = 0.f;
#pragma unroll
    for (int k = 0; k < 6; k++) {
        int dl = delays[b * 6 + k];
        float w = wts[b * 6 + k];
        s = fmaf(w, Vb[((long)((l + dl) & 511) << 9) + d], s);
    }
    out[i] = s;
}

// ------------------------- seasonal layernorm ------------------------------
__global__ __launch_bounds__(256)
void ln_k(const float* __restrict__ x, const float* __restrict__ g,
          const float* __restrict__ be, float* __restrict__ out)
{
    int row = blockIdx.x, tid = threadIdx.x;
    const float* xr = x + ((long)row << 9);
    float v0 = xr[tid], v1 = xr[tid + 256];
    __shared__ float rs[256];
    rs[tid] = v0 + v1; __syncthreads();
    for (int s = 128; s > 0; s >>= 1) { if (tid < s) rs[tid] += rs[tid + s]; __syncthreads(); }
    float mu = rs[0] * (1.f / 512.f);
    __syncthreads();
    float d0 = v0 - mu, d1 = v1 - mu;
    rs[tid] = d0 * d0 + d1 * d1; __syncthreads();
    for (int s = 128; s > 0; s >>= 1) { if (tid < s) rs[tid] += rs[tid + s]; __syncthreads(); }
    float rstd = 1.0f / sqrtf(rs[0] * (1.f / 512.f) + 1e-5f);
    out[((long)row << 9) + tid]       = d0 * rstd * g[tid] + be[tid];
    out[((long)row << 9) + tid + 256] = d1 * rstd * g[tid + 256] + be[tid + 256];
}

__global__ void colpart_k(const float* __restrict__ x, float* __restrict__ cp)
{
    int d = blockIdx.x * 256 + threadIdx.x;   // grid (2, 8, Bc)
    int ch = blockIdx.y, b = blockIdx.z;
    const float* xb = x + ((long)b << 18);
    float s = 0.f;
    for (int l = ch * 64; l < ch * 64 + 64; l++) s += xb[((long)l << 9) + d];
    cp[((long)(b * 8 + ch) << 9) + d] = s;
}

__global__ __launch_bounds__(256)
void subcol_k(const float* __restrict__ x, const float* __restrict__ cp,
              float* __restrict__ out)
{
    long i = (long)blockIdx.x * 256 + threadIdx.x;
    int d = (int)(i & 511), b = (int)(i >> 18);
    float m = 0.f;
#pragma unroll
    for (int ch = 0; ch < 8; ch++) m += cp[((long)(b * 8 + ch) << 9) + d];
    out[i] = x[i] - m * (1.f / 512.f);
}

// ------------------------- trend conv (as skinny GEMM) ---------------------
// H[r][j] = sum_d TS[r][d] * W[(j/21)][d][(j%21)], j<63; r = b*512+l
__global__ __launch_bounds__(256)
void tsgemm_k(const float* __restrict__ TS, const float* __restrict__ W,
              float* __restrict__ H)
{
    __shared__ float As[128][33];
    __shared__ float Ws[32][64];
    const int row0 = blockIdx.x * 128;
    const int tid = threadIdx.x;
    const int row = tid >> 1, half = tid & 1;
    float acc[32];
#pragma unroll
    for (int j = 0; j < 32; j++) acc[j] = 0.f;
    for (int k0 = 0; k0 < 512; k0 += 32) {
#pragma unroll
        for (int i = 0; i < 16; i++) {
            int lin = tid + i * 256; int r = lin >> 5, c = lin & 31;
            As[r][c] = TS[(long)(row0 + r) * 512 + k0 + c];
        }
#pragma unroll
        for (int i = 0; i < 8; i++) {
            int lin = tid + i * 256; int kk = lin >> 6, j = lin & 63;
            Ws[kk][j] = (j < 63) ? W[(long)(j / 21) * 10752 + (long)(k0 + kk) * 21 + (j % 21)] : 0.f;
        }
        __syncthreads();
        for (int kk = 0; kk < 32; kk++) {
            float a = As[row][kk];
            const float4* wr4 = (const float4*)&Ws[kk][half * 32];
#pragma unroll
            for (int q = 0; q < 8; q++) {
                float4 wv = wr4[q];
                acc[q*4+0] = fmaf(a, wv.x, acc[q*4+0]);
                acc[q*4+1] = fmaf(a, wv.y, acc[q*4+1]);
                acc[q*4+2] = fmaf(a, wv.z, acc[q*4+2]);
                acc[q*4+3] = fmaf(a, wv.w, acc[q*4+3]);
            }
        }
        __syncthreads();
    }
    float* out = H + (long)(row0 + row) * 64 + half * 32;
#pragma unroll
    for (int j = 0; j < 32; j++) out[j] = acc[j];
}

__global__ void shiftadd_k(const float* __restrict__ H, const float* __restrict__ tinit,
                           float* __restrict__ tf, int total)
{
    int i = blockIdx.x * 256 + threadIdx.x;
    if (i >= total) return;
    int c = i % 21, l = (i / 21) % 512, b = i / 10752;
    long r = (long)b * 512;
    tf[i] = tinit[i]
          + H[(r + ((l + 511) & 511)) * 64 + c]
          + H[(r + l) * 64 + 21 + c]
          + H[(r + ((l + 1) & 511)) * 64 + 42 + c];
}

__global__ void proj_k(const float* __restrict__ x, const float* __restrict__ pw,
                       const float* __restrict__ pb, const float* __restrict__ trend,
                       float* __restrict__ out, int total)
{
    int i = blockIdx.x * 256 + threadIdx.x;
    if (i >= total) return;
    int c = i % 21, l = (i / 21) % 256 + 256, b = i / 5376;
    const float* xr = x + ((long)(b * 512 + l) << 9);
    float s = 0.f;
    for (int d = 0; d < 512; d++) s = fmaf(xr[d], pw[d * 21 + c], s);
    out[i] = s + pb[c] + trend[((long)b * 512 + l) * 21 + c];
}

// ---------------------------------------------------------------------------
static void hgemm(int epi, const _Float16* A, const _Float16* B, const float* R,
                  float* C, int M, int N, int Ka, int batch,
                  long sA, long sB, long sC, hipStream_t st)
{
    dim3 g(N / 128, M / 128, batch), blk(256);
    switch (epi) {
    case 0: hgemm_k<0><<<g, blk, 0, st>>>(A, B, R, C, Ka, N, sA, sB, sC); break;
    case 1: hgemm_k<1><<<g, blk, 0, st>>>(A, B, R, C, Ka, N, sA, sB, sC); break;
    case 2: hgemm_k<2><<<g, blk, 0, st>>>(A, B, R, C, Ka, N, sA, sB, sC); break;
    default:hgemm_k<3><<<g, blk, 0, st>>>(A, B, R, C, Ka, N, sA, sB, sC); break;
    }
}

extern "C" void kernel_launch(void* const* d_in, const int* in_sizes, int n_in,
                              void* d_out, int out_size, void* d_ws, size_t ws_size,
                              hipStream_t stream)
{
    const float* x_enc    = (const float*)d_in[0];
    const float* xm_enc   = (const float*)d_in[1];
    const float* xm_dec   = (const float*)d_in[3];
    const float* enc_valW = (const float*)d_in[4];
    const float* enc_timeW= (const float*)d_in[5];
    const float* enc_Wq   = (const float*)d_in[6];
    const float* enc_Wk   = (const float*)d_in[7];
    const float* enc_Wv   = (const float*)d_in[8];
    const float* enc_Wo   = (const float*)d_in[9];
    const float* enc_W1   = (const float*)d_in[10];
    const float* enc_W2   = (const float*)d_in[11];
    const float* enc_g    = (const float*)d_in[12];
    const float* enc_b    = (const float*)d_in[13];
    const float* dec_valW = (const float*)d_in[14];
    const float* dec_timeW= (const float*)d_in[15];
    const float* sWq = (const float*)d_in[16];
    const float* sWk = (const float*)d_in[17];
    const float* sWv = (const float*)d_in[18];
    const float* sWo = (const float*)d_in[19];
    const float* cWq = (const float*)d_in[20];
    const float* cWk = (const float*)d_in[21];
    const float* cWv = (const float*)d_in[22];
    const float* cWo = (const float*)d_in[23];
    const float* dW1 = (const float*)d_in[24];
    const float* dW2 = (const float*)d_in[25];
    const float* dtW = (const float*)d_in[26];
    const float* dec_g = (const float*)d_in[27];
    const float* dec_b = (const float*)d_in[28];
    const float* projW = (const float*)d_in[29];
    const float* projB = (const float*)d_in[30];

    // ---- pick batch-chunk size (constant across calls -> deterministic) ----
    const size_t W_BYTES = 62914560;     // weight-cat f16 total
    const size_t perB = 5ull*1048576 + 3ull*1572864 + 131072 + 250000;
    int Bc = 32;
    while (Bc > 1 && W_BYTES + (size_t)Bc * perB + (2u<<20) > ws_size) Bc >>= 1;

    char* wp = (char*)d_ws;
    auto alloc = [&](size_t bytes) { char* p = wp; wp += (bytes + 255) & ~(size_t)255; return p; };

    _Float16* encWqC = (_Float16*)alloc(2 * 786432 * 2);
    _Float16* encWkC = (_Float16*)alloc(2 * 786432 * 2);
    _Float16* encWvC = (_Float16*)alloc(2 * 786432 * 2);
    _Float16* encWoC = (_Float16*)alloc(2 * 786432 * 2);
    _Float16* sWqC = (_Float16*)alloc(786432 * 2);
    _Float16* sWkC = (_Float16*)alloc(786432 * 2);
    _Float16* sWvC = (_Float16*)alloc(786432 * 2);
    _Float16* sWoC = (_Float16*)alloc(786432 * 2);
    _Float16* cWqC = (_Float16*)alloc(786432 * 2);
    _Float16* cWkC = (_Float16*)alloc(786432 * 2);
    _Float16* cWvC = (_Float16*)alloc(786432 * 2);
    _Float16* cWoC = (_Float16*)alloc(786432 * 2);
    _Float16* encW1C = (_Float16*)alloc(2 * 3145728 * 2);   // (2048 x 1536)/layer
    _Float16* decW1C = (_Float16*)alloc(3145728 * 2);
    _Float16* encW2C = (_Float16*)alloc(2 * 3145728 * 2);   // 4 x (512 x 1536)/layer
    _Float16* decW2C = (_Float16*)alloc(3145728 * 2);

    const long NBc = (long)Bc * 262144;
    float* X   = (float*)alloc(NBc * 4);
    float* O   = (float*)alloc(NBc * 4);
    float* P   = (float*)alloc(NBc * 4);
    float* ENC = (float*)alloc(NBc * 4);
    float* TS  = (float*)alloc(NBc * 4);
    _Float16* c0 = (_Float16*)alloc((long)Bc * 786432 * 2);
    _Float16* c1 = (_Float16*)alloc((long)Bc * 786432 * 2);
    _Float16* c2 = (_Float16*)alloc((long)Bc * 786432 * 2);
    float* H63   = (float*)alloc((long)Bc * 32768 * 4);
    float* seas_s  = (float*)alloc((long)Bc * 10752 * 4);
    float* trend_t = (float*)alloc((long)Bc * 10752 * 4);
    float* sinit   = (float*)alloc((long)Bc * 10752 * 4);
    float* tinit   = (float*)alloc((long)Bc * 10752 * 4);
    float* tfinal  = (float*)alloc((long)Bc * 10752 * 4);
    float* xmean   = (float*)alloc((long)Bc * 21 * 4);
    float* mc      = (float*)alloc((long)Bc * 512 * 4);
    float* cp      = (float*)alloc((long)Bc * 4096 * 4);
    float* wts     = (float*)alloc((long)Bc * 6 * 4);
    int*   delays  = (int*)alloc((long)Bc * 6 * 4);

    // ---- convert weights (every call; deterministic) ----
    dim3 cb(256);
    for (int L = 0; L < 2; L++) {
        convW_k<<<dim3(16,16), cb, 0, stream>>>(enc_Wq + (long)L*262144, encWqC + (long)L*786432, 512);
        convW_k<<<dim3(16,16), cb, 0, stream>>>(enc_Wk + (long)L*262144, encWkC + (long)L*786432, 512);
        convW_k<<<dim3(16,16), cb, 0, stream>>>(enc_Wv + (long)L*262144, encWvC + (long)L*786432, 512);
        convW_k<<<dim3(16,16), cb, 0, stream>>>(enc_Wo + (long)L*262144, encWoC + (long)L*786432, 512);
        convW_k<<<dim3(16,64), cb, 0, stream>>>(enc_W1 + (long)L*1048576, encW1C + (long)L*3145728, 2048);
        for (int cc = 0; cc < 4; cc++)
            convW_k<<<dim3(16,16), cb, 0, stream>>>(enc_W2 + (long)L*1048576 + cc*262144,
                                                    encW2C + (long)L*3145728 + cc*786432, 512);
    }
    convW_k<<<dim3(16,16), cb, 0, stream>>>(sWq, sWqC, 512);
    convW_k<<<dim3(16,16), cb, 0, stream>>>(sWk, sWkC, 512);
    convW_k<<<dim3(16,16), cb, 0, stream>>>(sWv, sWvC, 512);
    convW_k<<<dim3(16,16), cb, 0, stream>>>(sWo, sWoC, 512);
    convW_k<<<dim3(16,16), cb, 0, stream>>>(cWq, cWqC, 512);
    convW_k<<<dim3(16,16), cb, 0, stream>>>(cWk, cWkC, 512);
    convW_k<<<dim3(16,16), cb, 0, stream>>>(cWv, cWvC, 512);
    convW_k<<<dim3(16,16), cb, 0, stream>>>(cWo, cWoC, 512);
    convW_k<<<dim3(16,64), cb, 0, stream>>>(dW1, decW1C, 2048);
    for (int cc = 0; cc < 4; cc++)
        convW_k<<<dim3(16,16), cb, 0, stream>>>(dW2 + cc*262144, decW2C + cc*786432, 512);

    const int M = Bc * 512;
    const int t21 = Bc * 10752;
    const int gNB = (int)(NBc / 256);
    const int gSplit = Bc * 128;
    const long sQh = 786432;                 // per-batch cat stride (halfs)
    const long sS = 262144;

    // attention: Xc += attn(Xc; KVsrc). scr: S+agg scratch, must differ from
    // Xc, P, KVsrc. Uses P for Q/K/V outputs, c0/c1/c2 for cat operands.
    auto attn = [&](float* Xc, float* scr, const float* KVsrc,
                    const _Float16* WqC_, const _Float16* WkC_,
                    const _Float16* WvC_, const _Float16* WoC_) {
        split_k<0><<<gSplit, 256, 0, stream>>>(Xc, c0);
        hgemm(0, c0, WqC_, nullptr, P, M, 512, 1536, 1, 0, 0, 0, stream);
        split_k<0><<<gSplit, 256, 0, stream>>>(P, c1);          // Qcat (HHL)
        if (KVsrc != Xc) split_k<0><<<gSplit, 256, 0, stream>>>(KVsrc, c0);
        hgemm(0, c0, WkC_, nullptr, P, M, 512, 1536, 1, 0, 0, 0, stream);
        split_k<1><<<gSplit, 256, 0, stream>>>(P, c2);          // Kcat (HLH)
        hgemm(0, c1, c2, nullptr, scr, 512, 512, 1536, Bc, sQh, sQh, sS, stream); // S
        diagred_k<<<dim3(2, Bc), 256, 0, stream>>>(scr, mc);
        topk_k   <<<Bc, 256, 0, stream>>>(mc, delays, wts);
        hgemm(0, c0, WvC_, nullptr, P, M, 512, 1536, 1, 0, 0, 0, stream);        // V
        agg_k    <<<gNB, 256, 0, stream>>>(P, delays, wts, scr);
        split_k<0><<<gSplit, 256, 0, stream>>>(scr, c1);
        hgemm(1, c1, WoC_, Xc, Xc, M, 512, 1536, 1, 0, 0, 0, stream);            // Xc += agg@Wo
    };
    // FFN: Xout = gelu(Xc@W1)@W2 + Xc.  Hidden chunks live in P:
    // REQUIRES Xc != P and Xout != P.
    auto ffn = [&](const float* Xc, float* Xout, const _Float16* W1C, const _Float16* W2C) {
        split_k<0><<<gSplit, 256, 0, stream>>>(Xc, c0);
        for (int cc = 0; cc < 4; cc++) {
            hgemm(2, c0, W1C + (long)cc * 786432, nullptr, P, M, 512, 1536, 1, 0, 0, 0, stream);
            split_k<0><<<gSplit, 256, 0, stream>>>(P, c1);
            hgemm(cc == 0 ? 1 : 3, c1, W2C + (long)cc * 786432, Xc, Xout,
                  M, 512, 1536, 1, 0, 0, 0, stream);
        }
    };

    for (int b0 = 0; b0 < 32; b0 += Bc) {
        const float* xe  = x_enc  + (long)b0 * 10752;
        const float* mke = xm_enc + (long)b0 * 2048;
        const float* mkd = xm_dec + (long)b0 * 2048;
        float* outp = (float*)d_out + (long)b0 * 5376;

        meanseq_k  <<<(Bc*21 + 255)/256, 256, 0, stream>>>(xe, xmean, Bc*21);
        decomp21_k <<<t21/256, 256, 0, stream>>>(xe, seas_s, trend_t, t21);
        buildinit_k<<<t21/256, 256, 0, stream>>>(seas_s, trend_t, xmean, sinit, tinit, t21);

        // ---------------- encoder (ping-pong Xs/Os) ----------------
        float* Xs = X; float* Os = O;
        embed_k<<<dim3(64,2,Bc), 256, 0, stream>>>(xe, mke, enc_valW, enc_timeW, Xs);
        for (int L = 0; L < 2; L++) {
            attn(Xs, Os, Xs, encWqC + (long)L*786432, encWkC + (long)L*786432,
                 encWvC + (long)L*786432, encWoC + (long)L*786432);
            decomp512_k<0><<<gNB, 256, 0, stream>>>(Xs, Os, nullptr);   // Os = seasonal
            ffn(Os, Xs, encW1C + (long)L*3145728, encW2C + (long)L*3145728); // Xs = ffn+res
            decomp512_k<0><<<gNB, 256, 0, stream>>>(Xs, Os, nullptr);   // Os = layer out
            { float* t = Xs; Xs = Os; Os = t; }                          // stream -> Xs
        }
        ln_k     <<<Bc*512, 256, 0, stream>>>(Xs, enc_g, enc_b, Os);
        colpart_k<<<dim3(2,8,Bc), 256, 0, stream>>>(Os, cp);
        subcol_k <<<gNB, 256, 0, stream>>>(Os, cp, ENC);

        // ---------------- decoder ----------------
        embed_k<<<dim3(64,2,Bc), 256, 0, stream>>>(sinit, mkd, dec_valW, dec_timeW, X);
        zero_k <<<gNB, 256, 0, stream>>>(TS, NBc);

        attn(X, O, X, sWqC, sWkC, sWvC, sWoC);                   // self; scr=O
        decomp512_k<1><<<gNB, 256, 0, stream>>>(X, O, TS);       // stream -> O
        attn(O, X, ENC, cWqC, cWkC, cWvC, cWoC);                 // cross; scr=X (dead)
        decomp512_k<1><<<gNB, 256, 0, stream>>>(O, X, TS);       // stream -> X
        ffn(X, O, decW1C, decW2C);                               // O = ffn+res (hidden P)
        decomp512_k<1><<<gNB, 256, 0, stream>>>(O, X, TS);       // stream -> X

        tsgemm_k  <<<Bc*4, 256, 0, stream>>>(TS, dtW, H63);
        shiftadd_k<<<(t21+255)/256, 256, 0, stream>>>(H63, tinit, tfinal, t21);
        ln_k     <<<Bc*512, 256, 0, stream>>>(X, dec_g, dec_b, O);
        colpart_k<<<dim3(2,8,Bc), 256, 0, stream>>>(O, cp);
        subcol_k <<<gNB, 256, 0, stream>>>(O, cp, O);
        proj_k   <<<(Bc*5376+255)/256, 256, 0, stream>>>(O, projW, projB, tfinal, outp, Bc*5376);
    }
}

// Round 5
// 3790.716 us; speedup vs baseline: 2.2596x; 2.2596x over previous
//
#include <hip/hip_runtime.h>

// ---------------------------------------------------------------------------
// Autoformer forward, MI355X. Round 5: hi/lo-cat MFMA GEMM with virtual
// 3-phase K-schedule + global_load_lds staging + fused QKV/W1/W2 + epilogue
// split. B=32, L=512, D=512, C=21, FF=2048, MA_K=25, top_k=6.
// Operand format: rows x 2K f16, [hi(K) | lo(K)]; C = Ah*Bh + Ah*Bl + Al*Bh.
// ---------------------------------------------------------------------------

typedef _Float16 h8 __attribute__((ext_vector_type(8)));
typedef float f32x4 __attribute__((ext_vector_type(4)));

__device__ __forceinline__ float gelu_f(float x){
    return 0.5f * x * (1.0f + erff(x * 0.70710678118654752f));
}

__device__ __forceinline__ void gl_lds(const _Float16* gp, _Float16* lp) {
    __builtin_amdgcn_global_load_lds(
        (const __attribute__((address_space(1))) void*)gp,
        (__attribute__((address_space(3))) void*)lp, 16, 0, 0);
}

__global__ void zero_k(float* __restrict__ p, long n){
    long i = (long)blockIdx.x * 256 + threadIdx.x;
    if (i < n) p[i] = 0.f;
}

// ------------------------------ MFMA GEMM ----------------------------------
// A: M x 2K [hi|lo] (lda halfs/row, lo at +loA). B: N x 2K (ldb, +loB).
// 3 phases x (K/64) tiles: (Ah,Bh), (Ah,Bl), (Al,Bh). f32 accum.
// OUT=0: f32 C (ldc floats), EPI 0 none / 1 +R / 2 gelu.
// OUT=1: f16 cat write: hi at [row*ldc+col], lo at +loC. EPI 0 or 2.
// 128x128 tile, BK=64, 256 thr (4 waves 2x2), wave 64x64 (4x4 16x16x32 frags).
template<int EPI, int OUT>
__global__ __launch_bounds__(256)
void hgemm_k(const _Float16* __restrict__ A, int lda, int loA,
             const _Float16* __restrict__ Bm, int ldb, int loB,
             const float* __restrict__ R, void* __restrict__ Cv,
             int ldc, int loC, int K,
             long sA, long sB, long sC)
{
    __shared__ _Float16 As[128 * 64];
    __shared__ _Float16 Bs[128 * 64];
    const int bz = blockIdx.z;
    const int tid = threadIdx.x, lane = tid & 63, w = tid >> 6;
    const int wr = w >> 1, wc = w & 1;
    const _Float16* Ap = A + bz * sA + (long)(blockIdx.y * 128) * lda;
    const _Float16* Bp = Bm + bz * sB + (long)(blockIdx.x * 128) * ldb;

    // staging: wave w stages segments s=w*4+i (8 rows each, 1KB)
    // lane l -> row s*8 + (l>>3), swizzled chunk (l&7)^((l>>3)&7)
    const int swz = ((lane & 7) ^ ((lane >> 3) & 7)) * 8;
    const int rsub = w * 32 + (lane >> 3);
    const _Float16* ApT = Ap + (long)rsub * lda + swz;
    const _Float16* BpT = Bp + (long)rsub * ldb + swz;
    _Float16* AsT = As + w * 2048;
    _Float16* BsT = Bs + w * 2048;

    const int tpp = K >> 6;
    const int nkt = tpp * 3;
    f32x4 acc[4][4] = {};

    int p = 0, q = 0;
    for (int kt = 0; kt < nkt; ++kt) {
        const int aoff = q * 64 + (p == 2 ? loA : 0);
        const int boff = q * 64 + (p == 1 ? loB : 0);
        __syncthreads();
#pragma unroll
        for (int i = 0; i < 4; i++) {
            gl_lds(ApT + (long)i * 8 * lda + aoff, AsT + i * 512);
            gl_lds(BpT + (long)i * 8 * ldb + boff, BsT + i * 512);
        }
        __syncthreads();
#pragma unroll
        for (int kk = 0; kk < 2; ++kk) {
            h8 af[4], bf[4];
            const int ks = kk * 4 + (lane >> 4);
#pragma unroll
            for (int m = 0; m < 4; m++) {
                int rowa = wr * 64 + m * 16 + (lane & 15);
                af[m] = *(const h8*)(As + rowa * 64 + ((ks ^ (rowa & 7)) * 8));
                int rowb = wc * 64 + m * 16 + (lane & 15);
                bf[m] = *(const h8*)(Bs + rowb * 64 + ((ks ^ (rowb & 7)) * 8));
            }
#pragma unroll
            for (int m = 0; m < 4; m++)
#pragma unroll
                for (int n = 0; n < 4; n++)
                    acc[m][n] = __builtin_amdgcn_mfma_f32_16x16x32_f16(af[m], bf[n], acc[m][n], 0, 0, 0);
        }
        if (++q == tpp) { q = 0; ++p; }
    }

    const int crow0 = blockIdx.y * 128 + wr * 64 + (lane >> 4) * 4;
    const int ccol0 = blockIdx.x * 128 + wc * 64 + (lane & 15);
    if (OUT == 0) {
        float* Cp = (float*)Cv + (long)bz * sC;
        const float* Rp = (EPI == 1) ? (R + (long)bz * sC) : nullptr;
#pragma unroll
        for (int m = 0; m < 4; m++)
#pragma unroll
            for (int n = 0; n < 4; n++) {
                int col = ccol0 + n * 16;
#pragma unroll
                for (int r2 = 0; r2 < 4; r2++) {
                    long idx = (long)(crow0 + m * 16 + r2) * ldc + col;
                    float v = acc[m][n][r2];
                    if (EPI == 1) v += Rp[idx];
                    if (EPI == 2) v = gelu_f(v);
                    Cp[idx] = v;
                }
            }
    } else {
        _Float16* Cp = (_Float16*)Cv + (long)bz * sC;
#pragma unroll
        for (int m = 0; m < 4; m++)
#pragma unroll
            for (int n = 0; n < 4; n++) {
                int col = ccol0 + n * 16;
#pragma unroll
                for (int r2 = 0; r2 < 4; r2++) {
                    long base = (long)(crow0 + m * 16 + r2) * ldc + col;
                    float v = acc[m][n][r2];
                    if (EPI == 2) v = gelu_f(v);
                    _Float16 hi = (_Float16)v;
                    Cp[base] = hi;
                    Cp[base + loC] = (_Float16)(v - (float)hi);
                }
            }
    }
}

// ------------------------- split / weight conversion -----------------------
// f32 rows x 512 -> cat rows x 1024 [hi|lo]
__global__ __launch_bounds__(256)
void split2_k(const float* __restrict__ x, _Float16* __restrict__ y)
{
    long t = (long)blockIdx.x * 256 + threadIdx.x;
    long row = t >> 6; int kc = (int)(t & 63) * 8;
    const float4 v0 = *(const float4*)(x + row * 512 + kc);
    const float4 v1 = *(const float4*)(x + row * 512 + kc + 4);
    float vv[8] = {v0.x,v0.y,v0.z,v0.w,v1.x,v1.y,v1.z,v1.w};
    h8 hi, lo;
#pragma unroll
    for (int j = 0; j < 8; j++) {
        _Float16 h = (_Float16)vv[j];
        hi[j] = h; lo[j] = (_Float16)(vv[j] - (float)h);
    }
    *(h8*)(y + row * 1024 + kc)       = hi;
    *(h8*)(y + row * 1024 + 512 + kc) = lo;
}

// W (K x N f32) -> dst (N rows x 2K f16 cat). grid (K/32, N/32)
__global__ __launch_bounds__(256)
void convW2_k(const float* __restrict__ src, _Float16* __restrict__ dst,
              int N, int K)
{
    __shared__ float t[32][33];
    int k0 = blockIdx.x * 32, n0 = blockIdx.y * 32, tid = threadIdx.x;
#pragma unroll
    for (int i = 0; i < 4; i++) {
        int lin = tid + i * 256; int r = lin >> 5, c = lin & 31;
        t[r][c] = src[(long)(k0 + r) * N + n0 + c];
    }
    __syncthreads();
#pragma unroll
    for (int i = 0; i < 4; i++) {
        int lin = tid + i * 256; int n = lin >> 5, k = lin & 31;
        float v = t[k][n];
        _Float16 hi = (_Float16)v;
        long base = (long)(n0 + n) * 2 * K + k0 + k;
        dst[base]     = hi;
        dst[base + K] = (_Float16)(v - (float)hi);
    }
}

// ------------------------- embedding (conv3 + mark + pe) -------------------
__global__ __launch_bounds__(256)
void embed_k(const float* __restrict__ x, const float* __restrict__ mark,
             const float* __restrict__ valW, const float* __restrict__ timeW,
             float* __restrict__ out)
{
    const int lg = blockIdx.x, dh = blockIdx.y, b = blockIdx.z;
    const int tid = threadIdx.x;
    const int dd = dh * 256 + tid;
    const int l0 = lg * 8;
    __shared__ float xs[10][21];
    __shared__ float mk[8][4];
    if (tid < 210) {
        int r = tid / 21, c = tid % 21;
        int ll = (l0 - 1 + r + 512) & 511;
        xs[r][c] = x[((long)b * 512 + ll) * 21 + c];
    }
    if (tid >= 224 && tid < 256) {
        int t2 = tid - 224, il = t2 >> 2, m = t2 & 3;
        mk[il][m] = mark[((long)b * 512 + l0 + il) * 4 + m];
    }
    __syncthreads();
    float acc[8];
#pragma unroll
    for (int il = 0; il < 8; il++) acc[il] = 0.f;
    for (int t = 0; t < 3; t++)
        for (int c = 0; c < 21; c++) {
            float w = valW[(t * 21 + c) * 512 + dd];
#pragma unroll
            for (int il = 0; il < 8; il++)
                acc[il] = fmaf(xs[il + t][c], w, acc[il]);
        }
    for (int m = 0; m < 4; m++) {
        float w = timeW[m * 512 + dd];
#pragma unroll
        for (int il = 0; il < 8; il++)
            acc[il] = fmaf(mk[il][m], w, acc[il]);
    }
    const float freq = expf((float)(dd & ~1) * (-9.210340371976184f / 512.0f));
#pragma unroll
    for (int il = 0; il < 8; il++) {
        float ang = (float)(l0 + il) * freq;
        float pe = (dd & 1) ? cosf(ang) : sinf(ang);
        out[((long)b * 512 + l0 + il) * 512 + dd] = acc[il] + pe;
    }
}

// ------------------------- series decomp -----------------------------------
__global__ void decomp21_k(const float* __restrict__ x, float* __restrict__ seas,
                           float* __restrict__ trend, int total)
{
    int i = blockIdx.x * 256 + threadIdx.x;
    if (i >= total) return;
    int c = i % 21, l = (i / 21) % 512, b = i / 10752;
    float s = 0.f;
    for (int j = -12; j <= 12; j++) {
        int ll = l + j; ll = ll < 0 ? 0 : (ll > 511 ? 511 : ll);
        s += x[((long)b * 512 + ll) * 21 + c];
    }
    float t = s * (1.f / 25.f);
    trend[i] = t;
    seas[i] = x[i] - t;
}

template<int TREND>
__global__ __launch_bounds__(256)
void decomp512_k(const float* __restrict__ x, float* __restrict__ out,
                 float* __restrict__ ts)
{
    long i = (long)blockIdx.x * 256 + threadIdx.x;
    int d = (int)(i & 511), l = (int)((i >> 9) & 511), b = (int)(i >> 18);
    const float* xb = x + ((long)b << 18);
    float s = 0.f;
#pragma unroll
    for (int j = -12; j <= 12; j++) {
        int ll = l + j; ll = ll < 0 ? 0 : (ll > 511 ? 511 : ll);
        s += xb[((long)ll << 9) + d];
    }
    float t = s * (1.f / 25.f);
    out[i] = x[i] - t;
    if (TREND) ts[i] += t;
}

// ------------------------- small prep kernels ------------------------------
__global__ void meanseq_k(const float* __restrict__ x, float* __restrict__ xm, int total)
{
    int i = blockIdx.x * 256 + threadIdx.x;
    if (i >= total) return;
    int c = i % 21, b = i / 21;
    float s = 0.f;
    for (int l = 0; l < 512; l++) s += x[((long)b * 512 + l) * 21 + c];
    xm[i] = s * (1.f / 512.f);
}

__global__ void buildinit_k(const float* __restrict__ seas, const float* __restrict__ trend,
                            const float* __restrict__ xm,
                            float* __restrict__ sinit, float* __restrict__ tinit, int total)
{
    int i = blockIdx.x * 256 + threadIdx.x;
    if (i >= total) return;
    int c = i % 21, l = (i / 21) % 512, b = i / 10752;
    if (l < 256) {
        sinit[i] = seas[((long)b * 512 + 256 + l) * 21 + c];
        tinit[i] = trend[((long)b * 512 + 256 + l) * 21 + c];
    } else {
        sinit[i] = 0.f;
        tinit[i] = xm[b * 21 + c];
    }
}

// ------------------------- autocorrelation pieces --------------------------
// partial mc over 128 rows: grid (4, Bc), 512 threads
__global__ __launch_bounds__(512)
void diagred2_k(const float* __restrict__ S, float* __restrict__ mcp)
{
    const int p = blockIdx.x, b = blockIdx.y, tid = threadIdx.x;
    __shared__ float rowb[512];
    const float* Sb = S + ((long)b << 18);
    float acc = 0.f;
    for (int r = p * 128; r < p * 128 + 128; ++r) {
        rowb[tid] = Sb[((long)r << 9) + tid];
        __syncthreads();
        acc += rowb[(r - tid) & 511];
        __syncthreads();
    }
    mcp[((long)(b * 4 + p) << 9) + tid] = acc;
}

__global__ __launch_bounds__(256)
void topk_k(const float* __restrict__ mcp, int* __restrict__ delays,
            float* __restrict__ wts)
{
    int b = blockIdx.x, tid = threadIdx.x;
    __shared__ float v[512];
    __shared__ float rv[256];
    __shared__ int   ri[256];
    __shared__ float selv[6];
    const float* m0 = mcp + (long)(b * 4) * 512;
    v[tid]       = (m0[tid]       + m0[512 + tid]       + m0[1024 + tid]       + m0[1536 + tid])       * (1.f / 512.f);
    v[tid + 256] = (m0[tid + 256] + m0[512 + tid + 256] + m0[1024 + tid + 256] + m0[1536 + tid + 256]) * (1.f / 512.f);
    __syncthreads();
    for (int p = 0; p < 6; p++) {
        float bv = v[tid]; int bi = tid;
        float v2 = v[tid + 256];
        if (v2 > bv) { bv = v2; bi = tid + 256; }
        rv[tid] = bv; ri[tid] = bi;
        __syncthreads();
        for (int s = 128; s > 0; s >>= 1) {
            if (tid < s) {
                float ov = rv[tid + s]; int oi = ri[tid + s];
                if (ov > rv[tid] || (ov == rv[tid] && oi < ri[tid])) {
                    rv[tid] = ov; ri[tid] = oi;
                }
            }
            __syncthreads();
        }
        if (tid == 0) { selv[p] = rv[0]; delays[b * 6 + p] = ri[0]; v[ri[0]] = -3.4e38f; }
        __syncthreads();
    }
    if (tid == 0) {
        float mx = selv[0];
        for (int p = 1; p < 6; p++) mx = fmaxf(mx, selv[p]);
        float e[6], sum = 0.f;
        for (int p = 0; p < 6; p++) { e[p] = expf(selv[p] - mx); sum += e[p]; }
        for (int p = 0; p < 6; p++) wts[b * 6 + p] = e[p] / sum;
    }
}

// gather-agg from V cat slice; write cat out (rows x 1024)
__global__ __launch_bounds__(256)
void agg2_k(const _Float16* __restrict__ Vc, int vld, int vhi, int vlo,
            const int* __restrict__ delays, const float* __restrict__ wts,
            _Float16* __restrict__ out)
{
    long t = (long)blockIdx.x * 256 + threadIdx.x;
    int dc = (int)(t & 63);
    long row = t >> 6;
    int l = (int)(row & 511), b = (int)(row >> 9);
    float s[8] = {};
#pragma unroll
    for (int k = 0; k < 6; k++) {
        int dl = delays[b * 6 + k];
        float wv = wts[b * 6 + k];
        long sr = ((long)b * 512 + ((l + dl) & 511)) * vld + dc * 8;
        h8 hi8 = *(const h8*)(Vc + sr + vhi);
        h8 lo8 = *(const h8*)(Vc + sr + vlo);
#pragma unroll
        for (int j = 0; j < 8; j++)
            s[j] = fmaf(wv, (float)hi8[j] + (float)lo8[j], s[j]);
    }
    h8 ho, lo;
#pragma unroll
    for (int j = 0; j < 8; j++) {
        _Float16 h = (_Float16)s[j];
        ho[j] = h; lo[j] = (_Float16)(s[j] - (float)h);
    }
    long ob = row * 1024 + dc * 8;
    *(h8*)(out + ob)       = ho;
    *(h8*)(out + ob + 512) = lo;
}

// ------------------------- seasonal layernorm ------------------------------
__global__ __launch_bounds__(256)
void ln_k(const float* __restrict__ x, const float* __restrict__ g,
          const float* __restrict__ be, float* __restrict__ out)
{
    int row = blockIdx.x, tid = threadIdx.x;
    const float* xr = x + ((long)row << 9);
    float v0 = xr[tid], v1 = xr[tid + 256];
    __shared__ float rs[256];
    rs[tid] = v0 + v1; __syncthreads();
    for (int s = 128; s > 0; s >>= 1) { if (tid < s) rs[tid] += rs[tid + s]; __syncthreads(); }
    float mu = rs[0] * (1.f / 512.f);
    __syncthreads();
    float d0 = v0 - mu, d1 = v1 - mu;
    rs[tid] = d0 * d0 + d1 * d1; __syncthreads();
    for (int s = 128; s > 0; s >>= 1) { if (tid < s) rs[tid] += rs[tid + s]; __syncthreads(); }
    float rstd = 1.0f / sqrtf(rs[0] * (1.f / 512.f) + 1e-5f);
    out[((long)row << 9) + tid]       = d0 * rstd * g[tid] + be[tid];
    out[((long)row << 9) + tid + 256] = d1 * rstd * g[tid + 256] + be[tid + 256];
}

__global__ void colpart_k(const float* __restrict__ x, float* __restrict__ cp)
{
    int d = blockIdx.x * 256 + threadIdx.x;   // grid (2, 8, Bc)
    int ch = blockIdx.y, b = blockIdx.z;
    const float* xb = x + ((long)b << 18);
    float s = 0.f;
    for (int l = ch * 64; l < ch * 64 + 64; l++) s += xb[((long)l << 9) + d];
    cp[((long)(b * 8 + ch) << 9) + d] = s;
}

__global__ __launch_bounds__(256)
void subcol_k(const float* __restrict__ x, const float* __restrict__ cp,
              float* __restrict__ out)
{
    long i = (long)blockIdx.x * 256 + threadIdx.x;
    int d = (int)(i & 511), b = (int)(i >> 18);
    float m = 0.f;
#pragma unroll
    for (int ch = 0; ch < 8; ch++) m += cp[((long)(b * 8 + ch) << 9) + d];
    out[i] = x[i] - m * (1.f / 512.f);
}

// ------------------------- trend conv (skinny GEMM, 64-row tiles) ----------
__global__ __launch_bounds__(256)
void tsgemm2_k(const float* __restrict__ TS, const float* __restrict__ W,
               float* __restrict__ H)
{
    __shared__ float As[64][33];
    __shared__ float Ws[32][64];
    const int row0 = blockIdx.x * 64;
    const int tid = threadIdx.x;
    const int row = tid & 63, qq = tid >> 6;
    float acc[16] = {};
    for (int k0 = 0; k0 < 512; k0 += 32) {
#pragma unroll
        for (int i = 0; i < 8; i++) {
            int lin = tid + i * 256; int r = lin >> 5, c = lin & 31;
            As[r][c] = TS[(long)(row0 + r) * 512 + k0 + c];
        }
#pragma unroll
        for (int i = 0; i < 8; i++) {
            int lin = tid + i * 256; int kk = lin >> 6, j = lin & 63;
            Ws[kk][j] = (j < 63) ? W[(long)(j / 21) * 10752 + (long)(k0 + kk) * 21 + (j % 21)] : 0.f;
        }
        __syncthreads();
        for (int kk = 0; kk < 32; ++kk) {
            float a = As[row][kk];
            const float4* w4 = (const float4*)&Ws[kk][qq * 16];
#pragma unroll
            for (int t4 = 0; t4 < 4; ++t4) {
                float4 wv = w4[t4];
                acc[t4*4+0] = fmaf(a, wv.x, acc[t4*4+0]);
                acc[t4*4+1] = fmaf(a, wv.y, acc[t4*4+1]);
                acc[t4*4+2] = fmaf(a, wv.z, acc[t4*4+2]);
                acc[t4*4+3] = fmaf(a, wv.w, acc[t4*4+3]);
            }
        }
        __syncthreads();
    }
    float* out = H + (long)(row0 + row) * 64 + qq * 16;
#pragma unroll
    for (int j = 0; j < 16; j++) out[j] = acc[j];
}

__global__ void shiftadd_k(const float* __restrict__ H, const float* __restrict__ tinit,
                           float* __restrict__ tf, int total)
{
    int i = blockIdx.x * 256 + threadIdx.x;
    if (i >= total) return;
    int c = i % 21, l = (i / 21) % 512, b = i / 10752;
    long r = (long)b * 512;
    tf[i] = tinit[i]
          + H[(r + ((l + 511) & 511)) * 64 + c]
          + H[(r + l) * 64 + 21 + c]
          + H[(r + ((l + 1) & 511)) * 64 + 42 + c];
}

__global__ void proj_k(const float* __restrict__ x, const float* __restrict__ pw,
                       const float* __restrict__ pb, const float* __restrict__ trend,
                       float* __restrict__ out, int total)
{
    int i = blockIdx.x * 256 + threadIdx.x;
    if (i >= total) return;
    int c = i % 21, l = (i / 21) % 256 + 256, b = i / 5376;
    const float* xr = x + ((long)(b * 512 + l) << 9);
    float s = 0.f;
    for (int d = 0; d < 512; d++) s = fmaf(xr[d], pw[d * 21 + c], s);
    out[i] = s + pb[c] + trend[((long)b * 512 + l) * 21 + c];
}

// ---------------------------------------------------------------------------
static void hgemm(int epi, int out,
                  const _Float16* A, int lda, int loA,
                  const _Float16* B, int ldb, int loB,
                  const float* R, void* C, int ldc, int loC,
                  int K, int M, int N, int batch,
                  long sA, long sB, long sC, hipStream_t st)
{
    dim3 g(N / 128, M / 128, batch), blk(256);
    if (out == 0) {
        if (epi == 1) hgemm_k<1,0><<<g,blk,0,st>>>(A,lda,loA,B,ldb,loB,R,C,ldc,loC,K,sA,sB,sC);
        else          hgemm_k<0,0><<<g,blk,0,st>>>(A,lda,loA,B,ldb,loB,R,C,ldc,loC,K,sA,sB,sC);
    } else {
        if (epi == 2) hgemm_k<2,1><<<g,blk,0,st>>>(A,lda,loA,B,ldb,loB,R,C,ldc,loC,K,sA,sB,sC);
        else          hgemm_k<0,1><<<g,blk,0,st>>>(A,lda,loA,B,ldb,loB,R,C,ldc,loC,K,sA,sB,sC);
    }
}

extern "C" void kernel_launch(void* const* d_in, const int* in_sizes, int n_in,
                              void* d_out, int out_size, void* d_ws, size_t ws_size,
                              hipStream_t stream)
{
    const float* x_enc    = (const float*)d_in[0];
    const float* xm_enc   = (const float*)d_in[1];
    const float* xm_dec   = (const float*)d_in[3];
    const float* enc_valW = (const float*)d_in[4];
    const float* enc_timeW= (const float*)d_in[5];
    const float* enc_Wq   = (const float*)d_in[6];
    const float* enc_Wk   = (const float*)d_in[7];
    const float* enc_Wv   = (const float*)d_in[8];
    const float* enc_Wo   = (const float*)d_in[9];
    const float* enc_W1   = (const float*)d_in[10];
    const float* enc_W2   = (const float*)d_in[11];
    const float* enc_g    = (const float*)d_in[12];
    const float* enc_b    = (const float*)d_in[13];
    const float* dec_valW = (const float*)d_in[14];
    const float* dec_timeW= (const float*)d_in[15];
    const float* sWq = (const float*)d_in[16];
    const float* sWk = (const float*)d_in[17];
    const float* sWv = (const float*)d_in[18];
    const float* sWo = (const float*)d_in[19];
    const float* cWq = (const float*)d_in[20];
    const float* cWk = (const float*)d_in[21];
    const float* cWv = (const float*)d_in[22];
    const float* cWo = (const float*)d_in[23];
    const float* dW1 = (const float*)d_in[24];
    const float* dW2 = (const float*)d_in[25];
    const float* dtW = (const float*)d_in[26];
    const float* dec_g = (const float*)d_in[27];
    const float* dec_b = (const float*)d_in[28];
    const float* projW = (const float*)d_in[29];
    const float* projB = (const float*)d_in[30];

    // ---- batch-chunk sizing (deterministic) ----
    const size_t W_BYTES = 41943040;
    const size_t perB = 11534336ull + 131072 + 215040 + 8192 + 16384 + 512;
    int Bc = 32;
    while (Bc > 1 && W_BYTES + (size_t)Bc * perB + (4u << 20) > ws_size) Bc >>= 1;

    char* wp = (char*)d_ws;
    auto alloc = [&](size_t bytes) { char* p = wp; wp += (bytes + 255) & ~(size_t)255; return p; };

    // weight cat buffers
    _Float16* encQKVC = (_Float16*)alloc(2 * 1572864 * 2);   // 1536x1024 per layer
    _Float16* encWoC  = (_Float16*)alloc(2 * 524288 * 2);    // 512x1024
    _Float16* encW1C  = (_Float16*)alloc(2 * 2097152 * 2);   // 2048x1024
    _Float16* encW2C  = (_Float16*)alloc(2 * 2097152 * 2);   // 512x4096
    _Float16* dsQKVC  = (_Float16*)alloc(1572864 * 2);
    _Float16* dsWoC   = (_Float16*)alloc(524288 * 2);
    _Float16* dcWqC   = (_Float16*)alloc(524288 * 2);
    _Float16* dcWkvC  = (_Float16*)alloc(1048576 * 2);       // 1024x1024
    _Float16* dcWoC   = (_Float16*)alloc(524288 * 2);
    _Float16* dW1C    = (_Float16*)alloc(2097152 * 2);
    _Float16* dW2C    = (_Float16*)alloc(2097152 * 2);

    const long ROWS = (long)Bc * 512;
    const long NBc  = ROWS * 512;            // f32 activation elems
    float*    X      = (float*)alloc(NBc * 4);
    float*    O      = (float*)alloc(NBc * 4);
    float*    TS     = (float*)alloc(NBc * 4);
    float*    Sb     = (float*)alloc(NBc * 4);        // S matrix / ENC f32
    _Float16* c0     = (_Float16*)alloc(ROWS * 1024 * 2);
    _Float16* cAgg   = (_Float16*)alloc(ROWS * 1024 * 2);
    _Float16* ENCcat = (_Float16*)alloc(ROWS * 1024 * 2);
    _Float16* bigcat = (_Float16*)alloc(ROWS * 4096 * 2);
    float* H63     = (float*)alloc((long)Bc * 32768 * 4);
    float* seas_s  = (float*)alloc((long)Bc * 10752 * 4);
    float* trend_t = (float*)alloc((long)Bc * 10752 * 4);
    float* sinit   = (float*)alloc((long)Bc * 10752 * 4);
    float* tinit   = (float*)alloc((long)Bc * 10752 * 4);
    float* tfinal  = (float*)alloc((long)Bc * 10752 * 4);
    float* xmean   = (float*)alloc((long)Bc * 21 * 4);
    float* mcp     = (float*)alloc((long)Bc * 2048 * 4);
    float* cp      = (float*)alloc((long)Bc * 4096 * 4);
    float* wts     = (float*)alloc((long)Bc * 6 * 4);
    int*   delays  = (int*)alloc((long)Bc * 6 * 4);

    // ---- weight conversion ----
    dim3 cb(256);
    for (int L = 0; L < 2; L++) {
        _Float16* q = encQKVC + (long)L * 1572864;
        convW2_k<<<dim3(16,16), cb, 0, stream>>>(enc_Wq + (long)L*262144, q,              512, 512);
        convW2_k<<<dim3(16,16), cb, 0, stream>>>(enc_Wk + (long)L*262144, q + 512*1024,   512, 512);
        convW2_k<<<dim3(16,16), cb, 0, stream>>>(enc_Wv + (long)L*262144, q + 1024*1024,  512, 512);
        convW2_k<<<dim3(16,16), cb, 0, stream>>>(enc_Wo + (long)L*262144, encWoC + (long)L*524288, 512, 512);
        convW2_k<<<dim3(16,64), cb, 0, stream>>>(enc_W1 + (long)L*1048576, encW1C + (long)L*2097152, 2048, 512);
        convW2_k<<<dim3(64,16), cb, 0, stream>>>(enc_W2 + (long)L*1048576, encW2C + (long)L*2097152, 512, 2048);
    }
    convW2_k<<<dim3(16,16), cb, 0, stream>>>(sWq, dsQKVC,              512, 512);
    convW2_k<<<dim3(16,16), cb, 0, stream>>>(sWk, dsQKVC + 512*1024,   512, 512);
    convW2_k<<<dim3(16,16), cb, 0, stream>>>(sWv, dsQKVC + 1024*1024,  512, 512);
    convW2_k<<<dim3(16,16), cb, 0, stream>>>(sWo, dsWoC, 512, 512);
    convW2_k<<<dim3(16,16), cb, 0, stream>>>(cWq, dcWqC, 512, 512);
    convW2_k<<<dim3(16,16), cb, 0, stream>>>(cWk, dcWkvC,             512, 512);
    convW2_k<<<dim3(16,16), cb, 0, stream>>>(cWv, dcWkvC + 512*1024,  512, 512);
    convW2_k<<<dim3(16,16), cb, 0, stream>>>(cWo, dcWoC, 512, 512);
    convW2_k<<<dim3(16,64), cb, 0, stream>>>(dW1, dW1C, 2048, 512);
    convW2_k<<<dim3(64,16), cb, 0, stream>>>(dW2, dW2C, 512, 2048);

    const int M = (int)ROWS;
    const int t21 = Bc * 10752;
    const int gNB = (int)(NBc / 256);
    const int gRows = Bc * 128;              // split2/agg2 grids
    const long sSA = 512 * 4096;             // per-batch stride in bigcat (halfs)
    const long sSC = 262144;                 // per-batch stride in S (floats)

    // self/enc attention: Cout = Xin + attn(Xin)
    auto attn_self = [&](float* Xin, float* Cout,
                         const _Float16* WqkvC, const _Float16* WoC) {
        split2_k<<<gRows, 256, 0, stream>>>(Xin, c0);
        hgemm(0,1, c0,1024,512, WqkvC,1024,512, nullptr, bigcat, 4096, 1536,
              512, M, 1536, 1, 0,0,0, stream);
        hgemm(0,0, bigcat,4096,1536, bigcat+512,4096,1536, nullptr, Sb, 512, 0,
              512, 512, 512, Bc, sSA, sSA, sSC, stream);
        diagred2_k<<<dim3(4,Bc), 512, 0, stream>>>(Sb, mcp);
        topk_k    <<<Bc, 256, 0, stream>>>(mcp, delays, wts);
        agg2_k    <<<gRows, 256, 0, stream>>>(bigcat, 4096, 1024, 2560, delays, wts, cAgg);
        hgemm(1,0, cAgg,1024,512, WoC,1024,512, Xin, Cout, 512, 0,
              512, M, 512, 1, 0,0,0, stream);
    };
    // ffn: Cout = Xin + gelu(Xin@W1)@W2
    auto ffn = [&](float* Xin, float* Cout, const _Float16* W1C, const _Float16* W2C) {
        split2_k<<<gRows, 256, 0, stream>>>(Xin, c0);
        hgemm(2,1, c0,1024,512, W1C,1024,512, nullptr, bigcat, 4096, 2048,
              512, M, 2048, 1, 0,0,0, stream);
        hgemm(1,0, bigcat,4096,2048, W2C,4096,2048, Xin, Cout, 512, 0,
              2048, M, 512, 1, 0,0,0, stream);
    };

    for (int b0 = 0; b0 < 32; b0 += Bc) {
        const float* xe  = x_enc  + (long)b0 * 10752;
        const float* mke = xm_enc + (long)b0 * 2048;
        const float* mkd = xm_dec + (long)b0 * 2048;
        float* outp = (float*)d_out + (long)b0 * 5376;

        meanseq_k  <<<(Bc*21 + 255)/256, 256, 0, stream>>>(xe, xmean, Bc*21);
        decomp21_k <<<t21/256, 256, 0, stream>>>(xe, seas_s, trend_t, t21);
        buildinit_k<<<t21/256, 256, 0, stream>>>(seas_s, trend_t, xmean, sinit, tinit, t21);

        // ---------------- encoder ----------------
        embed_k<<<dim3(64,2,Bc), 256, 0, stream>>>(xe, mke, enc_valW, enc_timeW, X);
        for (int L = 0; L < 2; L++) {
            attn_self(X, O, encQKVC + (long)L*1572864, encWoC + (long)L*524288);
            decomp512_k<0><<<gNB, 256, 0, stream>>>(O, X, nullptr);     // X = seasonal
            ffn(X, O, encW1C + (long)L*2097152, encW2C + (long)L*2097152);
            decomp512_k<0><<<gNB, 256, 0, stream>>>(O, X, nullptr);     // X = layer out
        }
        ln_k     <<<Bc*512, 256, 0, stream>>>(X, enc_g, enc_b, O);
        colpart_k<<<dim3(2,8,Bc), 256, 0, stream>>>(O, cp);
        subcol_k <<<gNB, 256, 0, stream>>>(O, cp, Sb);                   // ENC f32 in Sb
        split2_k <<<gRows, 256, 0, stream>>>(Sb, ENCcat);

        // ---------------- decoder ----------------
        embed_k<<<dim3(64,2,Bc), 256, 0, stream>>>(sinit, mkd, dec_valW, dec_timeW, X);
        zero_k <<<gNB, 256, 0, stream>>>(TS, NBc);

        // self attention
        attn_self(X, O, dsQKVC, dsWoC);
        decomp512_k<1><<<gNB, 256, 0, stream>>>(O, X, TS);               // stream X

        // cross attention (Q from X, K/V from ENCcat)
        split2_k<<<gRows, 256, 0, stream>>>(X, c0);
        hgemm(0,1, c0,1024,512, dcWqC,1024,512, nullptr, cAgg, 1024, 512,
              512, M, 512, 1, 0,0,0, stream);                            // cQ in cAgg
        hgemm(0,1, ENCcat,1024,512, dcWkvC,1024,512, nullptr, bigcat, 4096, 1024,
              512, M, 1024, 1, 0,0,0, stream);                           // [K|V] cat
        hgemm(0,0, cAgg,1024,512, bigcat,4096,1024, nullptr, Sb, 512, 0,
              512, 512, 512, Bc, 512*1024, sSA, sSC, stream);
        diagred2_k<<<dim3(4,Bc), 512, 0, stream>>>(Sb, mcp);
        topk_k    <<<Bc, 256, 0, stream>>>(mcp, delays, wts);
        agg2_k    <<<gRows, 256, 0, stream>>>(bigcat, 4096, 512, 1536, delays, wts, cAgg);
        hgemm(1,0, cAgg,1024,512, dcWoC,1024,512, X, O, 512, 0,
              512, M, 512, 1, 0,0,0, stream);
        decomp512_k<1><<<gNB, 256, 0, stream>>>(O, X, TS);               // stream X

        // ffn
        ffn(X, O, dW1C, dW2C);
        decomp512_k<1><<<gNB, 256, 0, stream>>>(O, X, TS);               // stream X

        tsgemm2_k <<<Bc*8, 256, 0, stream>>>(TS, dtW, H63);
        shiftadd_k<<<(t21+255)/256, 256, 0, stream>>>(H63, tinit, tfinal, t21);
        ln_k     <<<Bc*512, 256, 0, stream>>>(X, dec_g, dec_b, O);
        colpart_k<<<dim3(2,8,Bc), 256, 0, stream>>>(O, cp);
        subcol_k <<<gNB, 256, 0, stream>>>(O, cp, O);
        proj_k   <<<(Bc*5376+255)/256, 256, 0, stream>>>(O, projW, projB, tfinal, outp, Bc*5376);
    }
}

// Round 6
// 3630.004 us; speedup vs baseline: 2.3597x; 1.0443x over previous
//
#include <hip/hip_runtime.h>

// ---------------------------------------------------------------------------
// Autoformer forward, MI355X. Round 6: fused splits (producers emit hi/lo cat),
// S-GEMM diagonal-reduce epilogue (no S materialization), fewer launches.
// B=32, L=512, D=512, C=21, FF=2048, MA_K=25, top_k=6.
// GEMM numerics: C = Ah*Bh + Ah*Bl + Al*Bh via virtual 3-phase K-schedule,
// operands stored rows x 2K f16 [hi(K)|lo(K)], f32 accum (rel err ~2^-21).
// ---------------------------------------------------------------------------

typedef _Float16 h8 __attribute__((ext_vector_type(8)));
typedef float f32x4 __attribute__((ext_vector_type(4)));

__device__ __forceinline__ float gelu_f(float x){
    return 0.5f * x * (1.0f + erff(x * 0.70710678118654752f));
}

__device__ __forceinline__ void gl_lds(const _Float16* gp, _Float16* lp) {
    __builtin_amdgcn_global_load_lds(
        (const __attribute__((address_space(1))) void*)gp,
        (__attribute__((address_space(3))) void*)lp, 16, 0, 0);
}

__global__ void zero_k(float* __restrict__ p, long n){
    long i = (long)blockIdx.x * 256 + threadIdx.x;
    if (i < n) p[i] = 0.f;
}

// ------------------------------ MFMA GEMM ----------------------------------
// A: M x 2K [hi|lo] (lda halfs/row, lo at +loA). B: N x 2K (ldb, +loB).
// 3 phases x (K/64): (Ah,Bh),(Ah,Bl),(Al,Bh). f32 accum.
// OUT=0: f32 C (ldc floats), EPI 1: +R residual.
// OUT=1: f16 cat C: hi at [row*ldc+col], lo at +loC. EPI 0 plain / 2 gelu.
// OUT=2: no C; diagonal reduce: atomicAdd mc[bz*sC + (row-col)&511] += acc.
template<int EPI, int OUT>
__global__ __launch_bounds__(256)
void hgemm_k(const _Float16* __restrict__ A, int lda, int loA,
             const _Float16* __restrict__ Bm, int ldb, int loB,
             const float* __restrict__ R, void* __restrict__ Cv,
             int ldc, int loC, int K,
             long sA, long sB, long sC)
{
    __shared__ _Float16 As[128 * 64];
    __shared__ _Float16 Bs[128 * 64];
    const int bz = blockIdx.z;
    const int tid = threadIdx.x, lane = tid & 63, w = tid >> 6;
    const int wr = w >> 1, wc = w & 1;
    const _Float16* Ap = A + bz * sA + (long)(blockIdx.y * 128) * lda;
    const _Float16* Bp = Bm + bz * sB + (long)(blockIdx.x * 128) * ldb;

    const int swz = ((lane & 7) ^ ((lane >> 3) & 7)) * 8;
    const int rsub = w * 32 + (lane >> 3);
    const _Float16* ApT = Ap + (long)rsub * lda + swz;
    const _Float16* BpT = Bp + (long)rsub * ldb + swz;
    _Float16* AsT = As + w * 2048;
    _Float16* BsT = Bs + w * 2048;

    const int tpp = K >> 6;
    const int nkt = tpp * 3;
    f32x4 acc[4][4] = {};

    int p = 0, q = 0;
    for (int kt = 0; kt < nkt; ++kt) {
        const int aoff = q * 64 + (p == 2 ? loA : 0);
        const int boff = q * 64 + (p == 1 ? loB : 0);
        __syncthreads();
#pragma unroll
        for (int i = 0; i < 4; i++) {
            gl_lds(ApT + (long)i * 8 * lda + aoff, AsT + i * 512);
            gl_lds(BpT + (long)i * 8 * ldb + boff, BsT + i * 512);
        }
        __syncthreads();
#pragma unroll
        for (int kk = 0; kk < 2; ++kk) {
            h8 af[4], bf[4];
            const int ks = kk * 4 + (lane >> 4);
#pragma unroll
            for (int m = 0; m < 4; m++) {
                int rowa = wr * 64 + m * 16 + (lane & 15);
                af[m] = *(const h8*)(As + rowa * 64 + ((ks ^ (rowa & 7)) * 8));
                int rowb = wc * 64 + m * 16 + (lane & 15);
                bf[m] = *(const h8*)(Bs + rowb * 64 + ((ks ^ (rowb & 7)) * 8));
            }
#pragma unroll
            for (int m = 0; m < 4; m++)
#pragma unroll
                for (int n = 0; n < 4; n++)
                    acc[m][n] = __builtin_amdgcn_mfma_f32_16x16x32_f16(af[m], bf[n], acc[m][n], 0, 0, 0);
        }
        if (++q == tpp) { q = 0; ++p; }
    }

    const int crow0 = blockIdx.y * 128 + wr * 64 + (lane >> 4) * 4;
    const int ccol0 = blockIdx.x * 128 + wc * 64 + (lane & 15);
    if constexpr (OUT == 0) {
        float* Cp = (float*)Cv + (long)bz * sC;
        const float* Rp = (EPI == 1) ? (R + (long)bz * sC) : nullptr;
#pragma unroll
        for (int m = 0; m < 4; m++)
#pragma unroll
            for (int n = 0; n < 4; n++) {
                int col = ccol0 + n * 16;
#pragma unroll
                for (int r2 = 0; r2 < 4; r2++) {
                    long idx = (long)(crow0 + m * 16 + r2) * ldc + col;
                    float v = acc[m][n][r2];
                    if (EPI == 1) v += Rp[idx];
                    if (EPI == 2) v = gelu_f(v);
                    Cp[idx] = v;
                }
            }
    } else if constexpr (OUT == 1) {
        _Float16* Cp = (_Float16*)Cv + (long)bz * sC;
#pragma unroll
        for (int m = 0; m < 4; m++)
#pragma unroll
            for (int n = 0; n < 4; n++) {
                int col = ccol0 + n * 16;
#pragma unroll
                for (int r2 = 0; r2 < 4; r2++) {
                    long base = (long)(crow0 + m * 16 + r2) * ldc + col;
                    float v = acc[m][n][r2];
                    if (EPI == 2) v = gelu_f(v);
                    _Float16 hi = (_Float16)v;
                    Cp[base] = hi;
                    Cp[base + loC] = (_Float16)(v - (float)hi);
                }
            }
    } else {
        __shared__ float diag[512];
        float* mc = (float*)Cv + (long)bz * sC;
        for (int t = tid; t < 512; t += 256) diag[t] = 0.f;
        __syncthreads();
#pragma unroll
        for (int m = 0; m < 4; m++)
#pragma unroll
            for (int n = 0; n < 4; n++) {
                int col = ccol0 + n * 16;
#pragma unroll
                for (int r2 = 0; r2 < 4; r2++) {
                    int row = crow0 + m * 16 + r2;
                    atomicAdd(&diag[(row - col) & 511], acc[m][n][r2]);
                }
            }
        __syncthreads();
        for (int t = tid; t < 512; t += 256) {
            float v = diag[t];
            if (v != 0.f) atomicAdd(&mc[t], v);
        }
    }
}

// ------------------------- weight conversion -------------------------------
// W (K x N f32) -> dst (N rows x 2K f16 cat). grid (K/32, N/32)
__global__ __launch_bounds__(256)
void convW2_k(const float* __restrict__ src, _Float16* __restrict__ dst,
              int N, int K)
{
    __shared__ float t[32][33];
    int k0 = blockIdx.x * 32, n0 = blockIdx.y * 32, tid = threadIdx.x;
#pragma unroll
    for (int i = 0; i < 4; i++) {
        int lin = tid + i * 256; int r = lin >> 5, c = lin & 31;
        t[r][c] = src[(long)(k0 + r) * N + n0 + c];
    }
    __syncthreads();
#pragma unroll
    for (int i = 0; i < 4; i++) {
        int lin = tid + i * 256; int n = lin >> 5, k = lin & 31;
        float v = t[k][n];
        _Float16 hi = (_Float16)v;
        long base = (long)(n0 + n) * 2 * K + k0 + k;
        dst[base]     = hi;
        dst[base + K] = (_Float16)(v - (float)hi);
    }
}

// ------------------------- embedding (conv3 + mark + pe + cat) -------------
__global__ __launch_bounds__(256)
void embed_k(const float* __restrict__ x, const float* __restrict__ mark,
             const float* __restrict__ valW, const float* __restrict__ timeW,
             float* __restrict__ out, _Float16* __restrict__ cat)
{
    const int lg = blockIdx.x, dh = blockIdx.y, b = blockIdx.z;
    const int tid = threadIdx.x;
    const int dd = dh * 256 + tid;
    const int l0 = lg * 8;
    __shared__ float xs[10][21];
    __shared__ float mk[8][4];
    if (tid < 210) {
        int r = tid / 21, c = tid % 21;
        int ll = (l0 - 1 + r + 512) & 511;
        xs[r][c] = x[((long)b * 512 + ll) * 21 + c];
    }
    if (tid >= 224 && tid < 256) {
        int t2 = tid - 224, il = t2 >> 2, m = t2 & 3;
        mk[il][m] = mark[((long)b * 512 + l0 + il) * 4 + m];
    }
    __syncthreads();
    float acc[8];
#pragma unroll
    for (int il = 0; il < 8; il++) acc[il] = 0.f;
    for (int t = 0; t < 3; t++)
        for (int c = 0; c < 21; c++) {
            float w = valW[(t * 21 + c) * 512 + dd];
#pragma unroll
            for (int il = 0; il < 8; il++)
                acc[il] = fmaf(xs[il + t][c], w, acc[il]);
        }
    for (int m = 0; m < 4; m++) {
        float w = timeW[m * 512 + dd];
#pragma unroll
        for (int il = 0; il < 8; il++)
            acc[il] = fmaf(mk[il][m], w, acc[il]);
    }
    const float freq = expf((float)(dd & ~1) * (-9.210340371976184f / 512.0f));
#pragma unroll
    for (int il = 0; il < 8; il++) {
        float ang = (float)(l0 + il) * freq;
        float pe = (dd & 1) ? cosf(ang) : sinf(ang);
        float v = acc[il] + pe;
        long row = (long)b * 512 + l0 + il;
        out[row * 512 + dd] = v;
        _Float16 hi = (_Float16)v;
        cat[row * 1024 + dd]       = hi;
        cat[row * 1024 + 512 + dd] = (_Float16)(v - (float)hi);
    }
}

// ------------------------- series decomp (C=21) ----------------------------
__global__ void decomp21_k(const float* __restrict__ x, float* __restrict__ seas,
                           float* __restrict__ trend, int total)
{
    int i = blockIdx.x * 256 + threadIdx.x;
    if (i >= total) return;
    int c = i % 21, l = (i / 21) % 512, b = i / 10752;
    float s = 0.f;
    for (int j = -12; j <= 12; j++) {
        int ll = l + j; ll = ll < 0 ? 0 : (ll > 511 ? 511 : ll);
        s += x[((long)b * 512 + ll) * 21 + c];
    }
    float t = s * (1.f / 25.f);
    trend[i] = t;
    seas[i] = x[i] - t;
}

// ------------------------- fused decomp (D=512, 8-wide, cat) ---------------
// TREND: 0 none, 1 ts += trend, 2 ts = trend.  CAT: write hi/lo cat.
template<int TREND, int CAT>
__global__ __launch_bounds__(256)
void decomp8_k(const float* __restrict__ x, float* __restrict__ out,
               _Float16* __restrict__ cat, float* __restrict__ ts)
{
    long t = (long)blockIdx.x * 256 + threadIdx.x;
    long row = t >> 6; int d8 = (int)(t & 63) * 8;
    int l = (int)(row & 511);
    const float* xb = x + ((row >> 9) << 18);
    float s[8] = {};
    float xo[8];
#pragma unroll
    for (int j = -12; j <= 12; j++) {
        int ll = l + j; ll = ll < 0 ? 0 : (ll > 511 ? 511 : ll);
        const float4* p = (const float4*)(xb + ((long)ll << 9) + d8);
        float4 v0 = p[0], v1 = p[1];
        s[0]+=v0.x; s[1]+=v0.y; s[2]+=v0.z; s[3]+=v0.w;
        s[4]+=v1.x; s[5]+=v1.y; s[6]+=v1.z; s[7]+=v1.w;
        if (j == 0) { xo[0]=v0.x; xo[1]=v0.y; xo[2]=v0.z; xo[3]=v0.w;
                      xo[4]=v1.x; xo[5]=v1.y; xo[6]=v1.z; xo[7]=v1.w; }
    }
    float tr[8], ov[8];
#pragma unroll
    for (int j = 0; j < 8; j++) { tr[j] = s[j] * (1.f/25.f); ov[j] = xo[j] - tr[j]; }
    float4* op = (float4*)(out + row * 512 + d8);
    op[0] = make_float4(ov[0],ov[1],ov[2],ov[3]);
    op[1] = make_float4(ov[4],ov[5],ov[6],ov[7]);
    if (CAT) {
        h8 hi, lo;
#pragma unroll
        for (int j = 0; j < 8; j++) {
            _Float16 h = (_Float16)ov[j];
            hi[j] = h; lo[j] = (_Float16)(ov[j] - (float)h);
        }
        *(h8*)(cat + row * 1024 + d8)       = hi;
        *(h8*)(cat + row * 1024 + 512 + d8) = lo;
    }
    if (TREND) {
        float* tp = ts + row * 512 + d8;
        if (TREND == 1) {
            float4 t0 = *(float4*)tp, t1 = *(float4*)(tp + 4);
            tr[0]+=t0.x; tr[1]+=t0.y; tr[2]+=t0.z; tr[3]+=t0.w;
            tr[4]+=t1.x; tr[5]+=t1.y; tr[6]+=t1.z; tr[7]+=t1.w;
        }
        *(float4*)tp     = make_float4(tr[0],tr[1],tr[2],tr[3]);
        *(float4*)(tp+4) = make_float4(tr[4],tr[5],tr[6],tr[7]);
    }
}

// ------------------------- small prep kernels ------------------------------
__global__ void meanseq_k(const float* __restrict__ x, float* __restrict__ xm, int total)
{
    int i = blockIdx.x * 256 + threadIdx.x;
    if (i >= total) return;
    int c = i % 21, b = i / 21;
    float s = 0.f;
    for (int l = 0; l < 512; l++) s += x[((long)b * 512 + l) * 21 + c];
    xm[i] = s * (1.f / 512.f);
}

__global__ void buildinit_k(const float* __restrict__ seas, const float* __restrict__ trend,
                            const float* __restrict__ xm,
                            float* __restrict__ sinit, float* __restrict__ tinit, int total)
{
    int i = blockIdx.x * 256 + threadIdx.x;
    if (i >= total) return;
    int c = i % 21, l = (i / 21) % 512, b = i / 10752;
    if (l < 256) {
        sinit[i] = seas[((long)b * 512 + 256 + l) * 21 + c];
        tinit[i] = trend[((long)b * 512 + 256 + l) * 21 + c];
    } else {
        sinit[i] = 0.f;
        tinit[i] = xm[b * 21 + c];
    }
}

// ------------------------- top-k (reads mc, then zeroes it) ----------------
__global__ __launch_bounds__(256)
void topk_k(float* __restrict__ mc, int* __restrict__ delays,
            float* __restrict__ wts)
{
    int b = blockIdx.x, tid = threadIdx.x;
    __shared__ float v[512];
    __shared__ float rv[256];
    __shared__ int   ri[256];
    __shared__ float selv[6];
    v[tid]       = mc[b * 512 + tid]       * (1.f / 512.f);
    v[tid + 256] = mc[b * 512 + tid + 256] * (1.f / 512.f);
    mc[b * 512 + tid] = 0.f;
    mc[b * 512 + tid + 256] = 0.f;
    __syncthreads();
    for (int p = 0; p < 6; p++) {
        float bv = v[tid]; int bi = tid;
        float v2 = v[tid + 256];
        if (v2 > bv) { bv = v2; bi = tid + 256; }
        rv[tid] = bv; ri[tid] = bi;
        __syncthreads();
        for (int s = 128; s > 0; s >>= 1) {
            if (tid < s) {
                float ov = rv[tid + s]; int oi = ri[tid + s];
                if (ov > rv[tid] || (ov == rv[tid] && oi < ri[tid])) {
                    rv[tid] = ov; ri[tid] = oi;
                }
            }
            __syncthreads();
        }
        if (tid == 0) { selv[p] = rv[0]; delays[b * 6 + p] = ri[0]; v[ri[0]] = -3.4e38f; }
        __syncthreads();
    }
    if (tid == 0) {
        float mx = selv[0];
        for (int p = 1; p < 6; p++) mx = fmaxf(mx, selv[p]);
        float e[6], sum = 0.f;
        for (int p = 0; p < 6; p++) { e[p] = expf(selv[p] - mx); sum += e[p]; }
        for (int p = 0; p < 6; p++) wts[b * 6 + p] = e[p] / sum;
    }
}

// gather-agg from V cat slice; write cat out (rows x 1024)
__global__ __launch_bounds__(256)
void agg2_k(const _Float16* __restrict__ Vc, int vld, int vhi, int vlo,
            const int* __restrict__ delays, const float* __restrict__ wts,
            _Float16* __restrict__ out)
{
    long t = (long)blockIdx.x * 256 + threadIdx.x;
    int dc = (int)(t & 63);
    long row = t >> 6;
    int l = (int)(row & 511), b = (int)(row >> 9);
    float s[8] = {};
#pragma unroll
    for (int k = 0; k < 6; k++) {
        int dl = delays[b * 6 + k];
        float wv = wts[b * 6 + k];
        long sr = ((long)b * 512 + ((l + dl) & 511)) * vld + dc * 8;
        h8 hi8 = *(const h8*)(Vc + sr + vhi);
        h8 lo8 = *(const h8*)(Vc + sr + vlo);
#pragma unroll
        for (int j = 0; j < 8; j++)
            s[j] = fmaf(wv, (float)hi8[j] + (float)lo8[j], s[j]);
    }
    h8 ho, lo;
#pragma unroll
    for (int j = 0; j < 8; j++) {
        _Float16 h = (_Float16)s[j];
        ho[j] = h; lo[j] = (_Float16)(s[j] - (float)h);
    }
    long ob = row * 1024 + dc * 8;
    *(h8*)(out + ob)       = ho;
    *(h8*)(out + ob + 512) = lo;
}

// ------------------------- seasonal layernorm ------------------------------
__global__ __launch_bounds__(256)
void ln_k(const float* __restrict__ x, const float* __restrict__ g,
          const float* __restrict__ be, float* __restrict__ out)
{
    int row = blockIdx.x, tid = threadIdx.x;
    const float* xr = x + ((long)row << 9);
    float v0 = xr[tid], v1 = xr[tid + 256];
    __shared__ float rs[256];
    rs[tid] = v0 + v1; __syncthreads();
    for (int s = 128; s > 0; s >>= 1) { if (tid < s) rs[tid] += rs[tid + s]; __syncthreads(); }
    float mu = rs[0] * (1.f / 512.f);
    __syncthreads();
    float d0 = v0 - mu, d1 = v1 - mu;
    rs[tid] = d0 * d0 + d1 * d1; __syncthreads();
    for (int s = 128; s > 0; s >>= 1) { if (tid < s) rs[tid] += rs[tid + s]; __syncthreads(); }
    float rstd = 1.0f / sqrtf(rs[0] * (1.f / 512.f) + 1e-5f);
    out[((long)row << 9) + tid]       = d0 * rstd * g[tid] + be[tid];
    out[((long)row << 9) + tid + 256] = d1 * rstd * g[tid + 256] + be[tid + 256];
}

__global__ void colpart_k(const float* __restrict__ x, float* __restrict__ cp)
{
    int d = blockIdx.x * 256 + threadIdx.x;   // grid (2, 8, Bc)
    int ch = blockIdx.y, b = blockIdx.z;
    const float* xb = x + ((long)b << 18);
    float s = 0.f;
    for (int l = ch * 64; l < ch * 64 + 64; l++) s += xb[((long)l << 9) + d];
    cp[((long)(b * 8 + ch) << 9) + d] = s;
}

// CAT=1: write hi/lo cat only; CAT=0: write f32 (in-place safe)
template<int CAT>
__global__ __launch_bounds__(256)
void subcol8_k(const float* __restrict__ x, const float* __restrict__ cp,
               float* __restrict__ out, _Float16* __restrict__ cat)
{
    long t = (long)blockIdx.x * 256 + threadIdx.x;
    long row = t >> 6; int d8 = (int)(t & 63) * 8;
    int b = (int)(row >> 9);
    float m[8] = {};
#pragma unroll
    for (int ch = 0; ch < 8; ch++) {
        const float4* c4 = (const float4*)(cp + ((long)(b * 8 + ch) << 9) + d8);
        float4 c0 = c4[0], c1 = c4[1];
        m[0]+=c0.x; m[1]+=c0.y; m[2]+=c0.z; m[3]+=c0.w;
        m[4]+=c1.x; m[5]+=c1.y; m[6]+=c1.z; m[7]+=c1.w;
    }
    const float4* xp = (const float4*)(x + row * 512 + d8);
    float4 x0 = xp[0], x1 = xp[1];
    float v[8] = {x0.x,x0.y,x0.z,x0.w,x1.x,x1.y,x1.z,x1.w};
#pragma unroll
    for (int j = 0; j < 8; j++) v[j] -= m[j] * (1.f / 512.f);
    if (CAT) {
        h8 hi, lo;
#pragma unroll
        for (int j = 0; j < 8; j++) {
            _Float16 h = (_Float16)v[j];
            hi[j] = h; lo[j] = (_Float16)(v[j] - (float)h);
        }
        *(h8*)(cat + row * 1024 + d8)       = hi;
        *(h8*)(cat + row * 1024 + 512 + d8) = lo;
    } else {
        float4* op = (float4*)(out + row * 512 + d8);
        op[0] = make_float4(v[0],v[1],v[2],v[3]);
        op[1] = make_float4(v[4],v[5],v[6],v[7]);
    }
}

// ------------------------- trend conv (skinny GEMM) ------------------------
__global__ __launch_bounds__(256)
void tsgemm2_k(const float* __restrict__ TS, const float* __restrict__ W,
               float* __restrict__ H)
{
    __shared__ float As[64][33];
    __shared__ float Ws[32][64];
    const int row0 = blockIdx.x * 64;
    const int tid = threadIdx.x;
    const int row = tid & 63, qq = tid >> 6;
    float acc[16] = {};
    for (int k0 = 0; k0 < 512; k0 += 32) {
#pragma unroll
        for (int i = 0; i < 8; i++) {
            int lin = tid + i * 256; int r = lin >> 5, c = lin & 31;
            As[r][c] = TS[(long)(row0 + r) * 512 + k0 + c];
        }
#pragma unroll
        for (int i = 0; i < 8; i++) {
            int lin = tid + i * 256; int kk = lin >> 6, j = lin & 63;
            Ws[kk][j] = (j < 63) ? W[(long)(j / 21) * 10752 + (long)(k0 + kk) * 21 + (j % 21)] : 0.f;
        }
        __syncthreads();
        for (int kk = 0; kk < 32; ++kk) {
            float a = As[row][kk];
            const float4* w4 = (const float4*)&Ws[kk][qq * 16];
#pragma unroll
            for (int t4 = 0; t4 < 4; ++t4) {
                float4 wv = w4[t4];
                acc[t4*4+0] = fmaf(a, wv.x, acc[t4*4+0]);
                acc[t4*4+1] = fmaf(a, wv.y, acc[t4*4+1]);
                acc[t4*4+2] = fmaf(a, wv.z, acc[t4*4+2]);
                acc[t4*4+3] = fmaf(a, wv.w, acc[t4*4+3]);
            }
        }
        __syncthreads();
    }
    float* out = H + (long)(row0 + row) * 64 + qq * 16;
#pragma unroll
    for (int j = 0; j < 16; j++) out[j] = acc[j];
}

__global__ void shiftadd_k(const float* __restrict__ H, const float* __restrict__ tinit,
                           float* __restrict__ tf, int total)
{
    int i = blockIdx.x * 256 + threadIdx.x;
    if (i >= total) return;
    int c = i % 21, l = (i / 21) % 512, b = i / 10752;
    long r = (long)b * 512;
    tf[i] = tinit[i]
          + H[(r + ((l + 511) & 511)) * 64 + c]
          + H[(r + l) * 64 + 21 + c]
          + H[(r + ((l + 1) & 511)) * 64 + 42 + c];
}

__global__ void proj_k(const float* __restrict__ x, const float* __restrict__ pw,
                       const float* __restrict__ pb, const float* __restrict__ trend,
                       float* __restrict__ out, int total)
{
    int i = blockIdx.x * 256 + threadIdx.x;
    if (i >= total) return;
    int c = i % 21, l = (i / 21) % 256 + 256, b = i / 5376;
    const float* xr = x + ((long)(b * 512 + l) << 9);
    float s = 0.f;
    for (int d = 0; d < 512; d++) s = fmaf(xr[d], pw[d * 21 + c], s);
    out[i] = s + pb[c] + trend[((long)b * 512 + l) * 21 + c];
}

// ---------------------------------------------------------------------------
// mode: 0 = OUT1 cat, 2 = OUT1 gelu-cat, 10 = OUT0 +residual f32, 20 = Scorr
static void hgemm(int mode,
                  const _Float16* A, int lda, int loA,
                  const _Float16* B, int ldb, int loB,
                  const float* R, void* C, int ldc, int loC,
                  int K, int M, int N, int batch,
                  long sA, long sB, long sC, hipStream_t st)
{
    dim3 g(N / 128, M / 128, batch), blk(256);
    switch (mode) {
    case 0:  hgemm_k<0,1><<<g,blk,0,st>>>(A,lda,loA,B,ldb,loB,R,C,ldc,loC,K,sA,sB,sC); break;
    case 2:  hgemm_k<2,1><<<g,blk,0,st>>>(A,lda,loA,B,ldb,loB,R,C,ldc,loC,K,sA,sB,sC); break;
    case 10: hgemm_k<1,0><<<g,blk,0,st>>>(A,lda,loA,B,ldb,loB,R,C,ldc,loC,K,sA,sB,sC); break;
    default: hgemm_k<0,2><<<g,blk,0,st>>>(A,lda,loA,B,ldb,loB,R,C,ldc,loC,K,sA,sB,sC); break;
    }
}

extern "C" void kernel_launch(void* const* d_in, const int* in_sizes, int n_in,
                              void* d_out, int out_size, void* d_ws, size_t ws_size,
                              hipStream_t stream)
{
    const float* x_enc    = (const float*)d_in[0];
    const float* xm_enc   = (const float*)d_in[1];
    const float* xm_dec   = (const float*)d_in[3];
    const float* enc_valW = (const float*)d_in[4];
    const float* enc_timeW= (const float*)d_in[5];
    const float* enc_Wq   = (const float*)d_in[6];
    const float* enc_Wk   = (const float*)d_in[7];
    const float* enc_Wv   = (const float*)d_in[8];
    const float* enc_Wo   = (const float*)d_in[9];
    const float* enc_W1   = (const float*)d_in[10];
    const float* enc_W2   = (const float*)d_in[11];
    const float* enc_g    = (const float*)d_in[12];
    const float* enc_b    = (const float*)d_in[13];
    const float* dec_valW = (const float*)d_in[14];
    const float* dec_timeW= (const float*)d_in[15];
    const float* sWq = (const float*)d_in[16];
    const float* sWk = (const float*)d_in[17];
    const float* sWv = (const float*)d_in[18];
    const float* sWo = (const float*)d_in[19];
    const float* cWq = (const float*)d_in[20];
    const float* cWk = (const float*)d_in[21];
    const float* cWv = (const float*)d_in[22];
    const float* cWo = (const float*)d_in[23];
    const float* dW1 = (const float*)d_in[24];
    const float* dW2 = (const float*)d_in[25];
    const float* dtW = (const float*)d_in[26];
    const float* dec_g = (const float*)d_in[27];
    const float* dec_b = (const float*)d_in[28];
    const float* projW = (const float*)d_in[29];
    const float* projB = (const float*)d_in[30];

    // ---- batch-chunk sizing (deterministic) ----
    const size_t W_BYTES = 41943040;
    const size_t perB = 11010048;
    int Bc = 32;
    while (Bc > 1 && W_BYTES + (size_t)Bc * perB + (4u << 20) > ws_size) Bc >>= 1;

    char* wp = (char*)d_ws;
    auto alloc = [&](size_t bytes) { char* p = wp; wp += (bytes + 255) & ~(size_t)255; return p; };

    _Float16* encQKVC = (_Float16*)alloc(2 * 1572864 * 2);
    _Float16* encWoC  = (_Float16*)alloc(2 * 524288 * 2);
    _Float16* encW1C  = (_Float16*)alloc(2 * 2097152 * 2);
    _Float16* encW2C  = (_Float16*)alloc(2 * 2097152 * 2);
    _Float16* dsQKVC  = (_Float16*)alloc(1572864 * 2);
    _Float16* dsWoC   = (_Float16*)alloc(524288 * 2);
    _Float16* dcWqC   = (_Float16*)alloc(524288 * 2);
    _Float16* dcWkvC  = (_Float16*)alloc(1048576 * 2);
    _Float16* dcWoC   = (_Float16*)alloc(524288 * 2);
    _Float16* dW1C    = (_Float16*)alloc(2097152 * 2);
    _Float16* dW2C    = (_Float16*)alloc(2097152 * 2);

    const long ROWS = (long)Bc * 512;
    const long NBc  = ROWS * 512;
    float*    X      = (float*)alloc(NBc * 4);
    float*    O      = (float*)alloc(NBc * 4);
    float*    TS     = (float*)alloc(NBc * 4);
    _Float16* cX     = (_Float16*)alloc(ROWS * 1024 * 2);
    _Float16* cAgg   = (_Float16*)alloc(ROWS * 1024 * 2);
    _Float16* ENCcat = (_Float16*)alloc(ROWS * 1024 * 2);
    _Float16* bigcat = (_Float16*)alloc(ROWS * 4096 * 2);
    float* H63     = (float*)alloc((long)Bc * 32768 * 4);
    float* seas_s  = (float*)alloc((long)Bc * 10752 * 4);
    float* trend_t = (float*)alloc((long)Bc * 10752 * 4);
    float* sinit   = (float*)alloc((long)Bc * 10752 * 4);
    float* tinit   = (float*)alloc((long)Bc * 10752 * 4);
    float* tfinal  = (float*)alloc((long)Bc * 10752 * 4);
    float* xmean   = (float*)alloc((long)Bc * 21 * 4);
    float* mc      = (float*)alloc((long)Bc * 512 * 4);
    float* cp      = (float*)alloc((long)Bc * 4096 * 4);
    float* wts     = (float*)alloc((long)Bc * 6 * 4);
    int*   delays  = (int*)alloc((long)Bc * 6 * 4);

    // ---- weight conversion ----
    dim3 cb(256);
    for (int L = 0; L < 2; L++) {
        _Float16* q = encQKVC + (long)L * 1572864;
        convW2_k<<<dim3(16,16), cb, 0, stream>>>(enc_Wq + (long)L*262144, q,              512, 512);
        convW2_k<<<dim3(16,16), cb, 0, stream>>>(enc_Wk + (long)L*262144, q + 512*1024,   512, 512);
        convW2_k<<<dim3(16,16), cb, 0, stream>>>(enc_Wv + (long)L*262144, q + 1024*1024,  512, 512);
        convW2_k<<<dim3(16,16), cb, 0, stream>>>(enc_Wo + (long)L*262144, encWoC + (long)L*524288, 512, 512);
        convW2_k<<<dim3(16,64), cb, 0, stream>>>(enc_W1 + (long)L*1048576, encW1C + (long)L*2097152, 2048, 512);
        convW2_k<<<dim3(64,16), cb, 0, stream>>>(enc_W2 + (long)L*1048576, encW2C + (long)L*2097152, 512, 2048);
    }
    convW2_k<<<dim3(16,16), cb, 0, stream>>>(sWq, dsQKVC,              512, 512);
    convW2_k<<<dim3(16,16), cb, 0, stream>>>(sWk, dsQKVC + 512*1024,   512, 512);
    convW2_k<<<dim3(16,16), cb, 0, stream>>>(sWv, dsQKVC + 1024*1024,  512, 512);
    convW2_k<<<dim3(16,16), cb, 0, stream>>>(sWo, dsWoC, 512, 512);
    convW2_k<<<dim3(16,16), cb, 0, stream>>>(cWq, dcWqC, 512, 512);
    convW2_k<<<dim3(16,16), cb, 0, stream>>>(cWk, dcWkvC,             512, 512);
    convW2_k<<<dim3(16,16), cb, 0, stream>>>(cWv, dcWkvC + 512*1024,  512, 512);
    convW2_k<<<dim3(16,16), cb, 0, stream>>>(cWo, dcWoC, 512, 512);
    convW2_k<<<dim3(16,64), cb, 0, stream>>>(dW1, dW1C, 2048, 512);
    convW2_k<<<dim3(64,16), cb, 0, stream>>>(dW2, dW2C, 512, 2048);

    const int M = (int)ROWS;
    const int t21 = Bc * 10752;
    const int gRows = Bc * 128;              // 8-wide elementwise grids
    const long sSA = 512 * 4096;             // per-batch row stride in bigcat
    const long sCA = 512 * 1024;             // per-batch row stride in cAgg/cX

    // zero mc once; topk self-cleans afterwards
    zero_k<<<(Bc*512 + 255)/256, 256, 0, stream>>>(mc, Bc*512);

    // self-attention on stream (f32 Xin + cat cXin): O = Xin + attn
    auto attn_self = [&](float* Xin, float* Cout, const _Float16* cXin,
                         const _Float16* WqkvC, const _Float16* WoC) {
        hgemm(0, cXin,1024,512, WqkvC,1024,512, nullptr, bigcat, 4096, 1536,
              512, M, 1536, 1, 0,0,0, stream);                         // [Q|K|V]
        hgemm(20, bigcat,4096,1536, bigcat+512,4096,1536, nullptr, mc, 0, 0,
              512, 512, 512, Bc, sSA, sSA, 512, stream);               // Scorr->mc
        topk_k<<<Bc, 256, 0, stream>>>(mc, delays, wts);
        agg2_k<<<gRows, 256, 0, stream>>>(bigcat, 4096, 1024, 2560, delays, wts, cAgg);
        hgemm(10, cAgg,1024,512, WoC,1024,512, Xin, Cout, 512, 0,
              512, M, 512, 1, 0,0,0, stream);                          // Cout = Xin + agg@Wo
    };
    // ffn: Cout = Xin + gelu(Xin@W1)@W2  (hidden cat in bigcat)
    auto ffn = [&](float* Xin, float* Cout, const _Float16* cXin,
                   const _Float16* W1C, const _Float16* W2C) {
        hgemm(2, cXin,1024,512, W1C,1024,512, nullptr, bigcat, 4096, 2048,
              512, M, 2048, 1, 0,0,0, stream);
        hgemm(10, bigcat,4096,2048, W2C,4096,2048, Xin, Cout, 512, 0,
              2048, M, 512, 1, 0,0,0, stream);
    };

    for (int b0 = 0; b0 < 32; b0 += Bc) {
        const float* xe  = x_enc  + (long)b0 * 10752;
        const float* mke = xm_enc + (long)b0 * 2048;
        const float* mkd = xm_dec + (long)b0 * 2048;
        float* outp = (float*)d_out + (long)b0 * 5376;

        meanseq_k  <<<(Bc*21 + 255)/256, 256, 0, stream>>>(xe, xmean, Bc*21);
        decomp21_k <<<t21/256, 256, 0, stream>>>(xe, seas_s, trend_t, t21);
        buildinit_k<<<t21/256, 256, 0, stream>>>(seas_s, trend_t, xmean, sinit, tinit, t21);

        // ---------------- encoder ----------------
        embed_k<<<dim3(64,2,Bc), 256, 0, stream>>>(xe, mke, enc_valW, enc_timeW, X, cX);
        for (int L = 0; L < 2; L++) {
            attn_self(X, O, cX, encQKVC + (long)L*1572864, encWoC + (long)L*524288);
            decomp8_k<0,1><<<gRows, 256, 0, stream>>>(O, X, cX, nullptr);
            ffn(X, O, cX, encW1C + (long)L*2097152, encW2C + (long)L*2097152);
            decomp8_k<0,1><<<gRows, 256, 0, stream>>>(O, X, cX, nullptr);
        }
        ln_k      <<<Bc*512, 256, 0, stream>>>(X, enc_g, enc_b, O);
        colpart_k <<<dim3(2,8,Bc), 256, 0, stream>>>(O, cp);
        subcol8_k<1><<<gRows, 256, 0, stream>>>(O, cp, nullptr, ENCcat);

        // ---------------- decoder ----------------
        embed_k<<<dim3(64,2,Bc), 256, 0, stream>>>(sinit, mkd, dec_valW, dec_timeW, X, cX);

        // self attention
        attn_self(X, O, cX, dsQKVC, dsWoC);
        decomp8_k<2,1><<<gRows, 256, 0, stream>>>(O, X, cX, TS);     // TS = trend

        // cross attention: Q from cX, K/V from ENCcat
        hgemm(0, cX,1024,512, dcWqC,1024,512, nullptr, cAgg, 1024, 512,
              512, M, 512, 1, 0,0,0, stream);                        // Qcat
        hgemm(0, ENCcat,1024,512, dcWkvC,1024,512, nullptr, bigcat, 4096, 1024,
              512, M, 1024, 1, 0,0,0, stream);                       // [K|V]cat
        hgemm(20, cAgg,1024,512, bigcat,4096,1024, nullptr, mc, 0, 0,
              512, 512, 512, Bc, sCA, sSA, 512, stream);
        topk_k<<<Bc, 256, 0, stream>>>(mc, delays, wts);
        agg2_k<<<gRows, 256, 0, stream>>>(bigcat, 4096, 512, 1536, delays, wts, cAgg);
        hgemm(10, cAgg,1024,512, dcWoC,1024,512, X, O, 512, 0,
              512, M, 512, 1, 0,0,0, stream);
        decomp8_k<1,1><<<gRows, 256, 0, stream>>>(O, X, cX, TS);     // TS += trend

        // ffn
        ffn(X, O, cX, dW1C, dW2C);
        decomp8_k<1,0><<<gRows, 256, 0, stream>>>(O, X, nullptr, TS);

        tsgemm2_k <<<Bc*8, 256, 0, stream>>>(TS, dtW, H63);
        shiftadd_k<<<(t21+255)/256, 256, 0, stream>>>(H63, tinit, tfinal, t21);
        ln_k      <<<Bc*512, 256, 0, stream>>>(X, dec_g, dec_b, O);
        colpart_k <<<dim3(2,8,Bc), 256, 0, stream>>>(O, cp);
        subcol8_k<0><<<gRows, 256, 0, stream>>>(O, cp, O, nullptr);
        proj_k    <<<(Bc*5376+255)/256, 256, 0, stream>>>(O, projW, projB, tfinal, outp, Bc*5376);
    }
}

// Round 8
// 3516.964 us; speedup vs baseline: 2.4355x; 1.0321x over previous
//
#include <hip/hip_runtime.h>

// ---------------------------------------------------------------------------
// Autoformer forward, MI355X. Round 8: round-7 structure + bigcat overflow fix
// (FFN hidden needs ROWS x 4096 halfs) + normal-range Wqk precompute scaling.
// GEMM numerics: C = Ah*Bh + Ah*Bl + Al*Bh, operands rows x 2K f16 [hi|lo].
// ---------------------------------------------------------------------------

typedef _Float16 h8 __attribute__((ext_vector_type(8)));
typedef float f32x4 __attribute__((ext_vector_type(4)));

__device__ __forceinline__ float gelu_f(float x){
    return 0.5f * x * (1.0f + erff(x * 0.70710678118654752f));
}

__device__ __forceinline__ void gl_lds(const _Float16* gp, _Float16* lp) {
    __builtin_amdgcn_global_load_lds(
        (const __attribute__((address_space(1))) void*)gp,
        (__attribute__((address_space(3))) void*)lp, 16, 0, 0);
}

__global__ void zero_k(float* __restrict__ p, long n){
    long i = (long)blockIdx.x * 256 + threadIdx.x;
    if (i < n) p[i] = 0.f;
}

// ------------------------------ MFMA GEMM ----------------------------------
// A: M x 2K [hi|lo] (lda halfs, lo at +loA). B: N x 2K (ldb, +loB).
// 3 phases x (K/64): (Ah,Bh),(Ah,Bl),(Al,Bh). f32 accum.
// OUT=0: f32 C (ldc floats); EPI 0 plain, 1 +R residual.
// OUT=1: f16 cat C (hi at row*ldc+col, lo at +loC); EPI 0 plain, 2 gelu.
// OUT=2: diag reduce: atomicAdd mc[bz*sC + (row-col)&511].
template<int EPI, int OUT>
__global__ __launch_bounds__(256)
void hgemm_k(const _Float16* __restrict__ A, int lda, int loA,
             const _Float16* __restrict__ Bm, int ldb, int loB,
             const float* __restrict__ R, void* __restrict__ Cv,
             int ldc, int loC, int K,
             long sA, long sB, long sC)
{
    __shared__ _Float16 As[128 * 64];
    __shared__ _Float16 Bs[128 * 64];
    const int bz = blockIdx.z;
    const int tid = threadIdx.x, lane = tid & 63, w = tid >> 6;
    const int wr = w >> 1, wc = w & 1;
    const _Float16* Ap = A + bz * sA + (long)(blockIdx.y * 128) * lda;
    const _Float16* Bp = Bm + bz * sB + (long)(blockIdx.x * 128) * ldb;

    const int swz = ((lane & 7) ^ ((lane >> 3) & 7)) * 8;
    const int rsub = w * 32 + (lane >> 3);
    const _Float16* ApT = Ap + (long)rsub * lda + swz;
    const _Float16* BpT = Bp + (long)rsub * ldb + swz;
    _Float16* AsT = As + w * 2048;
    _Float16* BsT = Bs + w * 2048;

    const int tpp = K >> 6;
    const int nkt = tpp * 3;
    f32x4 acc[4][4] = {};

    int p = 0, q = 0;
    for (int kt = 0; kt < nkt; ++kt) {
        const int aoff = q * 64 + (p == 2 ? loA : 0);
        const int boff = q * 64 + (p == 1 ? loB : 0);
        __syncthreads();
#pragma unroll
        for (int i = 0; i < 4; i++) {
            gl_lds(ApT + (long)i * 8 * lda + aoff, AsT + i * 512);
            gl_lds(BpT + (long)i * 8 * ldb + boff, BsT + i * 512);
        }
        __syncthreads();
#pragma unroll
        for (int kk = 0; kk < 2; ++kk) {
            h8 af[4], bf[4];
            const int ks = kk * 4 + (lane >> 4);
#pragma unroll
            for (int m = 0; m < 4; m++) {
                int rowa = wr * 64 + m * 16 + (lane & 15);
                af[m] = *(const h8*)(As + rowa * 64 + ((ks ^ (rowa & 7)) * 8));
                int rowb = wc * 64 + m * 16 + (lane & 15);
                bf[m] = *(const h8*)(Bs + rowb * 64 + ((ks ^ (rowb & 7)) * 8));
            }
#pragma unroll
            for (int m = 0; m < 4; m++)
#pragma unroll
                for (int n = 0; n < 4; n++)
                    acc[m][n] = __builtin_amdgcn_mfma_f32_16x16x32_f16(af[m], bf[n], acc[m][n], 0, 0, 0);
        }
        if (++q == tpp) { q = 0; ++p; }
    }

    const int crow0 = blockIdx.y * 128 + wr * 64 + (lane >> 4) * 4;
    const int ccol0 = blockIdx.x * 128 + wc * 64 + (lane & 15);
    if constexpr (OUT == 0) {
        float* Cp = (float*)Cv + (long)bz * sC;
        const float* Rp = (EPI == 1) ? (R + (long)bz * sC) : nullptr;
#pragma unroll
        for (int m = 0; m < 4; m++)
#pragma unroll
            for (int n = 0; n < 4; n++) {
                int col = ccol0 + n * 16;
#pragma unroll
                for (int r2 = 0; r2 < 4; r2++) {
                    long idx = (long)(crow0 + m * 16 + r2) * ldc + col;
                    float v = acc[m][n][r2];
                    if (EPI == 1) v += Rp[idx];
                    Cp[idx] = v;
                }
            }
    } else if constexpr (OUT == 1) {
        _Float16* Cp = (_Float16*)Cv + (long)bz * sC;
#pragma unroll
        for (int m = 0; m < 4; m++)
#pragma unroll
            for (int n = 0; n < 4; n++) {
                int col = ccol0 + n * 16;
#pragma unroll
                for (int r2 = 0; r2 < 4; r2++) {
                    long base = (long)(crow0 + m * 16 + r2) * ldc + col;
                    float v = acc[m][n][r2];
                    if (EPI == 2) v = gelu_f(v);
                    _Float16 hi = (_Float16)v;
                    Cp[base] = hi;
                    Cp[base + loC] = (_Float16)(v - (float)hi);
                }
            }
    } else {
        __shared__ float diag[512];
        float* mc = (float*)Cv + (long)bz * sC;
        for (int t = tid; t < 512; t += 256) diag[t] = 0.f;
        __syncthreads();
#pragma unroll
        for (int m = 0; m < 4; m++)
#pragma unroll
            for (int n = 0; n < 4; n++) {
                int col = ccol0 + n * 16;
#pragma unroll
                for (int r2 = 0; r2 < 4; r2++) {
                    int row = crow0 + m * 16 + r2;
                    atomicAdd(&diag[(row - col) & 511], acc[m][n][r2]);
                }
            }
        __syncthreads();
        for (int t = tid; t < 512; t += 256) {
            float v = diag[t];
            if (v != 0.f) atomicAdd(&mc[t], v);
        }
    }
}

// ------------------------- split / weight conversion -----------------------
// rows x 512 f32 -> rows x 1024 cat [hi|lo], scaled. one thread per 8 elems.
__global__ __launch_bounds__(256)
void split2_k(const float* __restrict__ x, _Float16* __restrict__ y, float scale)
{
    long t = (long)blockIdx.x * 256 + threadIdx.x;
    long row = t >> 6; int kc = (int)(t & 63) * 8;
    const float4 v0 = *(const float4*)(x + row * 512 + kc);
    const float4 v1 = *(const float4*)(x + row * 512 + kc + 4);
    float vv[8] = {v0.x,v0.y,v0.z,v0.w,v1.x,v1.y,v1.z,v1.w};
    h8 hi, lo;
#pragma unroll
    for (int j = 0; j < 8; j++) {
        float s = vv[j] * scale;
        _Float16 h = (_Float16)s;
        hi[j] = h; lo[j] = (_Float16)(s - (float)h);
    }
    *(h8*)(y + row * 1024 + kc)       = hi;
    *(h8*)(y + row * 1024 + 512 + kc) = lo;
}

// W (K x N f32) -> dst (N rows x 2K f16 cat). grid (K/32, N/32)
__global__ __launch_bounds__(256)
void convW2_k(const float* __restrict__ src, _Float16* __restrict__ dst,
              int N, int K)
{
    __shared__ float t[32][33];
    int k0 = blockIdx.x * 32, n0 = blockIdx.y * 32, tid = threadIdx.x;
#pragma unroll
    for (int i = 0; i < 4; i++) {
        int lin = tid + i * 256; int r = lin >> 5, c = lin & 31;
        t[r][c] = src[(long)(k0 + r) * N + n0 + c];
    }
    __syncthreads();
#pragma unroll
    for (int i = 0; i < 4; i++) {
        int lin = tid + i * 256; int n = lin >> 5, k = lin & 31;
        float v = t[k][n];
        _Float16 hi = (_Float16)v;
        long base = (long)(n0 + n) * 2 * K + k0 + k;
        dst[base]     = hi;
        dst[base + K] = (_Float16)(v - (float)hi);
    }
}

// dtW (3 x 512 x 21) -> 128 rows x 1024 cat (row j = t*21+c, zero-padded)
__global__ void convW63_k(const float* __restrict__ W, _Float16* __restrict__ dst)
{
    int i = blockIdx.x * 256 + threadIdx.x;   // 65536
    int k = i & 511, j = i >> 9;
    float v = (j < 63) ? W[(long)(j / 21) * 10752 + (long)k * 21 + (j % 21)] : 0.f;
    _Float16 hi = (_Float16)v;
    dst[(long)j * 1024 + k]       = hi;
    dst[(long)j * 1024 + 512 + k] = (_Float16)(v - (float)hi);
}

// ------------------------- embedding (conv3 + mark + pe + cat) -------------
__global__ __launch_bounds__(256)
void embed_k(const float* __restrict__ x, const float* __restrict__ mark,
             const float* __restrict__ valW, const float* __restrict__ timeW,
             float* __restrict__ out, _Float16* __restrict__ cat)
{
    const int lg = blockIdx.x, dh = blockIdx.y, b = blockIdx.z;
    const int tid = threadIdx.x;
    const int dd = dh * 256 + tid;
    const int l0 = lg * 8;
    __shared__ float xs[10][21];
    __shared__ float mk[8][4];
    if (tid < 210) {
        int r = tid / 21, c = tid % 21;
        int ll = (l0 - 1 + r + 512) & 511;
        xs[r][c] = x[((long)b * 512 + ll) * 21 + c];
    }
    if (tid >= 224 && tid < 256) {
        int t2 = tid - 224, il = t2 >> 2, m = t2 & 3;
        mk[il][m] = mark[((long)b * 512 + l0 + il) * 4 + m];
    }
    __syncthreads();
    float acc[8];
#pragma unroll
    for (int il = 0; il < 8; il++) acc[il] = 0.f;
    for (int t = 0; t < 3; t++)
        for (int c = 0; c < 21; c++) {
            float w = valW[(t * 21 + c) * 512 + dd];
#pragma unroll
            for (int il = 0; il < 8; il++)
                acc[il] = fmaf(xs[il + t][c], w, acc[il]);
        }
    for (int m = 0; m < 4; m++) {
        float w = timeW[m * 512 + dd];
#pragma unroll
        for (int il = 0; il < 8; il++)
            acc[il] = fmaf(mk[il][m], w, acc[il]);
    }
    const float freq = expf((float)(dd & ~1) * (-9.210340371976184f / 512.0f));
#pragma unroll
    for (int il = 0; il < 8; il++) {
        float ang = (float)(l0 + il) * freq;
        float pe = (dd & 1) ? cosf(ang) : sinf(ang);
        float v = acc[il] + pe;
        long row = (long)b * 512 + l0 + il;
        out[row * 512 + dd] = v;
        _Float16 hi = (_Float16)v;
        cat[row * 1024 + dd]       = hi;
        cat[row * 1024 + 512 + dd] = (_Float16)(v - (float)hi);
    }
}

// ------------------------- fused decomp (D=512, 8-wide) --------------------
// TREND: 0 none, 1 TSc += trend (cat), 2 TSc = trend (cat). CAT: seasonal cat.
template<int TREND, int CAT>
__global__ __launch_bounds__(256)
void decomp8_k(const float* __restrict__ x, float* __restrict__ out,
               _Float16* __restrict__ cat, _Float16* __restrict__ tsc)
{
    long t = (long)blockIdx.x * 256 + threadIdx.x;
    long row = t >> 6; int d8 = (int)(t & 63) * 8;
    int l = (int)(row & 511);
    const float* xb = x + ((row >> 9) << 18);
    float s[8] = {};
    float xo[8];
#pragma unroll
    for (int j = -12; j <= 12; j++) {
        int ll = l + j; ll = ll < 0 ? 0 : (ll > 511 ? 511 : ll);
        const float4* p = (const float4*)(xb + ((long)ll << 9) + d8);
        float4 v0 = p[0], v1 = p[1];
        s[0]+=v0.x; s[1]+=v0.y; s[2]+=v0.z; s[3]+=v0.w;
        s[4]+=v1.x; s[5]+=v1.y; s[6]+=v1.z; s[7]+=v1.w;
        if (j == 0) { xo[0]=v0.x; xo[1]=v0.y; xo[2]=v0.z; xo[3]=v0.w;
                      xo[4]=v1.x; xo[5]=v1.y; xo[6]=v1.z; xo[7]=v1.w; }
    }
    float tr[8], ov[8];
#pragma unroll
    for (int j = 0; j < 8; j++) { tr[j] = s[j] * (1.f/25.f); ov[j] = xo[j] - tr[j]; }
    float4* op = (float4*)(out + row * 512 + d8);
    op[0] = make_float4(ov[0],ov[1],ov[2],ov[3]);
    op[1] = make_float4(ov[4],ov[5],ov[6],ov[7]);
    if (CAT) {
        h8 hi, lo;
#pragma unroll
        for (int j = 0; j < 8; j++) {
            _Float16 h = (_Float16)ov[j];
            hi[j] = h; lo[j] = (_Float16)(ov[j] - (float)h);
        }
        *(h8*)(cat + row * 1024 + d8)       = hi;
        *(h8*)(cat + row * 1024 + 512 + d8) = lo;
    }
    if (TREND) {
        _Float16* tp = tsc + row * 1024 + d8;
        if (TREND == 1) {
            h8 th = *(h8*)tp, tl = *(h8*)(tp + 512);
#pragma unroll
            for (int j = 0; j < 8; j++) tr[j] += (float)th[j] + (float)tl[j];
        }
        h8 th2, tl2;
#pragma unroll
        for (int j = 0; j < 8; j++) {
            _Float16 h = (_Float16)tr[j];
            th2[j] = h; tl2[j] = (_Float16)(tr[j] - (float)h);
        }
        *(h8*)tp         = th2;
        *(h8*)(tp + 512) = tl2;
    }
}

// ------------------------- prep (mean + decomp tail + inits) ---------------
__global__ void meanseq_k(const float* __restrict__ x, float* __restrict__ xm, int total)
{
    int i = blockIdx.x * 256 + threadIdx.x;
    if (i >= total) return;
    int c = i % 21, b = i / 21;
    float s = 0.f;
    for (int l = 0; l < 512; l++) s += x[((long)b * 512 + l) * 21 + c];
    xm[i] = s * (1.f / 512.f);
}

__global__ void prep_k(const float* __restrict__ x, const float* __restrict__ xm,
                       float* __restrict__ sinit, float* __restrict__ tinit, int total)
{
    int i = blockIdx.x * 256 + threadIdx.x;
    if (i >= total) return;
    int c = i % 21, l = (i / 21) % 512, b = i / 10752;
    if (l < 256) {
        int lc = 256 + l;
        float s = 0.f;
        for (int j = -12; j <= 12; j++) {
            int ll = lc + j; ll = ll > 511 ? 511 : ll;
            s += x[((long)b * 512 + ll) * 21 + c];
        }
        float t = s * (1.f / 25.f);
        tinit[i] = t;
        sinit[i] = x[((long)b * 512 + lc) * 21 + c] - t;
    } else {
        sinit[i] = 0.f;
        tinit[i] = xm[b * 21 + c];
    }
}

// ------------------------- top-k (scaled mc; self-cleans) ------------------
__global__ __launch_bounds__(256)
void topk_k(float* __restrict__ mc, int* __restrict__ delays,
            float* __restrict__ wts)
{
    const float SCL = 1.f / (512.f * 4096.f);  // 1/512 mean, 1/(64*64) prescale
    int b = blockIdx.x, tid = threadIdx.x;
    __shared__ float v[512];
    __shared__ float rv[256];
    __shared__ int   ri[256];
    __shared__ float selv[6];
    v[tid]       = mc[b * 512 + tid]       * SCL;
    v[tid + 256] = mc[b * 512 + tid + 256] * SCL;
    mc[b * 512 + tid] = 0.f;
    mc[b * 512 + tid + 256] = 0.f;
    __syncthreads();
    for (int p = 0; p < 6; p++) {
        float bv = v[tid]; int bi = tid;
        float v2 = v[tid + 256];
        if (v2 > bv) { bv = v2; bi = tid + 256; }
        rv[tid] = bv; ri[tid] = bi;
        __syncthreads();
        for (int s = 128; s > 0; s >>= 1) {
            if (tid < s) {
                float ov = rv[tid + s]; int oi = ri[tid + s];
                if (ov > rv[tid] || (ov == rv[tid] && oi < ri[tid])) {
                    rv[tid] = ov; ri[tid] = oi;
                }
            }
            __syncthreads();
        }
        if (tid == 0) { selv[p] = rv[0]; delays[b * 6 + p] = ri[0]; v[ri[0]] = -3.4e38f; }
        __syncthreads();
    }
    if (tid == 0) {
        float mx = selv[0];
        for (int p = 1; p < 6; p++) mx = fmaxf(mx, selv[p]);
        float e[6], sum = 0.f;
        for (int p = 0; p < 6; p++) { e[p] = expf(selv[p] - mx); sum += e[p]; }
        for (int p = 0; p < 6; p++) wts[b * 6 + p] = e[p] / sum;
    }
}

// gather-agg from V cat slice; write cat out (rows x 1024)
__global__ __launch_bounds__(256)
void agg2_k(const _Float16* __restrict__ Vc, int vld, int vhi, int vlo,
            const int* __restrict__ delays, const float* __restrict__ wts,
            _Float16* __restrict__ out)
{
    long t = (long)blockIdx.x * 256 + threadIdx.x;
    int dc = (int)(t & 63);
    long row = t >> 6;
    int l = (int)(row & 511), b = (int)(row >> 9);
    float s[8] = {};
#pragma unroll
    for (int k = 0; k < 6; k++) {
        int dl = delays[b * 6 + k];
        float wv = wts[b * 6 + k];
        long sr = ((long)b * 512 + ((l + dl) & 511)) * vld + dc * 8;
        h8 hi8 = *(const h8*)(Vc + sr + vhi);
        h8 lo8 = *(const h8*)(Vc + sr + vlo);
#pragma unroll
        for (int j = 0; j < 8; j++)
            s[j] = fmaf(wv, (float)hi8[j] + (float)lo8[j], s[j]);
    }
    h8 ho, lo;
#pragma unroll
    for (int j = 0; j < 8; j++) {
        _Float16 h = (_Float16)s[j];
        ho[j] = h; lo[j] = (_Float16)(s[j] - (float)h);
    }
    long ob = row * 1024 + dc * 8;
    *(h8*)(out + ob)       = ho;
    *(h8*)(out + ob + 512) = lo;
}

// ------------------------- seasonal layernorm ------------------------------
__global__ __launch_bounds__(256)
void ln_k(const float* __restrict__ x, const float* __restrict__ g,
          const float* __restrict__ be, float* __restrict__ out)
{
    int row = blockIdx.x, tid = threadIdx.x;
    const float* xr = x + ((long)row << 9);
    float v0 = xr[tid], v1 = xr[tid + 256];
    __shared__ float rs[256];
    rs[tid] = v0 + v1; __syncthreads();
    for (int s = 128; s > 0; s >>= 1) { if (tid < s) rs[tid] += rs[tid + s]; __syncthreads(); }
    float mu = rs[0] * (1.f / 512.f);
    __syncthreads();
    float d0 = v0 - mu, d1 = v1 - mu;
    rs[tid] = d0 * d0 + d1 * d1; __syncthreads();
    for (int s = 128; s > 0; s >>= 1) { if (tid < s) rs[tid] += rs[tid + s]; __syncthreads(); }
    float rstd = 1.0f / sqrtf(rs[0] * (1.f / 512.f) + 1e-5f);
    out[((long)row << 9) + tid]       = d0 * rstd * g[tid] + be[tid];
    out[((long)row << 9) + tid + 256] = d1 * rstd * g[tid + 256] + be[tid + 256];
}

__global__ void colpart_k(const float* __restrict__ x, float* __restrict__ cp)
{
    int d = blockIdx.x * 256 + threadIdx.x;   // grid (2, 8, Bc)
    int ch = blockIdx.y, b = blockIdx.z;
    const float* xb = x + ((long)b << 18);
    float s = 0.f;
    for (int l = ch * 64; l < ch * 64 + 64; l++) s += xb[((long)l << 9) + d];
    cp[((long)(b * 8 + ch) << 9) + d] = s;
}

// CAT=1: write hi/lo cat only; CAT=0: write f32 (in-place safe)
template<int CAT>
__global__ __launch_bounds__(256)
void subcol8_k(const float* __restrict__ x, const float* __restrict__ cp,
               float* __restrict__ out, _Float16* __restrict__ cat)
{
    long t = (long)blockIdx.x * 256 + threadIdx.x;
    long row = t >> 6; int d8 = (int)(t & 63) * 8;
    int b = (int)(row >> 9);
    float m[8] = {};
#pragma unroll
    for (int ch = 0; ch < 8; ch++) {
        const float4* c4 = (const float4*)(cp + ((long)(b * 8 + ch) << 9) + d8);
        float4 c0 = c4[0], c1 = c4[1];
        m[0]+=c0.x; m[1]+=c0.y; m[2]+=c0.z; m[3]+=c0.w;
        m[4]+=c1.x; m[5]+=c1.y; m[6]+=c1.z; m[7]+=c1.w;
    }
    const float4* xp = (const float4*)(x + row * 512 + d8);
    float4 x0 = xp[0], x1 = xp[1];
    float v[8] = {x0.x,x0.y,x0.z,x0.w,x1.x,x1.y,x1.z,x1.w};
#pragma unroll
    for (int j = 0; j < 8; j++) v[j] -= m[j] * (1.f / 512.f);
    if (CAT) {
        h8 hi, lo;
#pragma unroll
        for (int j = 0; j < 8; j++) {
            _Float16 h = (_Float16)v[j];
            hi[j] = h; lo[j] = (_Float16)(v[j] - (float)h);
        }
        *(h8*)(cat + row * 1024 + d8)       = hi;
        *(h8*)(cat + row * 1024 + 512 + d8) = lo;
    } else {
        float4* op = (float4*)(out + row * 512 + d8);
        op[0] = make_float4(v[0],v[1],v[2],v[3]);
        op[1] = make_float4(v[4],v[5],v[6],v[7]);
    }
}

// ------------------------- trend shift-add + projection --------------------
__global__ void shiftadd_k(const float* __restrict__ H, const float* __restrict__ tinit,
                           float* __restrict__ tf, int total)
{
    int i = blockIdx.x * 256 + threadIdx.x;
    if (i >= total) return;
    int c = i % 21, l = (i / 21) % 512, b = i / 10752;
    long r = (long)b * 512;
    tf[i] = tinit[i]
          + H[(r + ((l + 511) & 511)) * 128 + c]
          + H[(r + l) * 128 + 21 + c]
          + H[(r + ((l + 1) & 511)) * 128 + 42 + c];
}

__global__ void proj_k(const float* __restrict__ x, const float* __restrict__ pw,
                       const float* __restrict__ pb, const float* __restrict__ trend,
                       float* __restrict__ out, int total)
{
    int i = blockIdx.x * 256 + threadIdx.x;
    if (i >= total) return;
    int c = i % 21, l = (i / 21) % 256 + 256, b = i / 5376;
    const float* xr = x + ((long)(b * 512 + l) << 9);
    float s = 0.f;
    for (int d = 0; d < 512; d++) s = fmaf(xr[d], pw[d * 21 + c], s);
    out[i] = s + pb[c] + trend[((long)b * 512 + l) * 21 + c];
}

// ---------------------------------------------------------------------------
// mode: 0 OUT1 cat, 2 OUT1 gelu-cat, 10 OUT0 +R, 11 OUT0 plain, 20 Scorr
static void hgemm(int mode,
                  const _Float16* A, int lda, int loA,
                  const _Float16* B, int ldb, int loB,
                  const float* R, void* C, int ldc, int loC,
                  int K, int M, int N, int batch,
                  long sA, long sB, long sC, hipStream_t st)
{
    dim3 g(N / 128, M / 128, batch), blk(256);
    switch (mode) {
    case 0:  hgemm_k<0,1><<<g,blk,0,st>>>(A,lda,loA,B,ldb,loB,R,C,ldc,loC,K,sA,sB,sC); break;
    case 2:  hgemm_k<2,1><<<g,blk,0,st>>>(A,lda,loA,B,ldb,loB,R,C,ldc,loC,K,sA,sB,sC); break;
    case 10: hgemm_k<1,0><<<g,blk,0,st>>>(A,lda,loA,B,ldb,loB,R,C,ldc,loC,K,sA,sB,sC); break;
    case 11: hgemm_k<0,0><<<g,blk,0,st>>>(A,lda,loA,B,ldb,loB,R,C,ldc,loC,K,sA,sB,sC); break;
    default: hgemm_k<0,2><<<g,blk,0,st>>>(A,lda,loA,B,ldb,loB,R,C,ldc,loC,K,sA,sB,sC); break;
    }
}

extern "C" void kernel_launch(void* const* d_in, const int* in_sizes, int n_in,
                              void* d_out, int out_size, void* d_ws, size_t ws_size,
                              hipStream_t stream)
{
    const float* x_enc    = (const float*)d_in[0];
    const float* xm_enc   = (const float*)d_in[1];
    const float* xm_dec   = (const float*)d_in[3];
    const float* enc_valW = (const float*)d_in[4];
    const float* enc_timeW= (const float*)d_in[5];
    const float* enc_Wq   = (const float*)d_in[6];
    const float* enc_Wk   = (const float*)d_in[7];
    const float* enc_Wv   = (const float*)d_in[8];
    const float* enc_Wo   = (const float*)d_in[9];
    const float* enc_W1   = (const float*)d_in[10];
    const float* enc_W2   = (const float*)d_in[11];
    const float* enc_g    = (const float*)d_in[12];
    const float* enc_b    = (const float*)d_in[13];
    const float* dec_valW = (const float*)d_in[14];
    const float* dec_timeW= (const float*)d_in[15];
    const float* sWq = (const float*)d_in[16];
    const float* sWk = (const float*)d_in[17];
    const float* sWv = (const float*)d_in[18];
    const float* sWo = (const float*)d_in[19];
    const float* cWq = (const float*)d_in[20];
    const float* cWk = (const float*)d_in[21];
    const float* cWv = (const float*)d_in[22];
    const float* cWo = (const float*)d_in[23];
    const float* dW1 = (const float*)d_in[24];
    const float* dW2 = (const float*)d_in[25];
    const float* dtW = (const float*)d_in[26];
    const float* dec_g = (const float*)d_in[27];
    const float* dec_b = (const float*)d_in[28];
    const float* projW = (const float*)d_in[29];
    const float* projB = (const float*)d_in[30];

    // ---- batch-chunk sizing (deterministic) ----
    const size_t W_BYTES = 42000000;
    const size_t perB = 11100000;      // includes bigcat = 512x4096 halfs = 4 MB
    int Bc = 32;
    while (Bc > 1 && W_BYTES + (size_t)Bc * perB + (4u << 20) > ws_size) Bc >>= 1;

    char* wp = (char*)d_ws;
    auto alloc = [&](size_t bytes) { char* p = wp; wp += (bytes + 255) & ~(size_t)255; return p; };

    // weight buffers (halfs counts x2 bytes)
    _Float16* encWcomb = (_Float16*)alloc(2 * 1048576 * 2);  // [WqkT|Wv] 1024x1024
    _Float16* encWoC   = (_Float16*)alloc(2 * 524288 * 2);
    _Float16* encW1C   = (_Float16*)alloc(2 * 2097152 * 2);
    _Float16* encW2C   = (_Float16*)alloc(2 * 2097152 * 2);
    _Float16* dsWcomb  = (_Float16*)alloc(1048576 * 2);
    _Float16* dsWoC    = (_Float16*)alloc(524288 * 2);
    _Float16* dcWqkT   = (_Float16*)alloc(524288 * 2);
    _Float16* dcWvC    = (_Float16*)alloc(524288 * 2);
    _Float16* dcWoC    = (_Float16*)alloc(524288 * 2);
    _Float16* dW1C     = (_Float16*)alloc(2097152 * 2);
    _Float16* dW2C     = (_Float16*)alloc(2097152 * 2);
    _Float16* W63C     = (_Float16*)alloc(131072 * 2);
    _Float16* wqS      = (_Float16*)alloc(524288 * 2);
    _Float16* wkS      = (_Float16*)alloc(524288 * 2);

    const long ROWS = (long)Bc * 512;
    const long NBc  = ROWS * 512;
    float*    X      = (float*)alloc(NBc * 4);
    float*    O      = (float*)alloc(NBc * 4);
    _Float16* TSc    = (_Float16*)alloc(ROWS * 1024 * 2);
    _Float16* cX     = (_Float16*)alloc(ROWS * 1024 * 2);
    _Float16* cAgg   = (_Float16*)alloc(ROWS * 1024 * 2);
    _Float16* ENCcat = (_Float16*)alloc(ROWS * 1024 * 2);
    _Float16* bigcat = (_Float16*)alloc(ROWS * 4096 * 2);   // FFN hidden needs x4096
    float* H       = (float*)alloc(ROWS * 128 * 4);
    float* sinit   = (float*)alloc((long)Bc * 10752 * 4);
    float* tinit   = (float*)alloc((long)Bc * 10752 * 4);
    float* tfinal  = (float*)alloc((long)Bc * 10752 * 4);
    float* xmean   = (float*)alloc((long)Bc * 21 * 4);
    float* mc      = (float*)alloc((long)Bc * 512 * 4);
    float* cp      = (float*)alloc((long)Bc * 4096 * 4);
    float* wts     = (float*)alloc((long)Bc * 6 * 4);
    int*   delays  = (int*)alloc((long)Bc * 6 * 4);

    // ---- weight setup ----
    dim3 cb(256);
    const float QS = 64.f;    // prescale BOTH Wq and Wk (lo stays f16-normal)
    auto makeWqk = [&](const float* Wq, const float* Wk, _Float16* dst) {
        split2_k<<<128, cb, 0, stream>>>(Wk, wkS, QS);
        split2_k<<<128, cb, 0, stream>>>(Wq, wqS, QS);
        // dst[d'][d] = QS^2 * sum_e Wk[d',e]*Wq[d,e]  (cat, ldc=1024)
        hgemm(0, wkS,1024,512, wqS,1024,512, nullptr, dst, 1024, 512,
              512, 512, 512, 1, 0,0,0, stream);
    };
    for (int L = 0; L < 2; L++) {
        makeWqk(enc_Wq + (long)L*262144, enc_Wk + (long)L*262144, encWcomb + (long)L*1048576);
        convW2_k<<<dim3(16,16), cb, 0, stream>>>(enc_Wv + (long)L*262144,
                                                 encWcomb + (long)L*1048576 + 512*1024, 512, 512);
        convW2_k<<<dim3(16,16), cb, 0, stream>>>(enc_Wo + (long)L*262144, encWoC + (long)L*524288, 512, 512);
        convW2_k<<<dim3(16,64), cb, 0, stream>>>(enc_W1 + (long)L*1048576, encW1C + (long)L*2097152, 2048, 512);
        convW2_k<<<dim3(64,16), cb, 0, stream>>>(enc_W2 + (long)L*1048576, encW2C + (long)L*2097152, 512, 2048);
    }
    makeWqk(sWq, sWk, dsWcomb);
    convW2_k<<<dim3(16,16), cb, 0, stream>>>(sWv, dsWcomb + 512*1024, 512, 512);
    convW2_k<<<dim3(16,16), cb, 0, stream>>>(sWo, dsWoC, 512, 512);
    makeWqk(cWq, cWk, dcWqkT);
    convW2_k<<<dim3(16,16), cb, 0, stream>>>(cWv, dcWvC, 512, 512);
    convW2_k<<<dim3(16,16), cb, 0, stream>>>(cWo, dcWoC, 512, 512);
    convW2_k<<<dim3(16,64), cb, 0, stream>>>(dW1, dW1C, 2048, 512);
    convW2_k<<<dim3(64,16), cb, 0, stream>>>(dW2, dW2C, 512, 2048);
    convW63_k<<<256, cb, 0, stream>>>(dtW, W63C);

    const int M = (int)ROWS;
    const int t21 = Bc * 10752;
    const int gRows = Bc * 128;
    const long sTV = 512 * 2048;   // per-batch row stride in bigcat (TV layout)
    const long sCA = 512 * 1024;

    zero_k<<<(Bc*512 + 255)/256, 256, 0, stream>>>(mc, Bc*512);

    // self-attention: Cout = Xin + attn(Xin). TV = [T|V] in bigcat (ldc 2048).
    auto attn_self = [&](float* Xin, float* Cout, const _Float16* cXin,
                         const _Float16* Wcomb, const _Float16* WoC) {
        hgemm(0, cXin,1024,512, Wcomb,1024,512, nullptr, bigcat, 2048, 1024,
              512, M, 1024, 1, 0,0,0, stream);                            // [T|V]
        hgemm(20, bigcat,2048,1024, cXin,1024,512, nullptr, mc, 0, 0,
              512, 512, 512, Bc, sTV, sCA, 512, stream);                  // diag(T X^T)
        topk_k<<<Bc, 256, 0, stream>>>(mc, delays, wts);
        agg2_k<<<gRows, 256, 0, stream>>>(bigcat, 2048, 512, 1536, delays, wts, cAgg);
        hgemm(10, cAgg,1024,512, WoC,1024,512, Xin, Cout, 512, 0,
              512, M, 512, 1, 0,0,0, stream);
    };
    auto ffn = [&](float* Xin, float* Cout, const _Float16* cXin,
                   const _Float16* W1C, const _Float16* W2C) {
        hgemm(2, cXin,1024,512, W1C,1024,512, nullptr, bigcat, 4096, 2048,
              512, M, 2048, 1, 0,0,0, stream);
        hgemm(10, bigcat,4096,2048, W2C,4096,2048, Xin, Cout, 512, 0,
              2048, M, 512, 1, 0,0,0, stream);
    };

    for (int b0 = 0; b0 < 32; b0 += Bc) {
        const float* xe  = x_enc  + (long)b0 * 10752;
        const float* mke = xm_enc + (long)b0 * 2048;
        const float* mkd = xm_dec + (long)b0 * 2048;
        float* outp = (float*)d_out + (long)b0 * 5376;

        meanseq_k<<<(Bc*21 + 255)/256, 256, 0, stream>>>(xe, xmean, Bc*21);
        prep_k   <<<(t21 + 255)/256, 256, 0, stream>>>(xe, xmean, sinit, tinit, t21);

        // ---------------- encoder ----------------
        embed_k<<<dim3(64,2,Bc), 256, 0, stream>>>(xe, mke, enc_valW, enc_timeW, X, cX);
        for (int L = 0; L < 2; L++) {
            attn_self(X, O, cX, encWcomb + (long)L*1048576, encWoC + (long)L*524288);
            decomp8_k<0,1><<<gRows, 256, 0, stream>>>(O, X, cX, nullptr);
            ffn(X, O, cX, encW1C + (long)L*2097152, encW2C + (long)L*2097152);
            decomp8_k<0,1><<<gRows, 256, 0, stream>>>(O, X, cX, nullptr);
        }
        ln_k      <<<Bc*512, 256, 0, stream>>>(X, enc_g, enc_b, O);
        colpart_k <<<dim3(2,8,Bc), 256, 0, stream>>>(O, cp);
        subcol8_k<1><<<gRows, 256, 0, stream>>>(O, cp, nullptr, ENCcat);

        // ---------------- decoder ----------------
        embed_k<<<dim3(64,2,Bc), 256, 0, stream>>>(sinit, mkd, dec_valW, dec_timeW, X, cX);

        // self attention
        attn_self(X, O, cX, dsWcomb, dsWoC);
        decomp8_k<2,1><<<gRows, 256, 0, stream>>>(O, X, cX, TSc);    // TSc = trend

        // cross attention: T = Xdec*WqkT ; V = ENC*Wv ; diag(T ENC^T)
        hgemm(0, cX,1024,512, dcWqkT,1024,512, nullptr, cAgg, 1024, 512,
              512, M, 512, 1, 0,0,0, stream);                        // cT
        hgemm(0, ENCcat,1024,512, dcWvC,1024,512, nullptr, bigcat, 1024, 512,
              512, M, 512, 1, 0,0,0, stream);                        // cV
        hgemm(20, cAgg,1024,512, ENCcat,1024,512, nullptr, mc, 0, 0,
              512, 512, 512, Bc, sCA, sCA, 512, stream);
        topk_k<<<Bc, 256, 0, stream>>>(mc, delays, wts);
        agg2_k<<<gRows, 256, 0, stream>>>(bigcat, 1024, 0, 512, delays, wts, cAgg);
        hgemm(10, cAgg,1024,512, dcWoC,1024,512, X, O, 512, 0,
              512, M, 512, 1, 0,0,0, stream);
        decomp8_k<1,1><<<gRows, 256, 0, stream>>>(O, X, cX, TSc);    // TSc += trend

        // ffn
        ffn(X, O, cX, dW1C, dW2C);
        decomp8_k<1,0><<<gRows, 256, 0, stream>>>(O, X, nullptr, TSc);

        // trend conv as MFMA GEMM: H = TSc @ W63 (padded to 128 cols)
        hgemm(11, TSc,1024,512, W63C,1024,512, nullptr, H, 128, 0,
              512, M, 128, 1, 0,0,0, stream);
        shiftadd_k<<<(t21+255)/256, 256, 0, stream>>>(H, tinit, tfinal, t21);
        ln_k      <<<Bc*512, 256, 0, stream>>>(X, dec_g, dec_b, O);
        colpart_k <<<dim3(2,8,Bc), 256, 0, stream>>>(O, cp);
        subcol8_k<0><<<gRows, 256, 0, stream>>>(O, cp, O, nullptr);
        proj_k    <<<(Bc*5376+255)/256, 256, 0, stream>>>(O, projW, projB, tfinal, outp, Bc*5376);
    }
}

// Round 9
// 3096.027 us; speedup vs baseline: 2.7667x; 1.1360x over previous
//
#include <hip/hip_runtime.h>

// ---------------------------------------------------------------------------
// Autoformer forward, MI355X. Round 9: Wv*Wo fold (no V projection / no Wo),
// 2-phase split on FFN/Wvo/trend GEMMs, hi-only hidden, epilogue scaling.
// GEMM numerics: C = Ah*Bh + Ah*Bl (+ Al*Bh when nph=3), rows x 2K f16 [hi|lo].
// ---------------------------------------------------------------------------

typedef _Float16 h8 __attribute__((ext_vector_type(8)));
typedef float f32x4 __attribute__((ext_vector_type(4)));

__device__ __forceinline__ float gelu_f(float x){
    return 0.5f * x * (1.0f + erff(x * 0.70710678118654752f));
}

__device__ __forceinline__ void gl_lds(const _Float16* gp, _Float16* lp) {
    __builtin_amdgcn_global_load_lds(
        (const __attribute__((address_space(1))) void*)gp,
        (__attribute__((address_space(3))) void*)lp, 16, 0, 0);
}

__global__ void zero_k(float* __restrict__ p, long n){
    long i = (long)blockIdx.x * 256 + threadIdx.x;
    if (i < n) p[i] = 0.f;
}

// ------------------------------ MFMA GEMM ----------------------------------
// A: M x 2K [hi|lo] (lda halfs, lo at +loA). B: N x 2K (ldb, +loB).
// nph phases x (K/64): (Ah,Bh),(Ah,Bl)[,(Al,Bh)]. f32 accum, *osc epilogue.
// OUT=0: f32 C (ldc floats); EPI 0 plain, 1 +R residual.
// OUT=1: f16 cat C (hi at row*ldc+col, lo at +loC; loC<0 -> hi only); EPI 0/2.
// OUT=2: diag reduce: atomicAdd mc[bz*sC + (row-col)&511].
template<int EPI, int OUT>
__global__ __launch_bounds__(256)
void hgemm_k(const _Float16* __restrict__ A, int lda, int loA,
             const _Float16* __restrict__ Bm, int ldb, int loB,
             const float* __restrict__ R, void* __restrict__ Cv,
             int ldc, int loC, int K, int nph, float osc,
             long sA, long sB, long sC)
{
    __shared__ _Float16 As[128 * 64];
    __shared__ _Float16 Bs[128 * 64];
    const int bz = blockIdx.z;
    const int tid = threadIdx.x, lane = tid & 63, w = tid >> 6;
    const int wr = w >> 1, wc = w & 1;
    const _Float16* Ap = A + bz * sA + (long)(blockIdx.y * 128) * lda;
    const _Float16* Bp = Bm + bz * sB + (long)(blockIdx.x * 128) * ldb;

    const int swz = ((lane & 7) ^ ((lane >> 3) & 7)) * 8;
    const int rsub = w * 32 + (lane >> 3);
    const _Float16* ApT = Ap + (long)rsub * lda + swz;
    const _Float16* BpT = Bp + (long)rsub * ldb + swz;
    _Float16* AsT = As + w * 2048;
    _Float16* BsT = Bs + w * 2048;

    const int tpp = K >> 6;
    const int nkt = tpp * nph;
    f32x4 acc[4][4] = {};

    int p = 0, q = 0;
    for (int kt = 0; kt < nkt; ++kt) {
        const int aoff = q * 64 + (p == 2 ? loA : 0);
        const int boff = q * 64 + (p == 1 ? loB : 0);
        __syncthreads();
#pragma unroll
        for (int i = 0; i < 4; i++) {
            gl_lds(ApT + (long)i * 8 * lda + aoff, AsT + i * 512);
            gl_lds(BpT + (long)i * 8 * ldb + boff, BsT + i * 512);
        }
        __syncthreads();
#pragma unroll
        for (int kk = 0; kk < 2; ++kk) {
            h8 af[4], bf[4];
            const int ks = kk * 4 + (lane >> 4);
#pragma unroll
            for (int m = 0; m < 4; m++) {
                int rowa = wr * 64 + m * 16 + (lane & 15);
                af[m] = *(const h8*)(As + rowa * 64 + ((ks ^ (rowa & 7)) * 8));
                int rowb = wc * 64 + m * 16 + (lane & 15);
                bf[m] = *(const h8*)(Bs + rowb * 64 + ((ks ^ (rowb & 7)) * 8));
            }
#pragma unroll
            for (int m = 0; m < 4; m++)
#pragma unroll
                for (int n = 0; n < 4; n++)
                    acc[m][n] = __builtin_amdgcn_mfma_f32_16x16x32_f16(af[m], bf[n], acc[m][n], 0, 0, 0);
        }
        if (++q == tpp) { q = 0; ++p; }
    }

    const int crow0 = blockIdx.y * 128 + wr * 64 + (lane >> 4) * 4;
    const int ccol0 = blockIdx.x * 128 + wc * 64 + (lane & 15);
    if constexpr (OUT == 0) {
        float* Cp = (float*)Cv + (long)bz * sC;
        const float* Rp = (EPI == 1) ? (R + (long)bz * sC) : nullptr;
#pragma unroll
        for (int m = 0; m < 4; m++)
#pragma unroll
            for (int n = 0; n < 4; n++) {
                int col = ccol0 + n * 16;
#pragma unroll
                for (int r2 = 0; r2 < 4; r2++) {
                    long idx = (long)(crow0 + m * 16 + r2) * ldc + col;
                    float v = acc[m][n][r2] * osc;
                    if (EPI == 1) v += Rp[idx];
                    Cp[idx] = v;
                }
            }
    } else if constexpr (OUT == 1) {
        _Float16* Cp = (_Float16*)Cv + (long)bz * sC;
#pragma unroll
        for (int m = 0; m < 4; m++)
#pragma unroll
            for (int n = 0; n < 4; n++) {
                int col = ccol0 + n * 16;
#pragma unroll
                for (int r2 = 0; r2 < 4; r2++) {
                    long base = (long)(crow0 + m * 16 + r2) * ldc + col;
                    float v = acc[m][n][r2] * osc;
                    if (EPI == 2) v = gelu_f(v);
                    _Float16 hi = (_Float16)v;
                    Cp[base] = hi;
                    if (loC >= 0) Cp[base + loC] = (_Float16)(v - (float)hi);
                }
            }
    } else {
        __shared__ float diag[512];
        float* mc = (float*)Cv + (long)bz * sC;
        for (int t = tid; t < 512; t += 256) diag[t] = 0.f;
        __syncthreads();
#pragma unroll
        for (int m = 0; m < 4; m++)
#pragma unroll
            for (int n = 0; n < 4; n++) {
                int col = ccol0 + n * 16;
#pragma unroll
                for (int r2 = 0; r2 < 4; r2++) {
                    int row = crow0 + m * 16 + r2;
                    atomicAdd(&diag[(row - col) & 511], acc[m][n][r2]);
                }
            }
        __syncthreads();
        for (int t = tid; t < 512; t += 256) {
            float v = diag[t];
            if (v != 0.f) atomicAdd(&mc[t], v);
        }
    }
}

// ------------------------- split / weight conversion -----------------------
// rows x 512 f32 -> rows x 1024 cat [hi|lo], scaled.
__global__ __launch_bounds__(256)
void split2_k(const float* __restrict__ x, _Float16* __restrict__ y, float scale)
{
    long t = (long)blockIdx.x * 256 + threadIdx.x;
    long row = t >> 6; int kc = (int)(t & 63) * 8;
    const float4 v0 = *(const float4*)(x + row * 512 + kc);
    const float4 v1 = *(const float4*)(x + row * 512 + kc + 4);
    float vv[8] = {v0.x,v0.y,v0.z,v0.w,v1.x,v1.y,v1.z,v1.w};
    h8 hi, lo;
#pragma unroll
    for (int j = 0; j < 8; j++) {
        float s = vv[j] * scale;
        _Float16 h = (_Float16)s;
        hi[j] = h; lo[j] = (_Float16)(s - (float)h);
    }
    *(h8*)(y + row * 1024 + kc)       = hi;
    *(h8*)(y + row * 1024 + 512 + kc) = lo;
}

// W (K x N f32) -> dst (N rows x 2K f16 cat), scaled. grid (K/32, N/32)
__global__ __launch_bounds__(256)
void convW2_k(const float* __restrict__ src, _Float16* __restrict__ dst,
              int N, int K, float scale)
{
    __shared__ float t[32][33];
    int k0 = blockIdx.x * 32, n0 = blockIdx.y * 32, tid = threadIdx.x;
#pragma unroll
    for (int i = 0; i < 4; i++) {
        int lin = tid + i * 256; int r = lin >> 5, c = lin & 31;
        t[r][c] = src[(long)(k0 + r) * N + n0 + c];
    }
    __syncthreads();
#pragma unroll
    for (int i = 0; i < 4; i++) {
        int lin = tid + i * 256; int n = lin >> 5, k = lin & 31;
        float v = t[k][n] * scale;
        _Float16 hi = (_Float16)v;
        long base = (long)(n0 + n) * 2 * K + k0 + k;
        dst[base]     = hi;
        dst[base + K] = (_Float16)(v - (float)hi);
    }
}

// dtW (3 x 512 x 21) -> 128 rows x 1024 cat, x64 (row j = t*21+c, zero-pad)
__global__ void convW63_k(const float* __restrict__ W, _Float16* __restrict__ dst)
{
    int i = blockIdx.x * 256 + threadIdx.x;   // 65536
    int k = i & 511, j = i >> 9;
    float v = (j < 63) ? 64.f * W[(long)(j / 21) * 10752 + (long)k * 21 + (j % 21)] : 0.f;
    _Float16 hi = (_Float16)v;
    dst[(long)j * 1024 + k]       = hi;
    dst[(long)j * 1024 + 512 + k] = (_Float16)(v - (float)hi);
}

// ------------------------- embedding (conv3 + mark + pe + cat) -------------
__global__ __launch_bounds__(256)
void embed_k(const float* __restrict__ x, const float* __restrict__ mark,
             const float* __restrict__ valW, const float* __restrict__ timeW,
             float* __restrict__ out, _Float16* __restrict__ cat)
{
    const int lg = blockIdx.x, dh = blockIdx.y, b = blockIdx.z;
    const int tid = threadIdx.x;
    const int dd = dh * 256 + tid;
    const int l0 = lg * 8;
    __shared__ float xs[10][21];
    __shared__ float mk[8][4];
    if (tid < 210) {
        int r = tid / 21, c = tid % 21;
        int ll = (l0 - 1 + r + 512) & 511;
        xs[r][c] = x[((long)b * 512 + ll) * 21 + c];
    }
    if (tid >= 224 && tid < 256) {
        int t2 = tid - 224, il = t2 >> 2, m = t2 & 3;
        mk[il][m] = mark[((long)b * 512 + l0 + il) * 4 + m];
    }
    __syncthreads();
    float acc[8];
#pragma unroll
    for (int il = 0; il < 8; il++) acc[il] = 0.f;
    for (int t = 0; t < 3; t++)
        for (int c = 0; c < 21; c++) {
            float w = valW[(t * 21 + c) * 512 + dd];
#pragma unroll
            for (int il = 0; il < 8; il++)
                acc[il] = fmaf(xs[il + t][c], w, acc[il]);
        }
    for (int m = 0; m < 4; m++) {
        float w = timeW[m * 512 + dd];
#pragma unroll
        for (int il = 0; il < 8; il++)
            acc[il] = fmaf(mk[il][m], w, acc[il]);
    }
    const float freq = expf((float)(dd & ~1) * (-9.210340371976184f / 512.0f));
#pragma unroll
    for (int il = 0; il < 8; il++) {
        float ang = (float)(l0 + il) * freq;
        float pe = (dd & 1) ? cosf(ang) : sinf(ang);
        float v = acc[il] + pe;
        long row = (long)b * 512 + l0 + il;
        out[row * 512 + dd] = v;
        _Float16 hi = (_Float16)v;
        cat[row * 1024 + dd]       = hi;
        cat[row * 1024 + 512 + dd] = (_Float16)(v - (float)hi);
    }
}

// ------------------------- fused decomp (D=512, 8-wide) --------------------
// TREND: 0 none, 1 TSc += trend (cat), 2 TSc = trend (cat). CAT: seasonal cat.
template<int TREND, int CAT>
__global__ __launch_bounds__(256)
void decomp8_k(const float* __restrict__ x, float* __restrict__ out,
               _Float16* __restrict__ cat, _Float16* __restrict__ tsc)
{
    long t = (long)blockIdx.x * 256 + threadIdx.x;
    long row = t >> 6; int d8 = (int)(t & 63) * 8;
    int l = (int)(row & 511);
    const float* xb = x + ((row >> 9) << 18);
    float s[8] = {};
    float xo[8];
#pragma unroll
    for (int j = -12; j <= 12; j++) {
        int ll = l + j; ll = ll < 0 ? 0 : (ll > 511 ? 511 : ll);
        const float4* p = (const float4*)(xb + ((long)ll << 9) + d8);
        float4 v0 = p[0], v1 = p[1];
        s[0]+=v0.x; s[1]+=v0.y; s[2]+=v0.z; s[3]+=v0.w;
        s[4]+=v1.x; s[5]+=v1.y; s[6]+=v1.z; s[7]+=v1.w;
        if (j == 0) { xo[0]=v0.x; xo[1]=v0.y; xo[2]=v0.z; xo[3]=v0.w;
                      xo[4]=v1.x; xo[5]=v1.y; xo[6]=v1.z; xo[7]=v1.w; }
    }
    float tr[8], ov[8];
#pragma unroll
    for (int j = 0; j < 8; j++) { tr[j] = s[j] * (1.f/25.f); ov[j] = xo[j] - tr[j]; }
    float4* op = (float4*)(out + row * 512 + d8);
    op[0] = make_float4(ov[0],ov[1],ov[2],ov[3]);
    op[1] = make_float4(ov[4],ov[5],ov[6],ov[7]);
    if (CAT) {
        h8 hi, lo;
#pragma unroll
        for (int j = 0; j < 8; j++) {
            _Float16 h = (_Float16)ov[j];
            hi[j] = h; lo[j] = (_Float16)(ov[j] - (float)h);
        }
        *(h8*)(cat + row * 1024 + d8)       = hi;
        *(h8*)(cat + row * 1024 + 512 + d8) = lo;
    }
    if (TREND) {
        _Float16* tp = tsc + row * 1024 + d8;
        if (TREND == 1) {
            h8 th = *(h8*)tp, tl = *(h8*)(tp + 512);
#pragma unroll
            for (int j = 0; j < 8; j++) tr[j] += (float)th[j] + (float)tl[j];
        }
        h8 th2, tl2;
#pragma unroll
        for (int j = 0; j < 8; j++) {
            _Float16 h = (_Float16)tr[j];
            th2[j] = h; tl2[j] = (_Float16)(tr[j] - (float)h);
        }
        *(h8*)tp         = th2;
        *(h8*)(tp + 512) = tl2;
    }
}

// ------------------------- prep (mean + decomp tail + inits) ---------------
__global__ void meanseq_k(const float* __restrict__ x, float* __restrict__ xm, int total)
{
    int i = blockIdx.x * 256 + threadIdx.x;
    if (i >= total) return;
    int c = i % 21, b = i / 21;
    float s = 0.f;
    for (int l = 0; l < 512; l++) s += x[((long)b * 512 + l) * 21 + c];
    xm[i] = s * (1.f / 512.f);
}

__global__ void prep_k(const float* __restrict__ x, const float* __restrict__ xm,
                       float* __restrict__ sinit, float* __restrict__ tinit, int total)
{
    int i = blockIdx.x * 256 + threadIdx.x;
    if (i >= total) return;
    int c = i % 21, l = (i / 21) % 512, b = i / 10752;
    if (l < 256) {
        int lc = 256 + l;
        float s = 0.f;
        for (int j = -12; j <= 12; j++) {
            int ll = lc + j; ll = ll > 511 ? 511 : ll;
            s += x[((long)b * 512 + ll) * 21 + c];
        }
        float t = s * (1.f / 25.f);
        tinit[i] = t;
        sinit[i] = x[((long)b * 512 + lc) * 21 + c] - t;
    } else {
        sinit[i] = 0.f;
        tinit[i] = xm[b * 21 + c];
    }
}

// ------------------------- top-k (scaled mc; self-cleans) ------------------
__global__ __launch_bounds__(256)
void topk_k(float* __restrict__ mc, int* __restrict__ delays,
            float* __restrict__ wts)
{
    const float SCL = 1.f / (512.f * 4096.f);  // 1/512 mean, 1/(64*64) prescale
    int b = blockIdx.x, tid = threadIdx.x;
    __shared__ float v[512];
    __shared__ float rv[256];
    __shared__ int   ri[256];
    __shared__ float selv[6];
    v[tid]       = mc[b * 512 + tid]       * SCL;
    v[tid + 256] = mc[b * 512 + tid + 256] * SCL;
    mc[b * 512 + tid] = 0.f;
    mc[b * 512 + tid + 256] = 0.f;
    __syncthreads();
    for (int p = 0; p < 6; p++) {
        float bv = v[tid]; int bi = tid;
        float v2 = v[tid + 256];
        if (v2 > bv) { bv = v2; bi = tid + 256; }
        rv[tid] = bv; ri[tid] = bi;
        __syncthreads();
        for (int s = 128; s > 0; s >>= 1) {
            if (tid < s) {
                float ov = rv[tid + s]; int oi = ri[tid + s];
                if (ov > rv[tid] || (ov == rv[tid] && oi < ri[tid])) {
                    rv[tid] = ov; ri[tid] = oi;
                }
            }
            __syncthreads();
        }
        if (tid == 0) { selv[p] = rv[0]; delays[b * 6 + p] = ri[0]; v[ri[0]] = -3.4e38f; }
        __syncthreads();
    }
    if (tid == 0) {
        float mx = selv[0];
        for (int p = 1; p < 6; p++) mx = fmaxf(mx, selv[p]);
        float e[6], sum = 0.f;
        for (int p = 0; p < 6; p++) { e[p] = expf(selv[p] - mx); sum += e[p]; }
        for (int p = 0; p < 6; p++) wts[b * 6 + p] = e[p] / sum;
    }
}

// gather-agg from cat source; write cat out (rows x 1024)
__global__ __launch_bounds__(256)
void agg2_k(const _Float16* __restrict__ Vc, int vld, int vhi, int vlo,
            const int* __restrict__ delays, const float* __restrict__ wts,
            _Float16* __restrict__ out)
{
    long t = (long)blockIdx.x * 256 + threadIdx.x;
    int dc = (int)(t & 63);
    long row = t >> 6;
    int l = (int)(row & 511), b = (int)(row >> 9);
    float s[8] = {};
#pragma unroll
    for (int k = 0; k < 6; k++) {
        int dl = delays[b * 6 + k];
        float wv = wts[b * 6 + k];
        long sr = ((long)b * 512 + ((l + dl) & 511)) * vld + dc * 8;
        h8 hi8 = *(const h8*)(Vc + sr + vhi);
        h8 lo8 = *(const h8*)(Vc + sr + vlo);
#pragma unroll
        for (int j = 0; j < 8; j++)
            s[j] = fmaf(wv, (float)hi8[j] + (float)lo8[j], s[j]);
    }
    h8 ho, lo;
#pragma unroll
    for (int j = 0; j < 8; j++) {
        _Float16 h = (_Float16)s[j];
        ho[j] = h; lo[j] = (_Float16)(s[j] - (float)h);
    }
    long ob = row * 1024 + dc * 8;
    *(h8*)(out + ob)       = ho;
    *(h8*)(out + ob + 512) = lo;
}

// ------------------------- seasonal layernorm ------------------------------
__global__ __launch_bounds__(256)
void ln_k(const float* __restrict__ x, const float* __restrict__ g,
          const float* __restrict__ be, float* __restrict__ out)
{
    int row = blockIdx.x, tid = threadIdx.x;
    const float* xr = x + ((long)row << 9);
    float v0 = xr[tid], v1 = xr[tid + 256];
    __shared__ float rs[256];
    rs[tid] = v0 + v1; __syncthreads();
    for (int s = 128; s > 0; s >>= 1) { if (tid < s) rs[tid] += rs[tid + s]; __syncthreads(); }
    float mu = rs[0] * (1.f / 512.f);
    __syncthreads();
    float d0 = v0 - mu, d1 = v1 - mu;
    rs[tid] = d0 * d0 + d1 * d1; __syncthreads();
    for (int s = 128; s > 0; s >>= 1) { if (tid < s) rs[tid] += rs[tid + s]; __syncthreads(); }
    float rstd = 1.0f / sqrtf(rs[0] * (1.f / 512.f) + 1e-5f);
    out[((long)row << 9) + tid]       = d0 * rstd * g[tid] + be[tid];
    out[((long)row << 9) + tid + 256] = d1 * rstd * g[tid + 256] + be[tid + 256];
}

__global__ void colpart_k(const float* __restrict__ x, float* __restrict__ cp)
{
    int d = blockIdx.x * 256 + threadIdx.x;   // grid (2, 8, Bc)
    int ch = blockIdx.y, b = blockIdx.z;
    const float* xb = x + ((long)b << 18);
    float s = 0.f;
    for (int l = ch * 64; l < ch * 64 + 64; l++) s += xb[((long)l << 9) + d];
    cp[((long)(b * 8 + ch) << 9) + d] = s;
}

// CAT=1: write hi/lo cat only; CAT=0: write f32 (in-place safe)
template<int CAT>
__global__ __launch_bounds__(256)
void subcol8_k(const float* __restrict__ x, const float* __restrict__ cp,
               float* __restrict__ out, _Float16* __restrict__ cat)
{
    long t = (long)blockIdx.x * 256 + threadIdx.x;
    long row = t >> 6; int d8 = (int)(t & 63) * 8;
    int b = (int)(row >> 9);
    float m[8] = {};
#pragma unroll
    for (int ch = 0; ch < 8; ch++) {
        const float4* c4 = (const float4*)(cp + ((long)(b * 8 + ch) << 9) + d8);
        float4 c0 = c4[0], c1 = c4[1];
        m[0]+=c0.x; m[1]+=c0.y; m[2]+=c0.z; m[3]+=c0.w;
        m[4]+=c1.x; m[5]+=c1.y; m[6]+=c1.z; m[7]+=c1.w;
    }
    const float4* xp = (const float4*)(x + row * 512 + d8);
    float4 x0 = xp[0], x1 = xp[1];
    float v[8] = {x0.x,x0.y,x0.z,x0.w,x1.x,x1.y,x1.z,x1.w};
#pragma unroll
    for (int j = 0; j < 8; j++) v[j] -= m[j] * (1.f / 512.f);
    if (CAT) {
        h8 hi, lo;
#pragma unroll
        for (int j = 0; j < 8; j++) {
            _Float16 h = (_Float16)v[j];
            hi[j] = h; lo[j] = (_Float16)(v[j] - (float)h);
        }
        *(h8*)(cat + row * 1024 + d8)       = hi;
        *(h8*)(cat + row * 1024 + 512 + d8) = lo;
    } else {
        float4* op = (float4*)(out + row * 512 + d8);
        op[0] = make_float4(v[0],v[1],v[2],v[3]);
        op[1] = make_float4(v[4],v[5],v[6],v[7]);
    }
}

// ------------------------- trend shift-add + projection --------------------
__global__ void shiftadd_k(const float* __restrict__ H, const float* __restrict__ tinit,
                           float* __restrict__ tf, int total)
{
    int i = blockIdx.x * 256 + threadIdx.x;
    if (i >= total) return;
    int c = i % 21, l = (i / 21) % 512, b = i / 10752;
    long r = (long)b * 512;
    tf[i] = tinit[i]
          + H[(r + ((l + 511) & 511)) * 128 + c]
          + H[(r + l) * 128 + 21 + c]
          + H[(r + ((l + 1) & 511)) * 128 + 42 + c];
}

__global__ void proj_k(const float* __restrict__ x, const float* __restrict__ pw,
                       const float* __restrict__ pb, const float* __restrict__ trend,
                       float* __restrict__ out, int total)
{
    int i = blockIdx.x * 256 + threadIdx.x;
    if (i >= total) return;
    int c = i % 21, l = (i / 21) % 256 + 256, b = i / 5376;
    const float* xr = x + ((long)(b * 512 + l) << 9);
    float s = 0.f;
    for (int d = 0; d < 512; d++) s = fmaf(xr[d], pw[d * 21 + c], s);
    out[i] = s + pb[c] + trend[((long)b * 512 + l) * 21 + c];
}

// ---------------------------------------------------------------------------
// mode: 0 OUT1 cat, 2 OUT1 gelu-cat, 10 OUT0 +R, 11 OUT0 plain, 20 Scorr
static void hgemm(int mode, int nph, float osc,
                  const _Float16* A, int lda, int loA,
                  const _Float16* B, int ldb, int loB,
                  const float* R, void* C, int ldc, int loC,
                  int K, int M, int N, int batch,
                  long sA, long sB, long sC, hipStream_t st)
{
    dim3 g(N / 128, M / 128, batch), blk(256);
    switch (mode) {
    case 0:  hgemm_k<0,1><<<g,blk,0,st>>>(A,lda,loA,B,ldb,loB,R,C,ldc,loC,K,nph,osc,sA,sB,sC); break;
    case 2:  hgemm_k<2,1><<<g,blk,0,st>>>(A,lda,loA,B,ldb,loB,R,C,ldc,loC,K,nph,osc,sA,sB,sC); break;
    case 10: hgemm_k<1,0><<<g,blk,0,st>>>(A,lda,loA,B,ldb,loB,R,C,ldc,loC,K,nph,osc,sA,sB,sC); break;
    case 11: hgemm_k<0,0><<<g,blk,0,st>>>(A,lda,loA,B,ldb,loB,R,C,ldc,loC,K,nph,osc,sA,sB,sC); break;
    default: hgemm_k<0,2><<<g,blk,0,st>>>(A,lda,loA,B,ldb,loB,R,C,ldc,loC,K,nph,osc,sA,sB,sC); break;
    }
}

extern "C" void kernel_launch(void* const* d_in, const int* in_sizes, int n_in,
                              void* d_out, int out_size, void* d_ws, size_t ws_size,
                              hipStream_t stream)
{
    const float* x_enc    = (const float*)d_in[0];
    const float* xm_enc   = (const float*)d_in[1];
    const float* xm_dec   = (const float*)d_in[3];
    const float* enc_valW = (const float*)d_in[4];
    const float* enc_timeW= (const float*)d_in[5];
    const float* enc_Wq   = (const float*)d_in[6];
    const float* enc_Wk   = (const float*)d_in[7];
    const float* enc_Wv   = (const float*)d_in[8];
    const float* enc_Wo   = (const float*)d_in[9];
    const float* enc_W1   = (const float*)d_in[10];
    const float* enc_W2   = (const float*)d_in[11];
    const float* enc_g    = (const float*)d_in[12];
    const float* enc_b    = (const float*)d_in[13];
    const float* dec_valW = (const float*)d_in[14];
    const float* dec_timeW= (const float*)d_in[15];
    const float* sWq = (const float*)d_in[16];
    const float* sWk = (const float*)d_in[17];
    const float* sWv = (const float*)d_in[18];
    const float* sWo = (const float*)d_in[19];
    const float* cWq = (const float*)d_in[20];
    const float* cWk = (const float*)d_in[21];
    const float* cWv = (const float*)d_in[22];
    const float* cWo = (const float*)d_in[23];
    const float* dW1 = (const float*)d_in[24];
    const float* dW2 = (const float*)d_in[25];
    const float* dtW = (const float*)d_in[26];
    const float* dec_g = (const float*)d_in[27];
    const float* dec_b = (const float*)d_in[28];
    const float* projW = (const float*)d_in[29];
    const float* projB = (const float*)d_in[30];

    // ---- batch-chunk sizing (deterministic) ----
    const size_t W_BYTES = 37000000;
    const size_t perB = 8900000;
    int Bc = 32;
    while (Bc > 1 && W_BYTES + (size_t)Bc * perB + (4u << 20) > ws_size) Bc >>= 1;

    char* wp = (char*)d_ws;
    auto alloc = [&](size_t bytes) { char* p = wp; wp += (bytes + 255) & ~(size_t)255; return p; };

    // weight buffers (halfs counts x2 bytes)
    _Float16* encWqkC = (_Float16*)alloc(2 * 524288 * 2);   // 512x1024 per layer
    _Float16* encWvoC = (_Float16*)alloc(2 * 524288 * 2);
    _Float16* encW1C  = (_Float16*)alloc(2 * 2097152 * 2);  // 2048x1024
    _Float16* encW2C  = (_Float16*)alloc(2 * 2097152 * 2);  // 512x4096
    _Float16* dsWqkC  = (_Float16*)alloc(524288 * 2);
    _Float16* dsWvoC  = (_Float16*)alloc(524288 * 2);
    _Float16* dcWqkC  = (_Float16*)alloc(524288 * 2);
    _Float16* dcWvoC  = (_Float16*)alloc(524288 * 2);
    _Float16* dW1C    = (_Float16*)alloc(2097152 * 2);
    _Float16* dW2C    = (_Float16*)alloc(2097152 * 2);
    _Float16* W63C    = (_Float16*)alloc(131072 * 2);
    _Float16* tmpA    = (_Float16*)alloc(524288 * 2);
    _Float16* tmpB    = (_Float16*)alloc(524288 * 2);

    const long ROWS = (long)Bc * 512;
    const long NBc  = ROWS * 512;
    float*    X      = (float*)alloc(NBc * 4);
    float*    O      = (float*)alloc(NBc * 4);
    _Float16* TSc    = (_Float16*)alloc(ROWS * 1024 * 2);
    _Float16* cX     = (_Float16*)alloc(ROWS * 1024 * 2);
    _Float16* cAgg   = (_Float16*)alloc(ROWS * 1024 * 2);
    _Float16* ENCcat = (_Float16*)alloc(ROWS * 1024 * 2);
    _Float16* bigcat = (_Float16*)alloc(ROWS * 2048 * 2);  // T cat / hidden hi
    float* H       = (float*)alloc(ROWS * 128 * 4);
    float* sinit   = (float*)alloc((long)Bc * 10752 * 4);
    float* tinit   = (float*)alloc((long)Bc * 10752 * 4);
    float* tfinal  = (float*)alloc((long)Bc * 10752 * 4);
    float* xmean   = (float*)alloc((long)Bc * 21 * 4);
    float* mc      = (float*)alloc((long)Bc * 512 * 4);
    float* cp      = (float*)alloc((long)Bc * 4096 * 4);
    float* wts     = (float*)alloc((long)Bc * 6 * 4);
    int*   delays  = (int*)alloc((long)Bc * 6 * 4);

    // ---- weight setup ----
    dim3 cb(256);
    const float QS = 64.f;
    // WqkC[e'][e] = QS^2 * sum_dk Wk[e',dk]*Wq[e,dk]  (B-operand for T = X@M)
    auto makeWqk = [&](const float* Wq, const float* Wk, _Float16* dst) {
        split2_k<<<128, cb, 0, stream>>>(Wk, tmpA, QS);
        split2_k<<<128, cb, 0, stream>>>(Wq, tmpB, QS);
        hgemm(0, 3, 1.f, tmpA,1024,512, tmpB,1024,512, nullptr, dst, 1024, 512,
              512, 512, 512, 1, 0,0,0, stream);
    };
    // WvoC[dout][e] = QS^2 * sum_dv Wo[dv,dout]*Wv[e,dv] (B-operand, osc 1/4096)
    auto makeWvo = [&](const float* Wv, const float* Wo, _Float16* dst) {
        convW2_k<<<dim3(16,16), cb, 0, stream>>>(Wo, tmpA, 512, 512, QS); // [dout][dv]
        split2_k<<<128, cb, 0, stream>>>(Wv, tmpB, QS);                   // [e][dv]
        hgemm(0, 3, 1.f, tmpA,1024,512, tmpB,1024,512, nullptr, dst, 1024, 512,
              512, 512, 512, 1, 0,0,0, stream);
    };
    for (int L = 0; L < 2; L++) {
        makeWqk(enc_Wq + (long)L*262144, enc_Wk + (long)L*262144, encWqkC + (long)L*524288);
        makeWvo(enc_Wv + (long)L*262144, enc_Wo + (long)L*262144, encWvoC + (long)L*524288);
        convW2_k<<<dim3(16,64), cb, 0, stream>>>(enc_W1 + (long)L*1048576, encW1C + (long)L*2097152, 2048, 512, 1.f);
        convW2_k<<<dim3(64,16), cb, 0, stream>>>(enc_W2 + (long)L*1048576, encW2C + (long)L*2097152, 512, 2048, 1.f);
    }
    makeWqk(sWq, sWk, dsWqkC);
    makeWvo(sWv, sWo, dsWvoC);
    makeWqk(cWq, cWk, dcWqkC);
    makeWvo(cWv, cWo, dcWvoC);
    convW2_k<<<dim3(16,64), cb, 0, stream>>>(dW1, dW1C, 2048, 512, 1.f);
    convW2_k<<<dim3(64,16), cb, 0, stream>>>(dW2, dW2C, 512, 2048, 1.f);
    convW63_k<<<256, cb, 0, stream>>>(dtW, W63C);

    const int M = (int)ROWS;
    const int t21 = Bc * 10752;
    const int gRows = Bc * 128;
    const long sCA = 512 * 1024;   // per-batch row stride (cat, ld 1024)
    const float IOS = 1.f / 4096.f;

    zero_k<<<(Bc*512 + 255)/256, 256, 0, stream>>>(mc, Bc*512);

    // attention: Cout = Xin + agg(KVcat)@Wvo; T = cQ@Wqk vs KVcat for corr.
    auto attn = [&](float* Xin, float* Cout, const _Float16* cQ,
                    const _Float16* KVcat, const _Float16* WqkC_,
                    const _Float16* WvoC_) {
        hgemm(0, 3, 1.f, cQ,1024,512, WqkC_,1024,512, nullptr, bigcat, 1024, 512,
              512, M, 512, 1, 0,0,0, stream);                              // T cat
        hgemm(20, 3, 1.f, bigcat,1024,512, KVcat,1024,512, nullptr, mc, 0, 0,
              512, 512, 512, Bc, sCA, sCA, 512, stream);                   // diag(T KV^T)
        topk_k<<<Bc, 256, 0, stream>>>(mc, delays, wts);
        agg2_k<<<gRows, 256, 0, stream>>>(KVcat, 1024, 0, 512, delays, wts, cAgg);
        hgemm(10, 2, IOS, cAgg,1024,512, WvoC_,1024,512, Xin, Cout, 512, 0,
              512, M, 512, 1, 0,0,0, stream);                              // += agg@Wvo
    };
    // ffn: Cout = Xin + gelu(Xin@W1)@W2 (hidden hi-only in bigcat, ld 2048)
    auto ffn = [&](float* Xin, float* Cout, const _Float16* cXin,
                   const _Float16* W1C, const _Float16* W2C) {
        hgemm(2, 2, 1.f, cXin,1024,512, W1C,1024,512, nullptr, bigcat, 2048, -1,
              512, M, 2048, 1, 0,0,0, stream);
        hgemm(10, 2, 1.f, bigcat,2048,0, W2C,4096,2048, Xin, Cout, 512, 0,
              2048, M, 512, 1, 0,0,0, stream);
    };

    for (int b0 = 0; b0 < 32; b0 += Bc) {
        const float* xe  = x_enc  + (long)b0 * 10752;
        const float* mke = xm_enc + (long)b0 * 2048;
        const float* mkd = xm_dec + (long)b0 * 2048;
        float* outp = (float*)d_out + (long)b0 * 5376;

        meanseq_k<<<(Bc*21 + 255)/256, 256, 0, stream>>>(xe, xmean, Bc*21);
        prep_k   <<<(t21 + 255)/256, 256, 0, stream>>>(xe, xmean, sinit, tinit, t21);

        // ---------------- encoder ----------------
        embed_k<<<dim3(64,2,Bc), 256, 0, stream>>>(xe, mke, enc_valW, enc_timeW, X, cX);
        for (int L = 0; L < 2; L++) {
            attn(X, O, cX, cX, encWqkC + (long)L*524288, encWvoC + (long)L*524288);
            decomp8_k<0,1><<<gRows, 256, 0, stream>>>(O, X, cX, nullptr);
            ffn(X, O, cX, encW1C + (long)L*2097152, encW2C + (long)L*2097152);
            decomp8_k<0,1><<<gRows, 256, 0, stream>>>(O, X, cX, nullptr);
        }
        ln_k      <<<Bc*512, 256, 0, stream>>>(X, enc_g, enc_b, O);
        colpart_k <<<dim3(2,8,Bc), 256, 0, stream>>>(O, cp);
        subcol8_k<1><<<gRows, 256, 0, stream>>>(O, cp, nullptr, ENCcat);

        // ---------------- decoder ----------------
        embed_k<<<dim3(64,2,Bc), 256, 0, stream>>>(sinit, mkd, dec_valW, dec_timeW, X, cX);

        // self attention
        attn(X, O, cX, cX, dsWqkC, dsWvoC);
        decomp8_k<2,1><<<gRows, 256, 0, stream>>>(O, X, cX, TSc);    // TSc = trend

        // cross attention (Q from dec stream, K/V role = ENCcat)
        attn(X, O, cX, ENCcat, dcWqkC, dcWvoC);
        decomp8_k<1,1><<<gRows, 256, 0, stream>>>(O, X, cX, TSc);    // TSc += trend

        // ffn
        ffn(X, O, cX, dW1C, dW2C);
        decomp8_k<1,0><<<gRows, 256, 0, stream>>>(O, X, nullptr, TSc);

        // trend conv as MFMA GEMM: H = (TSc @ W63x64)/64 (padded to 128 cols)
        hgemm(11, 2, 1.f/64.f, TSc,1024,512, W63C,1024,512, nullptr, H, 128, 0,
              512, M, 128, 1, 0,0,0, stream);
        shiftadd_k<<<(t21+255)/256, 256, 0, stream>>>(H, tinit, tfinal, t21);
        ln_k      <<<Bc*512, 256, 0, stream>>>(X, dec_g, dec_b, O);
        colpart_k <<<dim3(2,8,Bc), 256, 0, stream>>>(O, cp);
        subcol8_k<0><<<gRows, 256, 0, stream>>>(O, cp, O, nullptr);
        proj_k    <<<(Bc*5376+255)/256, 256, 0, stream>>>(O, projW, projB, tfinal, outp, Bc*5376);
    }
}

// Round 10
// 2576.555 us; speedup vs baseline: 3.3244x; 1.2016x over previous
//
#include <hip/hip_runtime.h>

// ---------------------------------------------------------------------------
// Autoformer forward, MI355X. Round 10: round-9 numerics + windowed decomp
// (4x less L2 traffic), batched weight setup (one batch=8 GEMM), fused tail.
// GEMM numerics: C = Ah*Bh + Ah*Bl (+ Al*Bh when nph=3), rows x 2K f16 [hi|lo].
// ---------------------------------------------------------------------------

typedef _Float16 h8 __attribute__((ext_vector_type(8)));
typedef _Float16 h4 __attribute__((ext_vector_type(4)));
typedef float f32x4 __attribute__((ext_vector_type(4)));

struct P12 { const float* p[12]; };
struct P4  { const float* p[4]; };

__device__ __forceinline__ float gelu_f(float x){
    return 0.5f * x * (1.0f + erff(x * 0.70710678118654752f));
}

__device__ __forceinline__ void gl_lds(const _Float16* gp, _Float16* lp) {
    __builtin_amdgcn_global_load_lds(
        (const __attribute__((address_space(1))) void*)gp,
        (__attribute__((address_space(3))) void*)lp, 16, 0, 0);
}

__global__ void zero_k(float* __restrict__ p, long n){
    long i = (long)blockIdx.x * 256 + threadIdx.x;
    if (i < n) p[i] = 0.f;
}

// ------------------------------ MFMA GEMM ----------------------------------
// A: M x 2K [hi|lo] (lda halfs, lo at +loA). B: N x 2K (ldb, +loB).
// nph phases x (K/64): (Ah,Bh),(Ah,Bl)[,(Al,Bh)]. f32 accum, *osc epilogue.
// OUT=0: f32 C (ldc floats); EPI 0 plain, 1 +R residual.
// OUT=1: f16 cat C (hi at row*ldc+col, lo at +loC; loC<0 -> hi only); EPI 0/2.
// OUT=2: diag reduce: atomicAdd mc[bz*sC + (row-col)&511].
template<int EPI, int OUT>
__global__ __launch_bounds__(256)
void hgemm_k(const _Float16* __restrict__ A, int lda, int loA,
             const _Float16* __restrict__ Bm, int ldb, int loB,
             const float* __restrict__ R, void* __restrict__ Cv,
             int ldc, int loC, int K, int nph, float osc,
             long sA, long sB, long sC)
{
    __shared__ _Float16 As[128 * 64];
    __shared__ _Float16 Bs[128 * 64];
    const int bz = blockIdx.z;
    const int tid = threadIdx.x, lane = tid & 63, w = tid >> 6;
    const int wr = w >> 1, wc = w & 1;
    const _Float16* Ap = A + bz * sA + (long)(blockIdx.y * 128) * lda;
    const _Float16* Bp = Bm + bz * sB + (long)(blockIdx.x * 128) * ldb;

    const int swz = ((lane & 7) ^ ((lane >> 3) & 7)) * 8;
    const int rsub = w * 32 + (lane >> 3);
    const _Float16* ApT = Ap + (long)rsub * lda + swz;
    const _Float16* BpT = Bp + (long)rsub * ldb + swz;
    _Float16* AsT = As + w * 2048;
    _Float16* BsT = Bs + w * 2048;

    const int tpp = K >> 6;
    const int nkt = tpp * nph;
    f32x4 acc[4][4] = {};

    int p = 0, q = 0;
    for (int kt = 0; kt < nkt; ++kt) {
        const int aoff = q * 64 + (p == 2 ? loA : 0);
        const int boff = q * 64 + (p == 1 ? loB : 0);
        __syncthreads();
#pragma unroll
        for (int i = 0; i < 4; i++) {
            gl_lds(ApT + (long)i * 8 * lda + aoff, AsT + i * 512);
            gl_lds(BpT + (long)i * 8 * ldb + boff, BsT + i * 512);
        }
        __syncthreads();
#pragma unroll
        for (int kk = 0; kk < 2; ++kk) {
            h8 af[4], bf[4];
            const int ks = kk * 4 + (lane >> 4);
#pragma unroll
            for (int m = 0; m < 4; m++) {
                int rowa = wr * 64 + m * 16 + (lane & 15);
                af[m] = *(const h8*)(As + rowa * 64 + ((ks ^ (rowa & 7)) * 8));
                int rowb = wc * 64 + m * 16 + (lane & 15);
                bf[m] = *(const h8*)(Bs + rowb * 64 + ((ks ^ (rowb & 7)) * 8));
            }
#pragma unroll
            for (int m = 0; m < 4; m++)
#pragma unroll
                for (int n = 0; n < 4; n++)
                    acc[m][n] = __builtin_amdgcn_mfma_f32_16x16x32_f16(af[m], bf[n], acc[m][n], 0, 0, 0);
        }
        if (++q == tpp) { q = 0; ++p; }
    }

    const int crow0 = blockIdx.y * 128 + wr * 64 + (lane >> 4) * 4;
    const int ccol0 = blockIdx.x * 128 + wc * 64 + (lane & 15);
    if constexpr (OUT == 0) {
        float* Cp = (float*)Cv + (long)bz * sC;
        const float* Rp = (EPI == 1) ? (R + (long)bz * sC) : nullptr;
#pragma unroll
        for (int m = 0; m < 4; m++)
#pragma unroll
            for (int n = 0; n < 4; n++) {
                int col = ccol0 + n * 16;
#pragma unroll
                for (int r2 = 0; r2 < 4; r2++) {
                    long idx = (long)(crow0 + m * 16 + r2) * ldc + col;
                    float v = acc[m][n][r2] * osc;
                    if (EPI == 1) v += Rp[idx];
                    Cp[idx] = v;
                }
            }
    } else if constexpr (OUT == 1) {
        _Float16* Cp = (_Float16*)Cv + (long)bz * sC;
#pragma unroll
        for (int m = 0; m < 4; m++)
#pragma unroll
            for (int n = 0; n < 4; n++) {
                int col = ccol0 + n * 16;
#pragma unroll
                for (int r2 = 0; r2 < 4; r2++) {
                    long base = (long)(crow0 + m * 16 + r2) * ldc + col;
                    float v = acc[m][n][r2] * osc;
                    if (EPI == 2) v = gelu_f(v);
                    _Float16 hi = (_Float16)v;
                    Cp[base] = hi;
                    if (loC >= 0) Cp[base + loC] = (_Float16)(v - (float)hi);
                }
            }
    } else {
        __shared__ float diag[512];
        float* mc = (float*)Cv + (long)bz * sC;
        for (int t = tid; t < 512; t += 256) diag[t] = 0.f;
        __syncthreads();
#pragma unroll
        for (int m = 0; m < 4; m++)
#pragma unroll
            for (int n = 0; n < 4; n++) {
                int col = ccol0 + n * 16;
#pragma unroll
                for (int r2 = 0; r2 < 4; r2++) {
                    int row = crow0 + m * 16 + r2;
                    atomicAdd(&diag[(row - col) & 511], acc[m][n][r2]);
                }
            }
        __syncthreads();
        for (int t = tid; t < 512; t += 256) {
            float v = diag[t];
            if (v != 0.f) atomicAdd(&mc[t], v);
        }
    }
}

// ------------------------- weight conversion -------------------------------
// 12 plain splits (512x512 each): m<4 -> PA[2m] (Wk); m in 4..7 -> PB[2(m-4)]
// (Wq); m in 8..11 -> PB[2(m-8)+1] (Wv). All scaled x64. grid (128, 12).
__global__ __launch_bounds__(256)
void splitAll_k(P12 ps, _Float16* __restrict__ PA, _Float16* __restrict__ PB)
{
    const int m = blockIdx.y;
    const float* __restrict__ src = ps.p[m];
    _Float16* dst;
    if (m < 4)      dst = PA + (long)(2 * m) * 524288;
    else if (m < 8) dst = PB + (long)(2 * (m - 4)) * 524288;
    else            dst = PB + (long)(2 * (m - 8) + 1) * 524288;
    long t = (long)blockIdx.x * 256 + threadIdx.x;
    long row = t >> 6; int kc = (int)(t & 63) * 8;
    const float4 v0 = *(const float4*)(src + row * 512 + kc);
    const float4 v1 = *(const float4*)(src + row * 512 + kc + 4);
    float vv[8] = {v0.x,v0.y,v0.z,v0.w,v1.x,v1.y,v1.z,v1.w};
    h8 hi, lo;
#pragma unroll
    for (int j = 0; j < 8; j++) {
        float s = vv[j] * 64.f;
        _Float16 h = (_Float16)s;
        hi[j] = h; lo[j] = (_Float16)(s - (float)h);
    }
    *(h8*)(dst + row * 1024 + kc)       = hi;
    *(h8*)(dst + row * 1024 + 512 + kc) = lo;
}

// 4 transposed converts (Wo, 512x512): z -> PA[2z+1], scaled x64. grid(16,16,4)
__global__ __launch_bounds__(256)
void convWoAll_k(P4 ps, _Float16* __restrict__ PA)
{
    const int z = blockIdx.z;
    const float* __restrict__ src = ps.p[z];
    _Float16* dst = PA + (long)(2 * z + 1) * 524288;
    __shared__ float t[32][33];
    int k0 = blockIdx.x * 32, n0 = blockIdx.y * 32, tid = threadIdx.x;
#pragma unroll
    for (int i = 0; i < 4; i++) {
        int lin = tid + i * 256; int r = lin >> 5, c = lin & 31;
        t[r][c] = src[(long)(k0 + r) * 512 + n0 + c];
    }
    __syncthreads();
#pragma unroll
    for (int i = 0; i < 4; i++) {
        int lin = tid + i * 256; int n = lin >> 5, k = lin & 31;
        float v = t[k][n] * 64.f;
        _Float16 hi = (_Float16)v;
        long base = (long)(n0 + n) * 1024 + k0 + k;
        dst[base]       = hi;
        dst[base + 512] = (_Float16)(v - (float)hi);
    }
}

// W (K x N f32) -> dst (N rows x 2K f16 cat). grid (K/32, N/32)
__global__ __launch_bounds__(256)
void convW2_k(const float* __restrict__ src, _Float16* __restrict__ dst,
              int N, int K)
{
    __shared__ float t[32][33];
    int k0 = blockIdx.x * 32, n0 = blockIdx.y * 32, tid = threadIdx.x;
#pragma unroll
    for (int i = 0; i < 4; i++) {
        int lin = tid + i * 256; int r = lin >> 5, c = lin & 31;
        t[r][c] = src[(long)(k0 + r) * N + n0 + c];
    }
    __syncthreads();
#pragma unroll
    for (int i = 0; i < 4; i++) {
        int lin = tid + i * 256; int n = lin >> 5, k = lin & 31;
        float v = t[k][n];
        _Float16 hi = (_Float16)v;
        long base = (long)(n0 + n) * 2 * K + k0 + k;
        dst[base]     = hi;
        dst[base + K] = (_Float16)(v - (float)hi);
    }
}

// dtW (3 x 512 x 21) -> 128 rows x 1024 cat, x64 (row j = t*21+c, zero-pad)
__global__ void convW63_k(const float* __restrict__ W, _Float16* __restrict__ dst)
{
    int i = blockIdx.x * 256 + threadIdx.x;   // 65536
    int k = i & 511, j = i >> 9;
    float v = (j < 63) ? 64.f * W[(long)(j / 21) * 10752 + (long)k * 21 + (j % 21)] : 0.f;
    _Float16 hi = (_Float16)v;
    dst[(long)j * 1024 + k]       = hi;
    dst[(long)j * 1024 + 512 + k] = (_Float16)(v - (float)hi);
}

// ------------------------- embedding (conv3 + mark + pe + cat) -------------
__global__ __launch_bounds__(256)
void embed_k(const float* __restrict__ x, const float* __restrict__ mark,
             const float* __restrict__ valW, const float* __restrict__ timeW,
             float* __restrict__ out, _Float16* __restrict__ cat)
{
    const int lg = blockIdx.x, dh = blockIdx.y, b = blockIdx.z;
    const int tid = threadIdx.x;
    const int dd = dh * 256 + tid;
    const int l0 = lg * 8;
    __shared__ float xs[10][21];
    __shared__ float mk[8][4];
    if (tid < 210) {
        int r = tid / 21, c = tid % 21;
        int ll = (l0 - 1 + r + 512) & 511;
        xs[r][c] = x[((long)b * 512 + ll) * 21 + c];
    }
    if (tid >= 224 && tid < 256) {
        int t2 = tid - 224, il = t2 >> 2, m = t2 & 3;
        mk[il][m] = mark[((long)b * 512 + l0 + il) * 4 + m];
    }
    __syncthreads();
    float acc[8];
#pragma unroll
    for (int il = 0; il < 8; il++) acc[il] = 0.f;
    for (int t = 0; t < 3; t++)
        for (int c = 0; c < 21; c++) {
            float w = valW[(t * 21 + c) * 512 + dd];
#pragma unroll
            for (int il = 0; il < 8; il++)
                acc[il] = fmaf(xs[il + t][c], w, acc[il]);
        }
    for (int m = 0; m < 4; m++) {
        float w = timeW[m * 512 + dd];
#pragma unroll
        for (int il = 0; il < 8; il++)
            acc[il] = fmaf(mk[il][m], w, acc[il]);
    }
    const float freq = expf((float)(dd & ~1) * (-9.210340371976184f / 512.0f));
#pragma unroll
    for (int il = 0; il < 8; il++) {
        float ang = (float)(l0 + il) * freq;
        float pe = (dd & 1) ? cosf(ang) : sinf(ang);
        float v = acc[il] + pe;
        long row = (long)b * 512 + l0 + il;
        out[row * 512 + dd] = v;
        _Float16 hi = (_Float16)v;
        cat[row * 1024 + dd]       = hi;
        cat[row * 1024 + 512 + dd] = (_Float16)(v - (float)hi);
    }
}

// ------------------- windowed decomp (8 rows/thread, D=512) ----------------
// TREND: 0 none, 1 TSc += trend (cat), 2 TSc = trend (cat). CAT: seasonal cat.
// Thread: batch b, 8 consecutive l's (l0..l0+7), 4 d's. Streams 32 rows.
template<int TREND, int CAT>
__global__ __launch_bounds__(256)
void decompW_k(const float* __restrict__ x, float* __restrict__ out,
               _Float16* __restrict__ cat, _Float16* __restrict__ tsc)
{
    long t = (long)blockIdx.x * 256 + threadIdx.x;
    long rowg = t >> 7; int d4 = (int)(t & 127) * 4;
    int lg = (int)(rowg & 63); long b = rowg >> 6;
    const int l0 = lg * 8;
    const float* xb = x + (b << 18);
    float s[8][4] = {};
    float xo[8][4];
#pragma unroll
    for (int rr = -12; rr <= 19; rr++) {
        int rc = l0 + rr; rc = rc < 0 ? 0 : (rc > 511 ? 511 : rc);
        float4 v = *(const float4*)(xb + ((long)rc << 9) + d4);
        float vv[4] = {v.x, v.y, v.z, v.w};
#pragma unroll
        for (int i = 0; i < 8; i++) {
            if (i >= rr - 12 && i <= rr + 12) {
#pragma unroll
                for (int j = 0; j < 4; j++) s[i][j] += vv[j];
            }
        }
        if (rr >= 0 && rr < 8) {
#pragma unroll
            for (int j = 0; j < 4; j++) xo[rr][j] = vv[j];
        }
    }
#pragma unroll
    for (int i = 0; i < 8; i++) {
        long row = b * 512 + l0 + i;
        float tr[4], ov[4];
#pragma unroll
        for (int j = 0; j < 4; j++) {
            tr[j] = s[i][j] * (1.f / 25.f);
            ov[j] = xo[i][j] - tr[j];
        }
        *(float4*)(out + row * 512 + d4) = make_float4(ov[0], ov[1], ov[2], ov[3]);
        if (CAT) {
            h4 hi, lo;
#pragma unroll
            for (int j = 0; j < 4; j++) {
                _Float16 h = (_Float16)ov[j];
                hi[j] = h; lo[j] = (_Float16)(ov[j] - (float)h);
            }
            *(h4*)(cat + row * 1024 + d4)       = hi;
            *(h4*)(cat + row * 1024 + 512 + d4) = lo;
        }
        if (TREND) {
            _Float16* tp = tsc + row * 1024 + d4;
            if (TREND == 1) {
                h4 th = *(h4*)tp, tl = *(h4*)(tp + 512);
#pragma unroll
                for (int j = 0; j < 4; j++) tr[j] += (float)th[j] + (float)tl[j];
            }
            h4 th2, tl2;
#pragma unroll
            for (int j = 0; j < 4; j++) {
                _Float16 h = (_Float16)tr[j];
                th2[j] = h; tl2[j] = (_Float16)(tr[j] - (float)h);
            }
            *(h4*)tp         = th2;
            *(h4*)(tp + 512) = tl2;
        }
    }
}

// ------------------------- prep (mean + decomp tail + inits) ---------------
__global__ void meanseq_k(const float* __restrict__ x, float* __restrict__ xm, int total)
{
    int i = blockIdx.x * 256 + threadIdx.x;
    if (i >= total) return;
    int c = i % 21, b = i / 21;
    float s = 0.f;
    for (int l = 0; l < 512; l++) s += x[((long)b * 512 + l) * 21 + c];
    xm[i] = s * (1.f / 512.f);
}

__global__ void prep_k(const float* __restrict__ x, const float* __restrict__ xm,
                       float* __restrict__ sinit, float* __restrict__ tinit, int total)
{
    int i = blockIdx.x * 256 + threadIdx.x;
    if (i >= total) return;
    int c = i % 21, l = (i / 21) % 512, b = i / 10752;
    if (l < 256) {
        int lc = 256 + l;
        float s = 0.f;
        for (int j = -12; j <= 12; j++) {
            int ll = lc + j; ll = ll > 511 ? 511 : ll;
            s += x[((long)b * 512 + ll) * 21 + c];
        }
        float t = s * (1.f / 25.f);
        tinit[i] = t;
        sinit[i] = x[((long)b * 512 + lc) * 21 + c] - t;
    } else {
        sinit[i] = 0.f;
        tinit[i] = xm[b * 21 + c];
    }
}

// ------------------------- top-k (scaled mc; self-cleans) ------------------
__global__ __launch_bounds__(256)
void topk_k(float* __restrict__ mc, int* __restrict__ delays,
            float* __restrict__ wts)
{
    const float SCL = 1.f / (512.f * 4096.f);  // 1/512 mean, 1/(64*64) prescale
    int b = blockIdx.x, tid = threadIdx.x;
    __shared__ float v[512];
    __shared__ float rv[256];
    __shared__ int   ri[256];
    __shared__ float selv[6];
    v[tid]       = mc[b * 512 + tid]       * SCL;
    v[tid + 256] = mc[b * 512 + tid + 256] * SCL;
    mc[b * 512 + tid] = 0.f;
    mc[b * 512 + tid + 256] = 0.f;
    __syncthreads();
    for (int p = 0; p < 6; p++) {
        float bv = v[tid]; int bi = tid;
        float v2 = v[tid + 256];
        if (v2 > bv) { bv = v2; bi = tid + 256; }
        rv[tid] = bv; ri[tid] = bi;
        __syncthreads();
        for (int s = 128; s > 0; s >>= 1) {
            if (tid < s) {
                float ov = rv[tid + s]; int oi = ri[tid + s];
                if (ov > rv[tid] || (ov == rv[tid] && oi < ri[tid])) {
                    rv[tid] = ov; ri[tid] = oi;
                }
            }
            __syncthreads();
        }
        if (tid == 0) { selv[p] = rv[0]; delays[b * 6 + p] = ri[0]; v[ri[0]] = -3.4e38f; }
        __syncthreads();
    }
    if (tid == 0) {
        float mx = selv[0];
        for (int p = 1; p < 6; p++) mx = fmaxf(mx, selv[p]);
        float e[6], sum = 0.f;
        for (int p = 0; p < 6; p++) { e[p] = expf(selv[p] - mx); sum += e[p]; }
        for (int p = 0; p < 6; p++) wts[b * 6 + p] = e[p] / sum;
    }
}

// gather-agg from cat source; write cat out (rows x 1024)
__global__ __launch_bounds__(256)
void agg2_k(const _Float16* __restrict__ Vc, int vld, int vhi, int vlo,
            const int* __restrict__ delays, const float* __restrict__ wts,
            _Float16* __restrict__ out)
{
    long t = (long)blockIdx.x * 256 + threadIdx.x;
    int dc = (int)(t & 63);
    long row = t >> 6;
    int l = (int)(row & 511), b = (int)(row >> 9);
    float s[8] = {};
#pragma unroll
    for (int k = 0; k < 6; k++) {
        int dl = delays[b * 6 + k];
        float wv = wts[b * 6 + k];
        long sr = ((long)b * 512 + ((l + dl) & 511)) * vld + dc * 8;
        h8 hi8 = *(const h8*)(Vc + sr + vhi);
        h8 lo8 = *(const h8*)(Vc + sr + vlo);
#pragma unroll
        for (int j = 0; j < 8; j++)
            s[j] = fmaf(wv, (float)hi8[j] + (float)lo8[j], s[j]);
    }
    h8 ho, lo;
#pragma unroll
    for (int j = 0; j < 8; j++) {
        _Float16 h = (_Float16)s[j];
        ho[j] = h; lo[j] = (_Float16)(s[j] - (float)h);
    }
    long ob = row * 1024 + dc * 8;
    *(h8*)(out + ob)       = ho;
    *(h8*)(out + ob + 512) = lo;
}

// ------------------------- seasonal layernorm ------------------------------
__global__ __launch_bounds__(256)
void ln_k(const float* __restrict__ x, const float* __restrict__ g,
          const float* __restrict__ be, float* __restrict__ out)
{
    int row = blockIdx.x, tid = threadIdx.x;
    const float* xr = x + ((long)row << 9);
    float v0 = xr[tid], v1 = xr[tid + 256];
    __shared__ float rs[256];
    rs[tid] = v0 + v1; __syncthreads();
    for (int s = 128; s > 0; s >>= 1) { if (tid < s) rs[tid] += rs[tid + s]; __syncthreads(); }
    float mu = rs[0] * (1.f / 512.f);
    __syncthreads();
    float d0 = v0 - mu, d1 = v1 - mu;
    rs[tid] = d0 * d0 + d1 * d1; __syncthreads();
    for (int s = 128; s > 0; s >>= 1) { if (tid < s) rs[tid] += rs[tid + s]; __syncthreads(); }
    float rstd = 1.0f / sqrtf(rs[0] * (1.f / 512.f) + 1e-5f);
    out[((long)row << 9) + tid]       = d0 * rstd * g[tid] + be[tid];
    out[((long)row << 9) + tid + 256] = d1 * rstd * g[tid + 256] + be[tid + 256];
}

__global__ void colpart_k(const float* __restrict__ x, float* __restrict__ cp)
{
    int d = blockIdx.x * 256 + threadIdx.x;   // grid (2, 8, Bc)
    int ch = blockIdx.y, b = blockIdx.z;
    const float* xb = x + ((long)b << 18);
    float s = 0.f;
    for (int l = ch * 64; l < ch * 64 + 64; l++) s += xb[((long)l << 9) + d];
    cp[((long)(b * 8 + ch) << 9) + d] = s;
}

__global__ void colmean_k(const float* __restrict__ cp, float* __restrict__ cm, int total)
{
    int i = blockIdx.x * 256 + threadIdx.x;
    if (i >= total) return;
    int d = i & 511, b = i >> 9;
    float s = 0.f;
#pragma unroll
    for (int ch = 0; ch < 8; ch++) s += cp[((long)(b * 8 + ch) << 9) + d];
    cm[i] = s * (1.f / 512.f);
}

// write hi/lo cat of (x - colmean) — encoder tail
__global__ __launch_bounds__(256)
void subcolcat_k(const float* __restrict__ x, const float* __restrict__ cp,
                 _Float16* __restrict__ cat)
{
    long t = (long)blockIdx.x * 256 + threadIdx.x;
    long row = t >> 6; int d8 = (int)(t & 63) * 8;
    int b = (int)(row >> 9);
    float m[8] = {};
#pragma unroll
    for (int ch = 0; ch < 8; ch++) {
        const float4* c4 = (const float4*)(cp + ((long)(b * 8 + ch) << 9) + d8);
        float4 c0 = c4[0], c1 = c4[1];
        m[0]+=c0.x; m[1]+=c0.y; m[2]+=c0.z; m[3]+=c0.w;
        m[4]+=c1.x; m[5]+=c1.y; m[6]+=c1.z; m[7]+=c1.w;
    }
    const float4* xp = (const float4*)(x + row * 512 + d8);
    float4 x0 = xp[0], x1 = xp[1];
    float v[8] = {x0.x,x0.y,x0.z,x0.w,x1.x,x1.y,x1.z,x1.w};
    h8 hi, lo;
#pragma unroll
    for (int j = 0; j < 8; j++) {
        float vv = v[j] - m[j] * (1.f / 512.f);
        _Float16 h = (_Float16)vv;
        hi[j] = h; lo[j] = (_Float16)(vv - (float)h);
    }
    *(h8*)(cat + row * 1024 + d8)       = hi;
    *(h8*)(cat + row * 1024 + 512 + d8) = lo;
}

// ------------------------- trend shift-add + projection --------------------
__global__ void shiftadd_k(const float* __restrict__ H, const float* __restrict__ tinit,
                           float* __restrict__ tf, int total)
{
    int i = blockIdx.x * 256 + threadIdx.x;
    if (i >= total) return;
    int c = i % 21, l = (i / 21) % 512, b = i / 10752;
    long r = (long)b * 512;
    tf[i] = tinit[i]
          + H[(r + ((l + 511) & 511)) * 128 + c]
          + H[(r + l) * 128 + 21 + c]
          + H[(r + ((l + 1) & 511)) * 128 + 42 + c];
}

// proj with fused column-mean subtraction (decoder tail)
__global__ void proj_k(const float* __restrict__ x, const float* __restrict__ cm,
                       const float* __restrict__ pw, const float* __restrict__ pb,
                       const float* __restrict__ trend, float* __restrict__ out, int total)
{
    int i = blockIdx.x * 256 + threadIdx.x;
    if (i >= total) return;
    int c = i % 21, l = (i / 21) % 256 + 256, b = i / 5376;
    const float* xr = x + ((long)(b * 512 + l) << 9);
    const float* cmb = cm + ((long)b << 9);
    float s = 0.f;
    for (int d = 0; d < 512; d++) s = fmaf(xr[d] - cmb[d], pw[d * 21 + c], s);
    out[i] = s + pb[c] + trend[((long)b * 512 + l) * 21 + c];
}

// ---------------------------------------------------------------------------
// mode: 0 OUT1 cat, 2 OUT1 gelu-cat, 10 OUT0 +R, 11 OUT0 plain, 20 Scorr
static void hgemm(int mode, int nph, float osc,
                  const _Float16* A, int lda, int loA,
                  const _Float16* B, int ldb, int loB,
                  const float* R, void* C, int ldc, int loC,
                  int K, int M, int N, int batch,
                  long sA, long sB, long sC, hipStream_t st)
{
    dim3 g(N / 128, M / 128, batch), blk(256);
    switch (mode) {
    case 0:  hgemm_k<0,1><<<g,blk,0,st>>>(A,lda,loA,B,ldb,loB,R,C,ldc,loC,K,nph,osc,sA,sB,sC); break;
    case 2:  hgemm_k<2,1><<<g,blk,0,st>>>(A,lda,loA,B,ldb,loB,R,C,ldc,loC,K,nph,osc,sA,sB,sC); break;
    case 10: hgemm_k<1,0><<<g,blk,0,st>>>(A,lda,loA,B,ldb,loB,R,C,ldc,loC,K,nph,osc,sA,sB,sC); break;
    case 11: hgemm_k<0,0><<<g,blk,0,st>>>(A,lda,loA,B,ldb,loB,R,C,ldc,loC,K,nph,osc,sA,sB,sC); break;
    default: hgemm_k<0,2><<<g,blk,0,st>>>(A,lda,loA,B,ldb,loB,R,C,ldc,loC,K,nph,osc,sA,sB,sC); break;
    }
}

extern "C" void kernel_launch(void* const* d_in, const int* in_sizes, int n_in,
                              void* d_out, int out_size, void* d_ws, size_t ws_size,
                              hipStream_t stream)
{
    const float* x_enc    = (const float*)d_in[0];
    const float* xm_enc   = (const float*)d_in[1];
    const float* xm_dec   = (const float*)d_in[3];
    const float* enc_valW = (const float*)d_in[4];
    const float* enc_timeW= (const float*)d_in[5];
    const float* enc_Wq   = (const float*)d_in[6];
    const float* enc_Wk   = (const float*)d_in[7];
    const float* enc_Wv   = (const float*)d_in[8];
    const float* enc_Wo   = (const float*)d_in[9];
    const float* enc_W1   = (const float*)d_in[10];
    const float* enc_W2   = (const float*)d_in[11];
    const float* enc_g    = (const float*)d_in[12];
    const float* enc_b    = (const float*)d_in[13];
    const float* dec_valW = (const float*)d_in[14];
    const float* dec_timeW= (const float*)d_in[15];
    const float* sWq = (const float*)d_in[16];
    const float* sWk = (const float*)d_in[17];
    const float* sWv = (const float*)d_in[18];
    const float* sWo = (const float*)d_in[19];
    const float* cWq = (const float*)d_in[20];
    const float* cWk = (const float*)d_in[21];
    const float* cWv = (const float*)d_in[22];
    const float* cWo = (const float*)d_in[23];
    const float* dW1 = (const float*)d_in[24];
    const float* dW2 = (const float*)d_in[25];
    const float* dtW = (const float*)d_in[26];
    const float* dec_g = (const float*)d_in[27];
    const float* dec_b = (const float*)d_in[28];
    const float* projW = (const float*)d_in[29];
    const float* projB = (const float*)d_in[30];

    // ---- batch-chunk sizing (deterministic) ----
    const size_t W_BYTES = 50000000;   // Wcat8 + W1/W2 cats + W63 + PA/PB
    const size_t perB = 8900000;
    int Bc = 32;
    while (Bc > 1 && W_BYTES + (size_t)Bc * perB + (4u << 20) > ws_size) Bc >>= 1;

    char* wp = (char*)d_ws;
    auto alloc = [&](size_t bytes) { char* p = wp; wp += (bytes + 255) & ~(size_t)255; return p; };

    // weight buffers
    _Float16* Wcat8  = (_Float16*)alloc(8 * 524288 * 2);   // qk/vo products (cat)
    _Float16* encW1C = (_Float16*)alloc(2 * 2097152 * 2);
    _Float16* encW2C = (_Float16*)alloc(2 * 2097152 * 2);
    _Float16* dW1C   = (_Float16*)alloc(2097152 * 2);
    _Float16* dW2C   = (_Float16*)alloc(2097152 * 2);
    _Float16* W63C   = (_Float16*)alloc(131072 * 2);
    _Float16* PA     = (_Float16*)alloc(8 * 524288 * 2);   // setup staging
    _Float16* PB     = (_Float16*)alloc(8 * 524288 * 2);

    const long ROWS = (long)Bc * 512;
    const long NBc  = ROWS * 512;
    float*    X      = (float*)alloc(NBc * 4);
    float*    O      = (float*)alloc(NBc * 4);
    _Float16* TSc    = (_Float16*)alloc(ROWS * 1024 * 2);
    _Float16* cX     = (_Float16*)alloc(ROWS * 1024 * 2);
    _Float16* cAgg   = (_Float16*)alloc(ROWS * 1024 * 2);
    _Float16* ENCcat = (_Float16*)alloc(ROWS * 1024 * 2);
    _Float16* bigcat = (_Float16*)alloc(ROWS * 2048 * 2);  // T cat / hidden hi
    float* H       = (float*)alloc(ROWS * 128 * 4);
    float* sinit   = (float*)alloc((long)Bc * 10752 * 4);
    float* tinit   = (float*)alloc((long)Bc * 10752 * 4);
    float* tfinal  = (float*)alloc((long)Bc * 10752 * 4);
    float* xmean   = (float*)alloc((long)Bc * 21 * 4);
    float* mc      = (float*)alloc((long)Bc * 512 * 4);
    float* cp      = (float*)alloc((long)Bc * 4096 * 4);
    float* cm      = (float*)alloc((long)Bc * 512 * 4);
    float* wts     = (float*)alloc((long)Bc * 6 * 4);
    int*   delays  = (int*)alloc((long)Bc * 6 * 4);

    // ---- weight setup (batched): attn order {enc0, enc1, self, cross} ----
    dim3 cb(256);
    P12 sp;
    sp.p[0] = enc_Wk;           sp.p[1] = enc_Wk + 262144;
    sp.p[2] = sWk;              sp.p[3] = cWk;
    sp.p[4] = enc_Wq;           sp.p[5] = enc_Wq + 262144;
    sp.p[6] = sWq;              sp.p[7] = cWq;
    sp.p[8] = enc_Wv;           sp.p[9] = enc_Wv + 262144;
    sp.p[10] = sWv;             sp.p[11] = cWv;
    P4 op;
    op.p[0] = enc_Wo;           op.p[1] = enc_Wo + 262144;
    op.p[2] = sWo;              op.p[3] = cWo;
    splitAll_k <<<dim3(128,12), cb, 0, stream>>>(sp, PA, PB);
    convWoAll_k<<<dim3(16,16,4), cb, 0, stream>>>(op, PA);
    // one batched GEMM: 8 x (512x512x512 cat products), nph=3
    hgemm(0, 3, 1.f, PA,1024,512, PB,1024,512, nullptr, Wcat8, 1024, 512,
          512, 512, 512, 8, 524288, 524288, 524288, stream);
    for (int L = 0; L < 2; L++) {
        convW2_k<<<dim3(16,64), cb, 0, stream>>>(enc_W1 + (long)L*1048576, encW1C + (long)L*2097152, 2048, 512);
        convW2_k<<<dim3(64,16), cb, 0, stream>>>(enc_W2 + (long)L*1048576, encW2C + (long)L*2097152, 512, 2048);
    }
    convW2_k<<<dim3(16,64), cb, 0, stream>>>(dW1, dW1C, 2048, 512);
    convW2_k<<<dim3(64,16), cb, 0, stream>>>(dW2, dW2C, 512, 2048);
    convW63_k<<<256, cb, 0, stream>>>(dtW, W63C);

    const int M = (int)ROWS;
    const int t21 = Bc * 10752;
    const int gRows = Bc * 128;      // 8-wide elementwise grids (per-row)
    const int gW = Bc * 32;          // decompW grid
    const long sCA = 512 * 1024;
    const float IOS = 1.f / 4096.f;

    zero_k<<<(Bc*512 + 255)/256, 256, 0, stream>>>(mc, Bc*512);

    // attention: Cout = Xin + agg(KVcat)@Wvo; T = cQ@Wqk vs KVcat for corr.
    auto attn = [&](float* Xin, float* Cout, const _Float16* cQ,
                    const _Float16* KVcat, int slot) {
        const _Float16* WqkC_ = Wcat8 + (long)(2*slot)     * 524288;
        const _Float16* WvoC_ = Wcat8 + (long)(2*slot + 1) * 524288;
        hgemm(0, 3, 1.f, cQ,1024,512, WqkC_,1024,512, nullptr, bigcat, 1024, 512,
              512, M, 512, 1, 0,0,0, stream);                              // T cat
        hgemm(20, 3, 1.f, bigcat,1024,512, KVcat,1024,512, nullptr, mc, 0, 0,
              512, 512, 512, Bc, sCA, sCA, 512, stream);                   // diag(T KV^T)
        topk_k<<<Bc, 256, 0, stream>>>(mc, delays, wts);
        agg2_k<<<gRows, 256, 0, stream>>>(KVcat, 1024, 0, 512, delays, wts, cAgg);
        hgemm(10, 2, IOS, cAgg,1024,512, WvoC_,1024,512, Xin, Cout, 512, 0,
              512, M, 512, 1, 0,0,0, stream);                              // += agg@Wvo
    };
    auto ffn = [&](float* Xin, float* Cout, const _Float16* cXin,
                   const _Float16* W1C, const _Float16* W2C) {
        hgemm(2, 2, 1.f, cXin,1024,512, W1C,1024,512, nullptr, bigcat, 2048, -1,
              512, M, 2048, 1, 0,0,0, stream);
        hgemm(10, 2, 1.f, bigcat,2048,0, W2C,4096,2048, Xin, Cout, 512, 0,
              2048, M, 512, 1, 0,0,0, stream);
    };

    for (int b0 = 0; b0 < 32; b0 += Bc) {
        const float* xe  = x_enc  + (long)b0 * 10752;
        const float* mke = xm_enc + (long)b0 * 2048;
        const float* mkd = xm_dec + (long)b0 * 2048;
        float* outp = (float*)d_out + (long)b0 * 5376;

        meanseq_k<<<(Bc*21 + 255)/256, 256, 0, stream>>>(xe, xmean, Bc*21);
        prep_k   <<<(t21 + 255)/256, 256, 0, stream>>>(xe, xmean, sinit, tinit, t21);

        // ---------------- encoder ----------------
        embed_k<<<dim3(64,2,Bc), 256, 0, stream>>>(xe, mke, enc_valW, enc_timeW, X, cX);
        for (int L = 0; L < 2; L++) {
            attn(X, O, cX, cX, L);
            decompW_k<0,1><<<gW, 256, 0, stream>>>(O, X, cX, nullptr);
            ffn(X, O, cX, encW1C + (long)L*2097152, encW2C + (long)L*2097152);
            decompW_k<0,1><<<gW, 256, 0, stream>>>(O, X, cX, nullptr);
        }
        ln_k      <<<Bc*512, 256, 0, stream>>>(X, enc_g, enc_b, O);
        colpart_k <<<dim3(2,8,Bc), 256, 0, stream>>>(O, cp);
        subcolcat_k<<<gRows, 256, 0, stream>>>(O, cp, ENCcat);

        // ---------------- decoder ----------------
        embed_k<<<dim3(64,2,Bc), 256, 0, stream>>>(sinit, mkd, dec_valW, dec_timeW, X, cX);

        // self attention
        attn(X, O, cX, cX, 2);
        decompW_k<2,1><<<gW, 256, 0, stream>>>(O, X, cX, TSc);       // TSc = trend

        // cross attention (Q from dec stream, K/V role = ENCcat)
        attn(X, O, cX, ENCcat, 3);
        decompW_k<1,1><<<gW, 256, 0, stream>>>(O, X, cX, TSc);       // TSc += trend

        // ffn
        ffn(X, O, cX, dW1C, dW2C);
        decompW_k<1,0><<<gW, 256, 0, stream>>>(O, X, nullptr, TSc);

        // trend conv as MFMA GEMM: H = (TSc @ W63x64)/64 (padded to 128 cols)
        hgemm(11, 2, 1.f/64.f, TSc,1024,512, W63C,1024,512, nullptr, H, 128, 0,
              512, M, 128, 1, 0,0,0, stream);
        shiftadd_k<<<(t21+255)/256, 256, 0, stream>>>(H, tinit, tfinal, t21);
        ln_k      <<<Bc*512, 256, 0, stream>>>(X, dec_g, dec_b, O);
        colpart_k <<<dim3(2,8,Bc), 256, 0, stream>>>(O, cp);
        colmean_k <<<(Bc*512+255)/256, 256, 0, stream>>>(cp, cm, Bc*512);
        proj_k    <<<(Bc*5376+255)/256, 256, 0, stream>>>(O, cm, projW, projB, tfinal, outp, Bc*5376);
    }
}

// Round 11
// 2212.916 us; speedup vs baseline: 3.8707x; 1.1643x over previous
//
#include <hip/hip_runtime.h>

// ---------------------------------------------------------------------------
// Autoformer forward, MI355X. Round 11: 1-phase (pure-f16-weight) FFN/Wvo/trend
// GEMMs (top-k path stays 3-phase), hi-only agg gather, fused tail kernels.
// GEMM numerics: C = Ah*Bh [+ Ah*Bl [+ Al*Bh]], operands rows x 2K f16 [hi|lo].
// ---------------------------------------------------------------------------

typedef _Float16 h8 __attribute__((ext_vector_type(8)));
typedef _Float16 h4 __attribute__((ext_vector_type(4)));
typedef float f32x4 __attribute__((ext_vector_type(4)));

struct P12 { const float* p[12]; };
struct P4  { const float* p[4]; };

__device__ __forceinline__ float gelu_f(float x){
    return 0.5f * x * (1.0f + erff(x * 0.70710678118654752f));
}

__device__ __forceinline__ void gl_lds(const _Float16* gp, _Float16* lp) {
    __builtin_amdgcn_global_load_lds(
        (const __attribute__((address_space(1))) void*)gp,
        (__attribute__((address_space(3))) void*)lp, 16, 0, 0);
}

__global__ void zero_k(float* __restrict__ p, long n){
    long i = (long)blockIdx.x * 256 + threadIdx.x;
    if (i < n) p[i] = 0.f;
}

// ------------------------------ MFMA GEMM ----------------------------------
// A: M x 2K [hi|lo] (lda halfs, lo at +loA). B: N x 2K (ldb, +loB).
// nph phases x (K/64): (Ah,Bh)[,(Ah,Bl)[,(Al,Bh)]]. f32 accum, *osc epilogue.
// OUT=0: f32 C (ldc floats); EPI 0 plain, 1 +R residual.
// OUT=1: f16 cat C (hi at row*ldc+col, lo at +loC; loC<0 -> hi only); EPI 0/2.
// OUT=2: diag reduce: atomicAdd mc[bz*sC + (row-col)&511].
template<int EPI, int OUT>
__global__ __launch_bounds__(256)
void hgemm_k(const _Float16* __restrict__ A, int lda, int loA,
             const _Float16* __restrict__ Bm, int ldb, int loB,
             const float* __restrict__ R, void* __restrict__ Cv,
             int ldc, int loC, int K, int nph, float osc,
             long sA, long sB, long sC)
{
    __shared__ _Float16 As[128 * 64];
    __shared__ _Float16 Bs[128 * 64];
    const int bz = blockIdx.z;
    const int tid = threadIdx.x, lane = tid & 63, w = tid >> 6;
    const int wr = w >> 1, wc = w & 1;
    const _Float16* Ap = A + bz * sA + (long)(blockIdx.y * 128) * lda;
    const _Float16* Bp = Bm + bz * sB + (long)(blockIdx.x * 128) * ldb;

    const int swz = ((lane & 7) ^ ((lane >> 3) & 7)) * 8;
    const int rsub = w * 32 + (lane >> 3);
    const _Float16* ApT = Ap + (long)rsub * lda + swz;
    const _Float16* BpT = Bp + (long)rsub * ldb + swz;
    _Float16* AsT = As + w * 2048;
    _Float16* BsT = Bs + w * 2048;

    const int tpp = K >> 6;
    const int nkt = tpp * nph;
    f32x4 acc[4][4] = {};

    int p = 0, q = 0;
    for (int kt = 0; kt < nkt; ++kt) {
        const int aoff = q * 64 + (p == 2 ? loA : 0);
        const int boff = q * 64 + (p == 1 ? loB : 0);
        __syncthreads();
#pragma unroll
        for (int i = 0; i < 4; i++) {
            gl_lds(ApT + (long)i * 8 * lda + aoff, AsT + i * 512);
            gl_lds(BpT + (long)i * 8 * ldb + boff, BsT + i * 512);
        }
        __syncthreads();
#pragma unroll
        for (int kk = 0; kk < 2; ++kk) {
            h8 af[4], bf[4];
            const int ks = kk * 4 + (lane >> 4);
#pragma unroll
            for (int m = 0; m < 4; m++) {
                int rowa = wr * 64 + m * 16 + (lane & 15);
                af[m] = *(const h8*)(As + rowa * 64 + ((ks ^ (rowa & 7)) * 8));
                int rowb = wc * 64 + m * 16 + (lane & 15);
                bf[m] = *(const h8*)(Bs + rowb * 64 + ((ks ^ (rowb & 7)) * 8));
            }
#pragma unroll
            for (int m = 0; m < 4; m++)
#pragma unroll
                for (int n = 0; n < 4; n++)
                    acc[m][n] = __builtin_amdgcn_mfma_f32_16x16x32_f16(af[m], bf[n], acc[m][n], 0, 0, 0);
        }
        if (++q == tpp) { q = 0; ++p; }
    }

    const int crow0 = blockIdx.y * 128 + wr * 64 + (lane >> 4) * 4;
    const int ccol0 = blockIdx.x * 128 + wc * 64 + (lane & 15);
    if constexpr (OUT == 0) {
        float* Cp = (float*)Cv + (long)bz * sC;
        const float* Rp = (EPI == 1) ? (R + (long)bz * sC) : nullptr;
#pragma unroll
        for (int m = 0; m < 4; m++)
#pragma unroll
            for (int n = 0; n < 4; n++) {
                int col = ccol0 + n * 16;
#pragma unroll
                for (int r2 = 0; r2 < 4; r2++) {
                    long idx = (long)(crow0 + m * 16 + r2) * ldc + col;
                    float v = acc[m][n][r2] * osc;
                    if (EPI == 1) v += Rp[idx];
                    Cp[idx] = v;
                }
            }
    } else if constexpr (OUT == 1) {
        _Float16* Cp = (_Float16*)Cv + (long)bz * sC;
#pragma unroll
        for (int m = 0; m < 4; m++)
#pragma unroll
            for (int n = 0; n < 4; n++) {
                int col = ccol0 + n * 16;
#pragma unroll
                for (int r2 = 0; r2 < 4; r2++) {
                    long base = (long)(crow0 + m * 16 + r2) * ldc + col;
                    float v = acc[m][n][r2] * osc;
                    if (EPI == 2) v = gelu_f(v);
                    _Float16 hi = (_Float16)v;
                    Cp[base] = hi;
                    if (loC >= 0) Cp[base + loC] = (_Float16)(v - (float)hi);
                }
            }
    } else {
        __shared__ float diag[512];
        float* mc = (float*)Cv + (long)bz * sC;
        for (int t = tid; t < 512; t += 256) diag[t] = 0.f;
        __syncthreads();
#pragma unroll
        for (int m = 0; m < 4; m++)
#pragma unroll
            for (int n = 0; n < 4; n++) {
                int col = ccol0 + n * 16;
#pragma unroll
                for (int r2 = 0; r2 < 4; r2++) {
                    int row = crow0 + m * 16 + r2;
                    atomicAdd(&diag[(row - col) & 511], acc[m][n][r2]);
                }
            }
        __syncthreads();
        for (int t = tid; t < 512; t += 256) {
            float v = diag[t];
            if (v != 0.f) atomicAdd(&mc[t], v);
        }
    }
}

// ------------------------- weight conversion -------------------------------
// 12 plain splits (512x512 each): m<4 -> PA[2m] (Wk); m in 4..7 -> PB[2(m-4)]
// (Wq); m in 8..11 -> PB[2(m-8)+1] (Wv). All scaled x64. grid (128, 12).
__global__ __launch_bounds__(256)
void splitAll_k(P12 ps, _Float16* __restrict__ PA, _Float16* __restrict__ PB)
{
    const int m = blockIdx.y;
    const float* __restrict__ src = ps.p[m];
    _Float16* dst;
    if (m < 4)      dst = PA + (long)(2 * m) * 524288;
    else if (m < 8) dst = PB + (long)(2 * (m - 4)) * 524288;
    else            dst = PB + (long)(2 * (m - 8) + 1) * 524288;
    long t = (long)blockIdx.x * 256 + threadIdx.x;
    long row = t >> 6; int kc = (int)(t & 63) * 8;
    const float4 v0 = *(const float4*)(src + row * 512 + kc);
    const float4 v1 = *(const float4*)(src + row * 512 + kc + 4);
    float vv[8] = {v0.x,v0.y,v0.z,v0.w,v1.x,v1.y,v1.z,v1.w};
    h8 hi, lo;
#pragma unroll
    for (int j = 0; j < 8; j++) {
        float s = vv[j] * 64.f;
        _Float16 h = (_Float16)s;
        hi[j] = h; lo[j] = (_Float16)(s - (float)h);
    }
    *(h8*)(dst + row * 1024 + kc)       = hi;
    *(h8*)(dst + row * 1024 + 512 + kc) = lo;
}

// 4 transposed converts (Wo, 512x512): z -> PA[2z+1], scaled x64. grid(16,16,4)
__global__ __launch_bounds__(256)
void convWoAll_k(P4 ps, _Float16* __restrict__ PA)
{
    const int z = blockIdx.z;
    const float* __restrict__ src = ps.p[z];
    _Float16* dst = PA + (long)(2 * z + 1) * 524288;
    __shared__ float t[32][33];
    int k0 = blockIdx.x * 32, n0 = blockIdx.y * 32, tid = threadIdx.x;
#pragma unroll
    for (int i = 0; i < 4; i++) {
        int lin = tid + i * 256; int r = lin >> 5, c = lin & 31;
        t[r][c] = src[(long)(k0 + r) * 512 + n0 + c];
    }
    __syncthreads();
#pragma unroll
    for (int i = 0; i < 4; i++) {
        int lin = tid + i * 256; int n = lin >> 5, k = lin & 31;
        float v = t[k][n] * 64.f;
        _Float16 hi = (_Float16)v;
        long base = (long)(n0 + n) * 1024 + k0 + k;
        dst[base]       = hi;
        dst[base + 512] = (_Float16)(v - (float)hi);
    }
}

// W (K x N f32) -> dst (N rows x 2K f16 cat). grid (K/32, N/32)
__global__ __launch_bounds__(256)
void convW2_k(const float* __restrict__ src, _Float16* __restrict__ dst,
              int N, int K)
{
    __shared__ float t[32][33];
    int k0 = blockIdx.x * 32, n0 = blockIdx.y * 32, tid = threadIdx.x;
#pragma unroll
    for (int i = 0; i < 4; i++) {
        int lin = tid + i * 256; int r = lin >> 5, c = lin & 31;
        t[r][c] = src[(long)(k0 + r) * N + n0 + c];
    }
    __syncthreads();
#pragma unroll
    for (int i = 0; i < 4; i++) {
        int lin = tid + i * 256; int n = lin >> 5, k = lin & 31;
        float v = t[k][n];
        _Float16 hi = (_Float16)v;
        long base = (long)(n0 + n) * 2 * K + k0 + k;
        dst[base]     = hi;
        dst[base + K] = (_Float16)(v - (float)hi);
    }
}

// dtW (3 x 512 x 21) -> 128 rows x 1024 cat, x64 (row j = t*21+c, zero-pad)
__global__ void convW63_k(const float* __restrict__ W, _Float16* __restrict__ dst)
{
    int i = blockIdx.x * 256 + threadIdx.x;   // 65536
    int k = i & 511, j = i >> 9;
    float v = (j < 63) ? 64.f * W[(long)(j / 21) * 10752 + (long)k * 21 + (j % 21)] : 0.f;
    _Float16 hi = (_Float16)v;
    dst[(long)j * 1024 + k]       = hi;
    dst[(long)j * 1024 + 512 + k] = (_Float16)(v - (float)hi);
}

// ------------------------- embedding (conv3 + mark + pe + cat) -------------
__global__ __launch_bounds__(256)
void embed_k(const float* __restrict__ x, const float* __restrict__ mark,
             const float* __restrict__ valW, const float* __restrict__ timeW,
             float* __restrict__ out, _Float16* __restrict__ cat)
{
    const int lg = blockIdx.x, dh = blockIdx.y, b = blockIdx.z;
    const int tid = threadIdx.x;
    const int dd = dh * 256 + tid;
    const int l0 = lg * 8;
    __shared__ float xs[10][21];
    __shared__ float mk[8][4];
    if (tid < 210) {
        int r = tid / 21, c = tid % 21;
        int ll = (l0 - 1 + r + 512) & 511;
        xs[r][c] = x[((long)b * 512 + ll) * 21 + c];
    }
    if (tid >= 224 && tid < 256) {
        int t2 = tid - 224, il = t2 >> 2, m = t2 & 3;
        mk[il][m] = mark[((long)b * 512 + l0 + il) * 4 + m];
    }
    __syncthreads();
    float acc[8];
#pragma unroll
    for (int il = 0; il < 8; il++) acc[il] = 0.f;
    for (int t = 0; t < 3; t++)
        for (int c = 0; c < 21; c++) {
            float w = valW[(t * 21 + c) * 512 + dd];
#pragma unroll
            for (int il = 0; il < 8; il++)
                acc[il] = fmaf(xs[il + t][c], w, acc[il]);
        }
    for (int m = 0; m < 4; m++) {
        float w = timeW[m * 512 + dd];
#pragma unroll
        for (int il = 0; il < 8; il++)
            acc[il] = fmaf(mk[il][m], w, acc[il]);
    }
    const float freq = expf((float)(dd & ~1) * (-9.210340371976184f / 512.0f));
#pragma unroll
    for (int il = 0; il < 8; il++) {
        float ang = (float)(l0 + il) * freq;
        float pe = (dd & 1) ? cosf(ang) : sinf(ang);
        float v = acc[il] + pe;
        long row = (long)b * 512 + l0 + il;
        out[row * 512 + dd] = v;
        _Float16 hi = (_Float16)v;
        cat[row * 1024 + dd]       = hi;
        cat[row * 1024 + 512 + dd] = (_Float16)(v - (float)hi);
    }
}

// ------------------- windowed decomp (8 rows/thread, D=512) ----------------
// TREND: 0 none, 1 TSc += trend (cat), 2 TSc = trend (cat). CAT: seasonal cat.
template<int TREND, int CAT>
__global__ __launch_bounds__(256)
void decompW_k(const float* __restrict__ x, float* __restrict__ out,
               _Float16* __restrict__ cat, _Float16* __restrict__ tsc)
{
    long t = (long)blockIdx.x * 256 + threadIdx.x;
    long rowg = t >> 7; int d4 = (int)(t & 127) * 4;
    int lg = (int)(rowg & 63); long b = rowg >> 6;
    const int l0 = lg * 8;
    const float* xb = x + (b << 18);
    float s[8][4] = {};
    float xo[8][4];
#pragma unroll
    for (int rr = -12; rr <= 19; rr++) {
        int rc = l0 + rr; rc = rc < 0 ? 0 : (rc > 511 ? 511 : rc);
        float4 v = *(const float4*)(xb + ((long)rc << 9) + d4);
        float vv[4] = {v.x, v.y, v.z, v.w};
#pragma unroll
        for (int i = 0; i < 8; i++) {
            if (i >= rr - 12 && i <= rr + 12) {
#pragma unroll
                for (int j = 0; j < 4; j++) s[i][j] += vv[j];
            }
        }
        if (rr >= 0 && rr < 8) {
#pragma unroll
            for (int j = 0; j < 4; j++) xo[rr][j] = vv[j];
        }
    }
#pragma unroll
    for (int i = 0; i < 8; i++) {
        long row = b * 512 + l0 + i;
        float tr[4], ov[4];
#pragma unroll
        for (int j = 0; j < 4; j++) {
            tr[j] = s[i][j] * (1.f / 25.f);
            ov[j] = xo[i][j] - tr[j];
        }
        *(float4*)(out + row * 512 + d4) = make_float4(ov[0], ov[1], ov[2], ov[3]);
        if (CAT) {
            h4 hi, lo;
#pragma unroll
            for (int j = 0; j < 4; j++) {
                _Float16 h = (_Float16)ov[j];
                hi[j] = h; lo[j] = (_Float16)(ov[j] - (float)h);
            }
            *(h4*)(cat + row * 1024 + d4)       = hi;
            *(h4*)(cat + row * 1024 + 512 + d4) = lo;
        }
        if (TREND) {
            _Float16* tp = tsc + row * 1024 + d4;
            if (TREND == 1) {
                h4 th = *(h4*)tp, tl = *(h4*)(tp + 512);
#pragma unroll
                for (int j = 0; j < 4; j++) tr[j] += (float)th[j] + (float)tl[j];
            }
            h4 th2, tl2;
#pragma unroll
            for (int j = 0; j < 4; j++) {
                _Float16 h = (_Float16)tr[j];
                th2[j] = h; tl2[j] = (_Float16)(tr[j] - (float)h);
            }
            *(h4*)tp         = th2;
            *(h4*)(tp + 512) = tl2;
        }
    }
}

// ------------------------- prep (mean + decomp tail + inits) ---------------
__global__ void meanseq_k(const float* __restrict__ x, float* __restrict__ xm, int total)
{
    int i = blockIdx.x * 256 + threadIdx.x;
    if (i >= total) return;
    int c = i % 21, b = i / 21;
    float s = 0.f;
    for (int l = 0; l < 512; l++) s += x[((long)b * 512 + l) * 21 + c];
    xm[i] = s * (1.f / 512.f);
}

__global__ void prep_k(const float* __restrict__ x, const float* __restrict__ xm,
                       float* __restrict__ sinit, float* __restrict__ tinit, int total)
{
    int i = blockIdx.x * 256 + threadIdx.x;
    if (i >= total) return;
    int c = i % 21, l = (i / 21) % 512, b = i / 10752;
    if (l < 256) {
        int lc = 256 + l;
        float s = 0.f;
        for (int j = -12; j <= 12; j++) {
            int ll = lc + j; ll = ll > 511 ? 511 : ll;
            s += x[((long)b * 512 + ll) * 21 + c];
        }
        float t = s * (1.f / 25.f);
        tinit[i] = t;
        sinit[i] = x[((long)b * 512 + lc) * 21 + c] - t;
    } else {
        sinit[i] = 0.f;
        tinit[i] = xm[b * 21 + c];
    }
}

// ------------------------- top-k (scaled mc; self-cleans) ------------------
__global__ __launch_bounds__(256)
void topk_k(float* __restrict__ mc, int* __restrict__ delays,
            float* __restrict__ wts)
{
    const float SCL = 1.f / (512.f * 4096.f);  // 1/512 mean, 1/(64*64) prescale
    int b = blockIdx.x, tid = threadIdx.x;
    __shared__ float v[512];
    __shared__ float rv[256];
    __shared__ int   ri[256];
    __shared__ float selv[6];
    v[tid]       = mc[b * 512 + tid]       * SCL;
    v[tid + 256] = mc[b * 512 + tid + 256] * SCL;
    mc[b * 512 + tid] = 0.f;
    mc[b * 512 + tid + 256] = 0.f;
    __syncthreads();
    for (int p = 0; p < 6; p++) {
        float bv = v[tid]; int bi = tid;
        float v2 = v[tid + 256];
        if (v2 > bv) { bv = v2; bi = tid + 256; }
        rv[tid] = bv; ri[tid] = bi;
        __syncthreads();
        for (int s = 128; s > 0; s >>= 1) {
            if (tid < s) {
                float ov = rv[tid + s]; int oi = ri[tid + s];
                if (ov > rv[tid] || (ov == rv[tid] && oi < ri[tid])) {
                    rv[tid] = ov; ri[tid] = oi;
                }
            }
            __syncthreads();
        }
        if (tid == 0) { selv[p] = rv[0]; delays[b * 6 + p] = ri[0]; v[ri[0]] = -3.4e38f; }
        __syncthreads();
    }
    if (tid == 0) {
        float mx = selv[0];
        for (int p = 1; p < 6; p++) mx = fmaxf(mx, selv[p]);
        float e[6], sum = 0.f;
        for (int p = 0; p < 6; p++) { e[p] = expf(selv[p] - mx); sum += e[p]; }
        for (int p = 0; p < 6; p++) wts[b * 6 + p] = e[p] / sum;
    }
}

// gather-agg (hi-only) from cat source; write hi-only out (rows x 512)
__global__ __launch_bounds__(256)
void agg2_k(const _Float16* __restrict__ Vc, int vld,
            const int* __restrict__ delays, const float* __restrict__ wts,
            _Float16* __restrict__ out)
{
    long t = (long)blockIdx.x * 256 + threadIdx.x;
    int dc = (int)(t & 63);
    long row = t >> 6;
    int l = (int)(row & 511), b = (int)(row >> 9);
    float s[8] = {};
#pragma unroll
    for (int k = 0; k < 6; k++) {
        int dl = delays[b * 6 + k];
        float wv = wts[b * 6 + k];
        long sr = ((long)b * 512 + ((l + dl) & 511)) * vld + dc * 8;
        h8 hi8 = *(const h8*)(Vc + sr);
#pragma unroll
        for (int j = 0; j < 8; j++)
            s[j] = fmaf(wv, (float)hi8[j], s[j]);
    }
    h8 ho;
#pragma unroll
    for (int j = 0; j < 8; j++) ho[j] = (_Float16)s[j];
    *(h8*)(out + row * 512 + dc * 8) = ho;
}

// ------------------------- seasonal layernorm ------------------------------
__global__ __launch_bounds__(256)
void ln_k(const float* __restrict__ x, const float* __restrict__ g,
          const float* __restrict__ be, float* __restrict__ out)
{
    int row = blockIdx.x, tid = threadIdx.x;
    const float* xr = x + ((long)row << 9);
    float v0 = xr[tid], v1 = xr[tid + 256];
    __shared__ float rs[256];
    rs[tid] = v0 + v1; __syncthreads();
    for (int s = 128; s > 0; s >>= 1) { if (tid < s) rs[tid] += rs[tid + s]; __syncthreads(); }
    float mu = rs[0] * (1.f / 512.f);
    __syncthreads();
    float d0 = v0 - mu, d1 = v1 - mu;
    rs[tid] = d0 * d0 + d1 * d1; __syncthreads();
    for (int s = 128; s > 0; s >>= 1) { if (tid < s) rs[tid] += rs[tid + s]; __syncthreads(); }
    float rstd = 1.0f / sqrtf(rs[0] * (1.f / 512.f) + 1e-5f);
    out[((long)row << 9) + tid]       = d0 * rstd * g[tid] + be[tid];
    out[((long)row << 9) + tid + 256] = d1 * rstd * g[tid + 256] + be[tid + 256];
}

// per-(b,d) column sums (raw, not divided). grid (2, Bc)
__global__ __launch_bounds__(256)
void colsum_k(const float* __restrict__ x, float* __restrict__ cs)
{
    int d = blockIdx.x * 256 + threadIdx.x;
    int b = blockIdx.y;
    const float* xb = x + ((long)b << 18);
    float s = 0.f;
    for (int l = 0; l < 512; l++) s += xb[((long)l << 9) + d];
    cs[((long)b << 9) + d] = s;
}

// write hi/lo cat of (x - colsum/512) — encoder tail
__global__ __launch_bounds__(256)
void subcolcat_k(const float* __restrict__ x, const float* __restrict__ cs,
                 _Float16* __restrict__ cat)
{
    long t = (long)blockIdx.x * 256 + threadIdx.x;
    long row = t >> 6; int d8 = (int)(t & 63) * 8;
    int b = (int)(row >> 9);
    const float4* c4 = (const float4*)(cs + ((long)b << 9) + d8);
    float4 m0 = c4[0], m1 = c4[1];
    float m[8] = {m0.x,m0.y,m0.z,m0.w,m1.x,m1.y,m1.z,m1.w};
    const float4* xp = (const float4*)(x + row * 512 + d8);
    float4 x0 = xp[0], x1 = xp[1];
    float v[8] = {x0.x,x0.y,x0.z,x0.w,x1.x,x1.y,x1.z,x1.w};
    h8 hi, lo;
#pragma unroll
    for (int j = 0; j < 8; j++) {
        float vv = v[j] - m[j] * (1.f / 512.f);
        _Float16 h = (_Float16)vv;
        hi[j] = h; lo[j] = (_Float16)(vv - (float)h);
    }
    *(h8*)(cat + row * 1024 + d8)       = hi;
    *(h8*)(cat + row * 1024 + 512 + d8) = lo;
}

// proj with fused column-mean subtract + trend shift-add (decoder tail)
__global__ void proj_k(const float* __restrict__ x, const float* __restrict__ cs,
                       const float* __restrict__ pw, const float* __restrict__ pb,
                       const float* __restrict__ tinit, const float* __restrict__ H,
                       float* __restrict__ out, int total)
{
    int i = blockIdx.x * 256 + threadIdx.x;
    if (i >= total) return;
    int c = i % 21, l = (i / 21) % 256 + 256, b = i / 5376;
    const float* xr = x + ((long)(b * 512 + l) << 9);
    const float* csb = cs + ((long)b << 9);
    float s = 0.f;
    for (int d = 0; d < 512; d++)
        s = fmaf(xr[d] - csb[d] * (1.f / 512.f), pw[d * 21 + c], s);
    long r = (long)b * 512;
    float trend = tinit[b * 10752 + l * 21 + c]
                + H[(r + ((l + 511) & 511)) * 128 + c]
                + H[(r + l) * 128 + 21 + c]
                + H[(r + ((l + 1) & 511)) * 128 + 42 + c];
    out[i] = s + pb[c] + trend;
}

// ---------------------------------------------------------------------------
// mode: 0 OUT1 cat, 2 OUT1 gelu-cat, 10 OUT0 +R, 11 OUT0 plain, 20 Scorr
static void hgemm(int mode, int nph, float osc,
                  const _Float16* A, int lda, int loA,
                  const _Float16* B, int ldb, int loB,
                  const float* R, void* C, int ldc, int loC,
                  int K, int M, int N, int batch,
                  long sA, long sB, long sC, hipStream_t st)
{
    dim3 g(N / 128, M / 128, batch), blk(256);
    switch (mode) {
    case 0:  hgemm_k<0,1><<<g,blk,0,st>>>(A,lda,loA,B,ldb,loB,R,C,ldc,loC,K,nph,osc,sA,sB,sC); break;
    case 2:  hgemm_k<2,1><<<g,blk,0,st>>>(A,lda,loA,B,ldb,loB,R,C,ldc,loC,K,nph,osc,sA,sB,sC); break;
    case 10: hgemm_k<1,0><<<g,blk,0,st>>>(A,lda,loA,B,ldb,loB,R,C,ldc,loC,K,nph,osc,sA,sB,sC); break;
    case 11: hgemm_k<0,0><<<g,blk,0,st>>>(A,lda,loA,B,ldb,loB,R,C,ldc,loC,K,nph,osc,sA,sB,sC); break;
    default: hgemm_k<0,2><<<g,blk,0,st>>>(A,lda,loA,B,ldb,loB,R,C,ldc,loC,K,nph,osc,sA,sB,sC); break;
    }
}

extern "C" void kernel_launch(void* const* d_in, const int* in_sizes, int n_in,
                              void* d_out, int out_size, void* d_ws, size_t ws_size,
                              hipStream_t stream)
{
    const float* x_enc    = (const float*)d_in[0];
    const float* xm_enc   = (const float*)d_in[1];
    const float* xm_dec   = (const float*)d_in[3];
    const float* enc_valW = (const float*)d_in[4];
    const float* enc_timeW= (const float*)d_in[5];
    const float* enc_Wq   = (const float*)d_in[6];
    const float* enc_Wk   = (const float*)d_in[7];
    const float* enc_Wv   = (const float*)d_in[8];
    const float* enc_Wo   = (const float*)d_in[9];
    const float* enc_W1   = (const float*)d_in[10];
    const float* enc_W2   = (const float*)d_in[11];
    const float* enc_g    = (const float*)d_in[12];
    const float* enc_b    = (const float*)d_in[13];
    const float* dec_valW = (const float*)d_in[14];
    const float* dec_timeW= (const float*)d_in[15];
    const float* sWq = (const float*)d_in[16];
    const float* sWk = (const float*)d_in[17];
    const float* sWv = (const float*)d_in[18];
    const float* sWo = (const float*)d_in[19];
    const float* cWq = (const float*)d_in[20];
    const float* cWk = (const float*)d_in[21];
    const float* cWv = (const float*)d_in[22];
    const float* cWo = (const float*)d_in[23];
    const float* dW1 = (const float*)d_in[24];
    const float* dW2 = (const float*)d_in[25];
    const float* dtW = (const float*)d_in[26];
    const float* dec_g = (const float*)d_in[27];
    const float* dec_b = (const float*)d_in[28];
    const float* projW = (const float*)d_in[29];
    const float* projB = (const float*)d_in[30];

    // ---- batch-chunk sizing (deterministic) ----
    const size_t W_BYTES = 50000000;
    const size_t perB = 8900000;
    int Bc = 32;
    while (Bc > 1 && W_BYTES + (size_t)Bc * perB + (4u << 20) > ws_size) Bc >>= 1;

    char* wp = (char*)d_ws;
    auto alloc = [&](size_t bytes) { char* p = wp; wp += (bytes + 255) & ~(size_t)255; return p; };

    // weight buffers
    _Float16* Wcat8  = (_Float16*)alloc(8 * 524288 * 2);   // qk/vo products (cat)
    _Float16* encW1C = (_Float16*)alloc(2 * 2097152 * 2);
    _Float16* encW2C = (_Float16*)alloc(2 * 2097152 * 2);
    _Float16* dW1C   = (_Float16*)alloc(2097152 * 2);
    _Float16* dW2C   = (_Float16*)alloc(2097152 * 2);
    _Float16* W63C   = (_Float16*)alloc(131072 * 2);
    _Float16* PA     = (_Float16*)alloc(8 * 524288 * 2);   // setup staging
    _Float16* PB     = (_Float16*)alloc(8 * 524288 * 2);

    const long ROWS = (long)Bc * 512;
    const long NBc  = ROWS * 512;
    float*    X      = (float*)alloc(NBc * 4);
    float*    O      = (float*)alloc(NBc * 4);
    _Float16* TSc    = (_Float16*)alloc(ROWS * 1024 * 2);
    _Float16* cX     = (_Float16*)alloc(ROWS * 1024 * 2);
    _Float16* cAgg   = (_Float16*)alloc(ROWS * 512 * 2);   // hi-only
    _Float16* ENCcat = (_Float16*)alloc(ROWS * 1024 * 2);
    _Float16* bigcat = (_Float16*)alloc(ROWS * 2048 * 2);  // T cat / hidden hi
    float* H       = (float*)alloc(ROWS * 128 * 4);
    float* sinit   = (float*)alloc((long)Bc * 10752 * 4);
    float* tinit   = (float*)alloc((long)Bc * 10752 * 4);
    float* xmean   = (float*)alloc((long)Bc * 21 * 4);
    float* mc      = (float*)alloc((long)Bc * 512 * 4);
    float* cs      = (float*)alloc((long)Bc * 512 * 4);
    float* wts     = (float*)alloc((long)Bc * 6 * 4);
    int*   delays  = (int*)alloc((long)Bc * 6 * 4);

    // ---- weight setup (batched): attn order {enc0, enc1, self, cross} ----
    dim3 cb(256);
    P12 sp;
    sp.p[0] = enc_Wk;           sp.p[1] = enc_Wk + 262144;
    sp.p[2] = sWk;              sp.p[3] = cWk;
    sp.p[4] = enc_Wq;           sp.p[5] = enc_Wq + 262144;
    sp.p[6] = sWq;              sp.p[7] = cWq;
    sp.p[8] = enc_Wv;           sp.p[9] = enc_Wv + 262144;
    sp.p[10] = sWv;             sp.p[11] = cWv;
    P4 op;
    op.p[0] = enc_Wo;           op.p[1] = enc_Wo + 262144;
    op.p[2] = sWo;              op.p[3] = cWo;
    splitAll_k <<<dim3(128,12), cb, 0, stream>>>(sp, PA, PB);
    convWoAll_k<<<dim3(16,16,4), cb, 0, stream>>>(op, PA);
    hgemm(0, 3, 1.f, PA,1024,512, PB,1024,512, nullptr, Wcat8, 1024, 512,
          512, 512, 512, 8, 524288, 524288, 524288, stream);
    for (int L = 0; L < 2; L++) {
        convW2_k<<<dim3(16,64), cb, 0, stream>>>(enc_W1 + (long)L*1048576, encW1C + (long)L*2097152, 2048, 512);
        convW2_k<<<dim3(64,16), cb, 0, stream>>>(enc_W2 + (long)L*1048576, encW2C + (long)L*2097152, 512, 2048);
    }
    convW2_k<<<dim3(16,64), cb, 0, stream>>>(dW1, dW1C, 2048, 512);
    convW2_k<<<dim3(64,16), cb, 0, stream>>>(dW2, dW2C, 512, 2048);
    convW63_k<<<256, cb, 0, stream>>>(dtW, W63C);

    const int M = (int)ROWS;
    const int t21 = Bc * 10752;
    const int gRows = Bc * 128;
    const int gW = Bc * 32;
    const long sCA = 512 * 1024;
    const float IOS = 1.f / 4096.f;

    zero_k<<<(Bc*512 + 255)/256, 256, 0, stream>>>(mc, Bc*512);

    // attention: Cout = Xin + agg(KVcat)@Wvo; T = cQ@Wqk vs KVcat for corr.
    // T/Scorr: 3-phase (top-k path). Wvo: 1-phase + hi-only agg.
    auto attn = [&](float* Xin, float* Cout, const _Float16* cQ,
                    const _Float16* KVcat, int slot) {
        const _Float16* WqkC_ = Wcat8 + (long)(2*slot)     * 524288;
        const _Float16* WvoC_ = Wcat8 + (long)(2*slot + 1) * 524288;
        hgemm(0, 3, 1.f, cQ,1024,512, WqkC_,1024,512, nullptr, bigcat, 1024, 512,
              512, M, 512, 1, 0,0,0, stream);                              // T cat
        hgemm(20, 3, 1.f, bigcat,1024,512, KVcat,1024,512, nullptr, mc, 0, 0,
              512, 512, 512, Bc, sCA, sCA, 512, stream);                   // diag(T KV^T)
        topk_k<<<Bc, 256, 0, stream>>>(mc, delays, wts);
        agg2_k<<<gRows, 256, 0, stream>>>(KVcat, 1024, delays, wts, cAgg);
        hgemm(10, 1, IOS, cAgg,512,0, WvoC_,1024,512, Xin, Cout, 512, 0,
              512, M, 512, 1, 0,0,0, stream);                              // += agg@Wvo
    };
    // ffn: 1-phase both GEMMs; hidden hi-only in bigcat (ld 2048)
    auto ffn = [&](float* Xin, float* Cout, const _Float16* cXin,
                   const _Float16* W1C, const _Float16* W2C) {
        hgemm(2, 1, 1.f, cXin,1024,512, W1C,1024,512, nullptr, bigcat, 2048, -1,
              512, M, 2048, 1, 0,0,0, stream);
        hgemm(10, 1, 1.f, bigcat,2048,0, W2C,4096,2048, Xin, Cout, 512, 0,
              2048, M, 512, 1, 0,0,0, stream);
    };

    for (int b0 = 0; b0 < 32; b0 += Bc) {
        const float* xe  = x_enc  + (long)b0 * 10752;
        const float* mke = xm_enc + (long)b0 * 2048;
        const float* mkd = xm_dec + (long)b0 * 2048;
        float* outp = (float*)d_out + (long)b0 * 5376;

        meanseq_k<<<(Bc*21 + 255)/256, 256, 0, stream>>>(xe, xmean, Bc*21);
        prep_k   <<<(t21 + 255)/256, 256, 0, stream>>>(xe, xmean, sinit, tinit, t21);

        // ---------------- encoder ----------------
        embed_k<<<dim3(64,2,Bc), 256, 0, stream>>>(xe, mke, enc_valW, enc_timeW, X, cX);
        for (int L = 0; L < 2; L++) {
            attn(X, O, cX, cX, L);
            decompW_k<0,1><<<gW, 256, 0, stream>>>(O, X, cX, nullptr);
            ffn(X, O, cX, encW1C + (long)L*2097152, encW2C + (long)L*2097152);
            decompW_k<0,1><<<gW, 256, 0, stream>>>(O, X, cX, nullptr);
        }
        ln_k      <<<Bc*512, 256, 0, stream>>>(X, enc_g, enc_b, O);
        colsum_k  <<<dim3(2,Bc), 256, 0, stream>>>(O, cs);
        subcolcat_k<<<gRows, 256, 0, stream>>>(O, cs, ENCcat);

        // ---------------- decoder ----------------
        embed_k<<<dim3(64,2,Bc), 256, 0, stream>>>(sinit, mkd, dec_valW, dec_timeW, X, cX);

        // self attention
        attn(X, O, cX, cX, 2);
        decompW_k<2,1><<<gW, 256, 0, stream>>>(O, X, cX, TSc);       // TSc = trend

        // cross attention (Q from dec stream, K/V role = ENCcat)
        attn(X, O, cX, ENCcat, 3);
        decompW_k<1,1><<<gW, 256, 0, stream>>>(O, X, cX, TSc);       // TSc += trend

        // ffn
        ffn(X, O, cX, dW1C, dW2C);
        decompW_k<1,0><<<gW, 256, 0, stream>>>(O, X, nullptr, TSc);

        // trend conv as MFMA GEMM (1-phase): H = (TSc_hi @ W63x64_hi)/64
        hgemm(11, 1, 1.f/64.f, TSc,1024,512, W63C,1024,512, nullptr, H, 128, 0,
              512, M, 128, 1, 0,0,0, stream);
        ln_k      <<<Bc*512, 256, 0, stream>>>(X, dec_g, dec_b, O);
        colsum_k  <<<dim3(2,Bc), 256, 0, stream>>>(O, cs);
        proj_k    <<<(Bc*5376+255)/256, 256, 0, stream>>>(O, cs, projW, projB,
                                                          tinit, H, outp, Bc*5376);
    }
}